// Round 2
// baseline (3029.841 us; speedup 1.0000x reference)
//
#include <hip/hip_runtime.h>
#include <math.h>

#define NC 256
#define CH3 768
#define HWSZ 16384

// float-element offsets into workspace (total 31,658,304 floats = 121 MiB)
static const size_t OFF_TABD  = 0;          // 32768 f (16384 float2)
static const size_t OFF_TW1   = 32768;
static const size_t OFF_STAB  = 65536;
static const size_t OFF_TW2   = 98304;
static const size_t OFF_ETAB  = 131072;
static const size_t OFF_HM    = 163840;     // 64
static const size_t OFF_SCALE = 163904;     // 1024 (b,ch)
static const size_t OFF_SHIFT = 164928;     // 1024
static const size_t OFF_SSUM  = 165952;     // 768 (per-batch ch)
static const size_t OFF_SALT  = 166720;     // 768
static const size_t OFF_SSQ   = 167488;     // 768
static const size_t OFF_ATTN  = 168256;     // 16384
static const size_t OFF_ACOMB = 184640;     // 16384
static const size_t OFF_PP    = 201024;     // 64 splits * 4 heads * 4096
static const size_t OFF_RP    = 1249600;    // 1,048,576
static const size_t OFF_H     = 2298176;    // 128 u * 256 rows * 128 r = 4,194,304
static const size_t OFF_QKV   = 6492480;    // 768*16384 = 12,582,912 (per-batch, post-dw)
static const size_t OFF_SCR   = 19075392;   // 12,582,912 : pre-dw qkv -> T/U -> out_head

// ---------------- tables ----------------
__global__ __launch_bounds__(256) void init_tables_k(float* __restrict__ ws){
  int idx = blockIdx.x*256 + threadIdx.x;       // 0..16383
  float2* tabD = (float2*)(ws + OFF_TABD);
  float2* tw1  = (float2*)(ws + OFF_TW1);
  float2* stab = (float2*)(ws + OFF_STAB);
  float2* tw2  = (float2*)(ws + OFF_TW2);
  float2* etab = (float2*)(ws + OFF_ETAB);
  float*  hm   = ws + OFF_HM;
  const double P2 = 6.283185307179586476925286766559005;
  int m = idx >> 7, k = idx & 127;
  double a1 = P2 * (double)((m*k) & 127) / 128.0;
  tabD[idx] = make_float2((float)cos(a1), (float)(-sin(a1)));   // D[f0,a]=e^{-2pi i f0 a/128}
  double a2 = P2 * (double)(m*k) / 16384.0;
  tw1[idx]  = make_float2((float)cos(a2), (float)(-sin(a2)));   // e^{-2pi i f0 b2/16384}
  tw2[idx]  = make_float2((float)cos(a2), (float)( sin(a2)));   // e^{+2pi i f0 r/16384}
  etab[idx] = make_float2((float)cos(a1), (float)( sin(a1)));   // e^{+2pi i u f0/128}
  int d = (k - m) & 127;                                        // stab[b2*128+r] = S[(r-b2)%128]
  double sr = 0.0, si = 0.0;
  for (int f1 = 0; f1 < 64; f1++){
    double a3 = P2 * (double)((f1*d) & 127) / 128.0;
    sr += cos(a3); si += sin(a3);
  }
  stab[idx] = make_float2((float)sr, (float)si);
  if (idx < 64){
    double acc = 0.0;
    for (int v = 1; v < 32; v++) acc += sin(P2 * (double)((v*idx) & 63) / 64.0);
    hm[idx] = (float)(-acc / 32.0);
  }
}

// ---------------- groupnorm stats -> per-(b,ch) scale/shift ----------------
__global__ __launch_bounds__(256) void gn_stats_k(const float* __restrict__ x, const float* __restrict__ gw,
                                                  const float* __restrict__ gb, float* __restrict__ scale,
                                                  float* __restrict__ shift){
  int bg = blockIdx.x; int b = bg >> 5, g = bg & 31;
  size_t base = ((size_t)b*NC + g*8) * HWSZ;
  const int n = 8*HWSZ;
  int tid = threadIdx.x;
  float s = 0.f, sq = 0.f;
  for (int i = tid; i < n; i += 256){ float v = x[base+i]; s += v; sq += v*v; }
  __shared__ float r1[256], r2[256];
  r1[tid] = s; r2[tid] = sq; __syncthreads();
  for (int off = 128; off; off >>= 1){
    if (tid < off){ r1[tid] += r1[tid+off]; r2[tid] += r2[tid+off]; }
    __syncthreads();
  }
  float mu = r1[0]/n, var = r2[0]/n - mu*mu;
  float rs = rsqrtf(var + 1e-5f);
  if (tid < 8){
    int ch = g*8 + tid;
    float sc = rs * gw[ch];
    scale[b*NC + ch] = sc;
    shift[b*NC + ch] = gb[ch] - mu*sc;
  }
}

// ---------------- fp32 GEMM (K=256), optional per-k scale/shift on B, optional bias ----------------
__global__ __launch_bounds__(256) void gemm_k(const float* __restrict__ A, const float* __restrict__ B,
                                              const float* __restrict__ scale, const float* __restrict__ shift,
                                              const float* __restrict__ bias, float* __restrict__ C){
  int m0 = blockIdx.y*64, n0 = blockIdx.x*64;
  __shared__ float As[16][65], Bs[16][65];
  int tid = threadIdx.x, tx = tid & 15, ty = tid >> 4;
  float acc[4][4] = {};
  for (int k0 = 0; k0 < 256; k0 += 16){
    #pragma unroll
    for (int i=0;i<4;i++){ int id=tid+i*256; int k=id&15, mm=id>>4; As[k][mm] = A[(size_t)(m0+mm)*256 + k0+k]; }
    #pragma unroll
    for (int i=0;i<4;i++){ int id=tid+i*256; int nn=id&63, k=id>>6;
      float v = B[(size_t)(k0+k)*HWSZ + n0+nn];
      if (scale) v = v*scale[k0+k] + shift[k0+k];
      Bs[k][nn] = v; }
    __syncthreads();
    #pragma unroll
    for (int k=0;k<16;k++){
      float a[4], bv[4];
      #pragma unroll
      for (int i=0;i<4;i++) a[i]=As[k][ty*4+i];
      #pragma unroll
      for (int j=0;j<4;j++) bv[j]=Bs[k][tx*4+j];
      #pragma unroll
      for (int i=0;i<4;i++)
        #pragma unroll
        for (int j=0;j<4;j++) acc[i][j] += a[i]*bv[j];
    }
    __syncthreads();
  }
  #pragma unroll
  for (int i=0;i<4;i++){
    int m = m0+ty*4+i; float bb = bias ? bias[m] : 0.0f;
    #pragma unroll
    for (int j=0;j<4;j++) C[(size_t)m*HWSZ + n0+tx*4+j] = acc[i][j] + bb;
  }
}

// ---------------- depthwise 3x3 + per-channel stats (one batch: 768 channels) ----------------
__global__ __launch_bounds__(256) void dwconv_stats_k(const float* __restrict__ qkv, const float* __restrict__ wdw,
                                                      float* __restrict__ outp, float* __restrict__ ssum,
                                                      float* __restrict__ salt, float* __restrict__ ssq){
  int ch = blockIdx.x;                 // 0..767
  const float* in = qkv + (size_t)ch * HWSZ;
  float w[9];
  #pragma unroll
  for (int i=0;i<9;i++) w[i] = wdw[ch*9+i];
  int tid = threadIdx.x;
  float s=0.f, sa=0.f, sq=0.f;
  for (int it=0; it<64; it++){
    int idx = it*256 + tid;
    int h = idx >> 7, xw = idx & 127;
    float acc = 0.f;
    #pragma unroll
    for (int ky=0; ky<3; ky++){
      int hh = h + ky - 1;
      if (hh < 0 || hh > 127) continue;
      #pragma unroll
      for (int kx=0; kx<3; kx++){
        int xx = xw + kx - 1;
        if (xx < 0 || xx > 127) continue;
        acc += in[hh*128 + xx] * w[ky*3+kx];
      }
    }
    outp[(size_t)ch*HWSZ + idx] = acc;
    s += acc; sa += (xw & 1) ? -acc : acc; sq += acc*acc;   // (-1)^s = (-1)^w since s=128h+w
  }
  __shared__ float r0[256], r1[256], r2[256];
  r0[tid]=s; r1[tid]=sa; r2[tid]=sq; __syncthreads();
  for (int off=128; off; off>>=1){
    if (tid<off){ r0[tid]+=r0[tid+off]; r1[tid]+=r1[tid+off]; r2[tid]+=r2[tid+off]; }
    __syncthreads();
  }
  if (tid==0){ ssum[ch]=r0[0]; salt[ch]=r1[0]; ssq[ch]=r2[0]; }
}

// ---------------- FFT stage 1: T'[f0][row][b2] = tw1 * sum_a D[f0,a] k[row][128a+b2] ----------------
// grid (256, 2): n = row_local*128+b2 (16384), m = f0 (128). chunk of 128 rows.
__global__ __launch_bounds__(256) void fft1_k(const float* __restrict__ Kb, const float* __restrict__ ws,
                                              float2* __restrict__ Tc, int rowBase){
  const float2* tabD = (const float2*)(ws + OFF_TABD);
  const float2* tw1  = (const float2*)(ws + OFF_TW1);
  int n0 = blockIdx.x*64, m0 = blockIdx.y*64;
  __shared__ float AsR[16][65], AsI[16][65], Bs[16][65];
  int tid=threadIdx.x, tx=tid&15, ty=tid>>4;
  float accR[4][4]={}, accI[4][4]={};
  for (int k0=0;k0<128;k0+=16){
    #pragma unroll
    for (int i=0;i<4;i++){ int id=tid+i*256; int k=id&15, mm=id>>4;
      float2 v = tabD[(m0+mm)*128 + k0+k]; AsR[k][mm]=v.x; AsI[k][mm]=v.y; }
    #pragma unroll
    for (int i=0;i<4;i++){ int id=tid+i*256; int nn=id&63, k=id>>6;
      int ng = n0+nn; int row = rowBase + (ng>>7);
      Bs[k][nn] = Kb[(size_t)row*HWSZ + (size_t)(k0+k)*128 + (ng&127)]; }
    __syncthreads();
    #pragma unroll
    for (int k=0;k<16;k++){
      float ar[4],ai[4],bv[4];
      #pragma unroll
      for (int i=0;i<4;i++){ ar[i]=AsR[k][ty*4+i]; ai[i]=AsI[k][ty*4+i]; }
      #pragma unroll
      for (int j=0;j<4;j++) bv[j]=Bs[k][tx*4+j];
      #pragma unroll
      for (int i=0;i<4;i++)
        #pragma unroll
        for (int j=0;j<4;j++){ accR[i][j] += ar[i]*bv[j]; accI[i][j] += ai[i]*bv[j]; }
    }
    __syncthreads();
  }
  #pragma unroll
  for (int i=0;i<4;i++)
    #pragma unroll
    for (int j=0;j<4;j++){
      int m = m0+ty*4+i, n = n0+tx*4+j;
      float2 t = tw1[m*128 + (n&127)];
      float r = accR[i][j], im = accI[i][j];
      Tc[(size_t)m*16384 + n] = make_float2(r*t.x - im*t.y, r*t.y + im*t.x);
    }
}

// ---------------- FFT stage 2: U'[f0][row][r] = tw2 * sum_b2 T'[f0,row,b2]*S[(r-b2)%128] ----------------
// grid (2, 256): n = r (128), m = f0*128+row_local (16384)
__global__ __launch_bounds__(256) void fft2_k(const float* __restrict__ ws, const float2* __restrict__ Tc,
                                              float2* __restrict__ U){
  const float2* stab = (const float2*)(ws + OFF_STAB);
  const float2* tw2  = (const float2*)(ws + OFF_TW2);
  int n0 = blockIdx.x*64, m0 = blockIdx.y*64;
  __shared__ float AsR[16][65], AsI[16][65], BsR[16][65], BsI[16][65];
  int tid=threadIdx.x, tx=tid&15, ty=tid>>4;
  float accR[4][4]={}, accI[4][4]={};
  for (int k0=0;k0<128;k0+=16){
    #pragma unroll
    for (int i=0;i<4;i++){ int id=tid+i*256; int k=id&15, mm=id>>4;
      float2 v = Tc[(size_t)(m0+mm)*128 + k0+k]; AsR[k][mm]=v.x; AsI[k][mm]=v.y; }
    #pragma unroll
    for (int i=0;i<4;i++){ int id=tid+i*256; int nn=id&63, k=id>>6;
      float2 v = stab[(k0+k)*128 + n0+nn]; BsR[k][nn]=v.x; BsI[k][nn]=v.y; }
    __syncthreads();
    #pragma unroll
    for (int k=0;k<16;k++){
      float ar[4],ai[4],br[4],bi[4];
      #pragma unroll
      for (int i=0;i<4;i++){ ar[i]=AsR[k][ty*4+i]; ai[i]=AsI[k][ty*4+i]; }
      #pragma unroll
      for (int j=0;j<4;j++){ br[j]=BsR[k][tx*4+j]; bi[j]=BsI[k][tx*4+j]; }
      #pragma unroll
      for (int i=0;i<4;i++)
        #pragma unroll
        for (int j=0;j<4;j++){
          accR[i][j] += ar[i]*br[j] - ai[i]*bi[j];
          accI[i][j] += ar[i]*bi[j] + ai[i]*br[j];
        }
    }
    __syncthreads();
  }
  #pragma unroll
  for (int i=0;i<4;i++)
    #pragma unroll
    for (int j=0;j<4;j++){
      int m = m0+ty*4+i, n = n0+tx*4+j;
      float2 t = tw2[((m>>7)<<7) + n];
      float r = accR[i][j], im = accI[i][j];
      U[(size_t)m*128 + n] = make_float2(r*t.x - im*t.y, r*t.y + im*t.x);
    }
}

// ---------------- FFT stage 3: H[u][rowBase+row][r] = Im sum_f0 E[u,f0]*U'[f0,row,r] ----------------
// grid (256, 2): n = row_local*128+r (16384), m = u (128)
__global__ __launch_bounds__(256) void fft3_k(const float* __restrict__ ws, const float2* __restrict__ U,
                                              float* __restrict__ Hb, int chunkBase){
  const float2* etab = (const float2*)(ws + OFF_ETAB);
  int n0 = blockIdx.x*64, m0 = blockIdx.y*64;
  __shared__ float AsR[16][65], AsI[16][65], BsR[16][65], BsI[16][65];
  int tid=threadIdx.x, tx=tid&15, ty=tid>>4;
  float acc[4][4]={};
  for (int k0=0;k0<128;k0+=16){
    #pragma unroll
    for (int i=0;i<4;i++){ int id=tid+i*256; int k=id&15, mm=id>>4;
      float2 v = etab[(m0+mm)*128 + k0+k]; AsR[k][mm]=v.x; AsI[k][mm]=v.y; }
    #pragma unroll
    for (int i=0;i<4;i++){ int id=tid+i*256; int nn=id&63, k=id>>6;
      float2 v = U[(size_t)(k0+k)*16384 + n0+nn]; BsR[k][nn]=v.x; BsI[k][nn]=v.y; }
    __syncthreads();
    #pragma unroll
    for (int k=0;k<16;k++){
      float ar[4],ai[4],br[4],bi[4];
      #pragma unroll
      for (int i=0;i<4;i++){ ar[i]=AsR[k][ty*4+i]; ai[i]=AsI[k][ty*4+i]; }
      #pragma unroll
      for (int j=0;j<4;j++){ br[j]=BsR[k][tx*4+j]; bi[j]=BsI[k][tx*4+j]; }
      #pragma unroll
      for (int i=0;i<4;i++)
        #pragma unroll
        for (int j=0;j<4;j++) acc[i][j] += ar[i]*bi[j] + ai[i]*br[j];
    }
    __syncthreads();
  }
  #pragma unroll
  for (int i=0;i<4;i++)
    #pragma unroll
    for (int j=0;j<4;j++)
      Hb[(size_t)(m0+ty*4+i)*32768 + chunkBase + n0+tx*4+j] = acc[i][j];
}

// ---------------- P & Ri split-K GEMMs (flip-addressed), one batch ----------------
// grid (64 splits, 4 heads)
__global__ __launch_bounds__(256) void pri_k(const float* __restrict__ qkvdw, const float* __restrict__ Hb,
                                             float* __restrict__ Pp, float* __restrict__ Rp){
  int sp = blockIdx.x, head = blockIdx.y;
  const float* Qb = qkvdw + (size_t)(head*64)*HWSZ;
  const float* Kb = qkvdw + (size_t)(256 + head*64)*HWSZ;
  int rowg0 = head*64;
  __shared__ float As[16][65], B1[16][65], B2[16][65];
  int tid=threadIdx.x, tx=tid&15, ty=tid>>4;
  float aP[4][4]={}, aR[4][4]={};
  for (int kc=0;kc<16;kc++){
    int s0 = sp*256 + kc*16;
    #pragma unroll
    for (int i=0;i<4;i++){ int id=tid+i*256; int kk=id&15, m=id>>4;
      As[kk][m] = Qb[(size_t)m*HWSZ + s0+kk]; }
    #pragma unroll
    for (int i=0;i<4;i++){ int id=tid+i*256; int kk=id&15, dd=id>>4;
      int t = (16384 - (s0+kk)) & 16383;
      B1[kk][dd] = Kb[(size_t)dd*HWSZ + t];
      int u = t>>7, r = t&127;
      B2[kk][dd] = Hb[(size_t)u*32768 + (size_t)(rowg0+dd)*128 + r]; }
    __syncthreads();
    #pragma unroll
    for (int k=0;k<16;k++){
      float a[4], b1[4], b2[4];
      #pragma unroll
      for (int i=0;i<4;i++) a[i]=As[k][ty*4+i];
      #pragma unroll
      for (int j=0;j<4;j++){ b1[j]=B1[k][tx*4+j]; b2[j]=B2[k][tx*4+j]; }
      #pragma unroll
      for (int i=0;i<4;i++)
        #pragma unroll
        for (int j=0;j<4;j++){ aP[i][j]+=a[i]*b1[j]; aR[i][j]+=a[i]*b2[j]; }
    }
    __syncthreads();
  }
  size_t base = ((size_t)(sp*4+head))<<12;
  #pragma unroll
  for (int i=0;i<4;i++)
    #pragma unroll
    for (int j=0;j<4;j++){
      size_t o = base + (size_t)(ty*4+i)*64 + tx*4+j;
      Pp[o]=aP[i][j]; Rp[o]=aR[i][j];
    }
}

// ---------------- attn build (one batch): reduce splits, rank-1 terms, norms, Hilbert mix ----------------
// grid 4 (heads)
__global__ __launch_bounds__(256) void attn_build_k(const float* __restrict__ ws, const float* __restrict__ temperature,
                                                    float* __restrict__ attn){
  const float* Pp   = ws + OFF_PP;
  const float* Rp   = ws + OFF_RP;
  const float* ssum = ws + OFF_SSUM;
  const float* salt = ws + OFF_SALT;
  const float* ssq  = ws + OFF_SSQ;
  const float* hmg  = ws + OFF_HM;
  __shared__ float Rn[64][65], Ril[64][65], hm[64];
  int head = blockIdx.x;
  int tid = threadIdx.x;
  if (tid < 64) hm[tid] = hmg[tid];
  for (int t=0;t<16;t++){
    int idx = tid + t*256; int c = idx>>6, d = idx&63;
    float P=0.f, Ri=0.f;
    for (int sp=0;sp<64;sp++){ size_t o = ((size_t)(sp*4+head)<<12) + idx; P += Pp[o]; Ri += Rp[o]; }
    int qch = head*64 + c;
    int kch = 256 + head*64 + d;
    float qs=ssum[qch], qa=salt[qch], qn=fmaxf(sqrtf(ssq[qch]), 1e-12f);
    float ks=ssum[kch], ka=salt[kch], kn=fmaxf(sqrtf(ssq[kch]), 1e-12f);
    float Rr = 0.5f*(16384.0f*P + qs*ks + qa*ka);
    float sc = 1.0f/(qn*kn);
    Rn[c][d]  = Rr*sc;
    Ril[c][d] = Ri*sc;
  }
  __syncthreads();
  float tmp2 = temperature[(head+2)&3];
  for (int t=0;t<16;t++){
    int idx = tid + t*256; int c = idx>>6, e = idx&63;
    float s = Rn[c][e];
    #pragma unroll 8
    for (int d=0; d<64; d++) s += Ril[c][d]*hm[(e-d)&63];
    attn[((size_t)head<<12) + (size_t)(c*64+e)] = s*tmp2;
  }
}

// ---------------- nested top-k masked softmax, combined over 4 branch weights ----------------
// grid 256 (head*64 + c)
__global__ __launch_bounds__(64) void topk_k(const float* __restrict__ attn, const float* __restrict__ attn_w,
                                             float* __restrict__ Acomb){
  int blk = blockIdx.x;
  int tid = threadIdx.x;
  __shared__ float row[64];
  float v = attn[(size_t)blk*64 + tid];
  row[tid] = v;
  __syncthreads();
  int rank = 0; float vmax = -1e30f;
  for (int l=0;l<64;l++){
    float w = row[l];
    if (w > v || (w == v && l < tid)) rank++;
    vmax = fmaxf(vmax, w);
  }
  float e = expf(v - vmax);
  const int kks[4] = {32,42,48,51};
  float denom[4];
  #pragma unroll
  for (int i=0;i<4;i++){
    float x = (rank < kks[i]) ? e : 0.0f;
    #pragma unroll
    for (int off=32; off; off>>=1) x += __shfl_xor(x, off);
    denom[i] = x;
  }
  float wgt = 0.f;
  #pragma unroll
  for (int i=0;i<4;i++) if (rank < kks[i]) wgt += attn_w[i] / denom[i];
  Acomb[(size_t)blk*64 + tid] = e * wgt;
}

// ---------------- out_head = A_comb @ v (one batch) ----------------
// grid (256, 4 heads)
__global__ __launch_bounds__(256) void av_k(const float* __restrict__ Acomb, const float* __restrict__ qkvdw,
                                            float* __restrict__ outh){
  int head = blockIdx.y;
  int n0 = blockIdx.x*64;
  const float* Vb = qkvdw + (size_t)(512 + head*64)*HWSZ;
  float* Op = outh + (size_t)(head*64)*HWSZ;
  __shared__ float As[64][65], Bs[16][65];
  int tid=threadIdx.x, tx=tid&15, ty=tid>>4;
  for (int t=0;t<16;t++){ int idx=tid+t*256; As[idx>>6][idx&63] = Acomb[((size_t)head<<12)+idx]; }
  __syncthreads();
  float acc[4][4]={};
  for (int k0=0;k0<64;k0+=16){
    #pragma unroll
    for (int i=0;i<4;i++){ int id=tid+i*256; int nn=id&63, k=id>>6;
      Bs[k][nn] = Vb[(size_t)(k0+k)*HWSZ + n0+nn]; }
    __syncthreads();
    #pragma unroll
    for (int k=0;k<16;k++){
      float a[4], bv[4];
      #pragma unroll
      for (int i=0;i<4;i++) a[i]=As[ty*4+i][k0+k];
      #pragma unroll
      for (int j=0;j<4;j++) bv[j]=Bs[k][tx*4+j];
      #pragma unroll
      for (int i=0;i<4;i++)
        #pragma unroll
        for (int j=0;j<4;j++) acc[i][j] += a[i]*bv[j];
    }
    __syncthreads();
  }
  #pragma unroll
  for (int i=0;i<4;i++)
    #pragma unroll
    for (int j=0;j<4;j++)
      Op[(size_t)(ty*4+i)*HWSZ + n0+tx*4+j] = acc[i][j];
}

extern "C" void kernel_launch(void* const* d_in, const int* in_sizes, int n_in,
                              void* d_out, int out_size, void* d_ws, size_t ws_size,
                              hipStream_t stream) {
  const float* x     = (const float*)d_in[0];
  const float* gn_w  = (const float*)d_in[1];
  const float* gn_b  = (const float*)d_in[2];
  const float* w_qkv = (const float*)d_in[3];
  const float* w_dw  = (const float*)d_in[4];
  const float* w_out = (const float*)d_in[5];
  const float* b_out = (const float*)d_in[6];
  const float* temperature = (const float*)d_in[7];
  const float* attn_w = (const float*)d_in[8];
  float* out = (float*)d_out;
  float* ws  = (float*)d_ws;

  init_tables_k<<<64,256,0,stream>>>(ws);
  gn_stats_k<<<128,256,0,stream>>>(x, gn_w, gn_b, ws+OFF_SCALE, ws+OFF_SHIFT);

  for (int b = 0; b < 4; b++){
    const float* xb = x + (size_t)b*NC*HWSZ;
    // qkv = w_qkv @ groupnorm(x_b)   (GN fused into B-load)
    gemm_k<<<dim3(256,12),256,0,stream>>>(w_qkv, xb, ws+OFF_SCALE+b*NC, ws+OFF_SHIFT+b*NC,
                                          nullptr, ws+OFF_SCR);
    // depthwise 3x3 + channel stats
    dwconv_stats_k<<<CH3,256,0,stream>>>(ws+OFF_SCR, w_dw, ws+OFF_QKV,
                                         ws+OFF_SSUM, ws+OFF_SALT, ws+OFF_SSQ);
    // H = Im KA2 for this batch's 256 k-rows, 2 chunks of 128 rows (T/U reuse SCR)
    for (int ch = 0; ch < 2; ch++){
      fft1_k<<<dim3(256,2),256,0,stream>>>(ws+OFF_QKV + (size_t)256*HWSZ, ws,
                                           (float2*)(ws+OFF_SCR), ch*128);
      fft2_k<<<dim3(2,256),256,0,stream>>>(ws, (const float2*)(ws+OFF_SCR),
                                           (float2*)(ws+OFF_SCR+4194304));
      fft3_k<<<dim3(256,2),256,0,stream>>>(ws, (const float2*)(ws+OFF_SCR+4194304),
                                           ws+OFF_H, ch*16384);
    }
    pri_k<<<dim3(64,4),256,0,stream>>>(ws+OFF_QKV, ws+OFF_H, ws+OFF_PP, ws+OFF_RP);
    attn_build_k<<<4,256,0,stream>>>(ws, temperature, ws+OFF_ATTN);
    topk_k<<<256,64,0,stream>>>(ws+OFF_ATTN, attn_w, ws+OFF_ACOMB);
    av_k<<<dim3(256,4),256,0,stream>>>(ws+OFF_ACOMB, ws+OFF_QKV, ws+OFF_SCR);
    // out_b = w_out @ out_head_b + b_out
    gemm_k<<<dim3(256,4),256,0,stream>>>(w_out, ws+OFF_SCR, nullptr, nullptr,
                                         b_out, out + (size_t)b*NC*HWSZ);
  }
}

// Round 3
// 2481.728 us; speedup vs baseline: 1.2209x; 1.2209x over previous
//
#include <hip/hip_runtime.h>
#include <math.h>

#define NC 256
#define CH3 768
#define HWSZ 16384

typedef __attribute__((ext_vector_type(8))) short short8;
typedef __attribute__((ext_vector_type(4))) float f32x4;
typedef __attribute__((ext_vector_type(4))) int i32x4;

// float-element offsets into workspace
static const size_t OFF_TABD  = 0;          // 32768 f (16384 float2)
static const size_t OFF_TW1   = 32768;
static const size_t OFF_STAB  = 65536;
static const size_t OFF_TW2   = 98304;
static const size_t OFF_ETAB  = 131072;
static const size_t OFF_HM    = 163840;     // 64
static const size_t OFF_SCALE = 163904;     // 1024 (b,ch)
static const size_t OFF_SHIFT = 164928;     // 1024
static const size_t OFF_SSUM  = 165952;     // 768 (per-batch ch)
static const size_t OFF_SALT  = 166720;     // 768
static const size_t OFF_SSQ   = 167488;     // 768
static const size_t OFF_ATTN  = 168256;     // 16384
static const size_t OFF_ACOMB = 184640;     // 16384
static const size_t OFF_PP    = 201024;     // 64 splits * 4 heads * 4096
static const size_t OFF_RP    = 1249600;    // 1,048,576
static const size_t OFF_H     = 2298176;    // 128 u * 256 rows * 128 r = 4,194,304
static const size_t OFF_QKV   = 6492480;    // 768*16384 (per-batch, post-dw)
static const size_t OFF_SCR   = 19075392;   // 12,582,912 : pre-dw qkv -> T/U -> out_head
static const size_t OFF_GNP   = 31658304;   // 2048 (1024 float2 partials)

// ---------------- tables ----------------
__global__ __launch_bounds__(256) void init_tables_k(float* __restrict__ ws){
  int idx = blockIdx.x*256 + threadIdx.x;       // 0..16383
  float2* tabD = (float2*)(ws + OFF_TABD);
  float2* tw1  = (float2*)(ws + OFF_TW1);
  float2* stab = (float2*)(ws + OFF_STAB);
  float2* tw2  = (float2*)(ws + OFF_TW2);
  float2* etab = (float2*)(ws + OFF_ETAB);
  float*  hm   = ws + OFF_HM;
  const double P2 = 6.283185307179586476925286766559005;
  int m = idx >> 7, k = idx & 127;
  double a1 = P2 * (double)((m*k) & 127) / 128.0;
  tabD[idx] = make_float2((float)cos(a1), (float)(-sin(a1)));   // D[f0,a]=e^{-2pi i f0 a/128}
  double a2 = P2 * (double)(m*k) / 16384.0;
  tw1[idx]  = make_float2((float)cos(a2), (float)(-sin(a2)));   // e^{-2pi i f0 b2/16384}
  tw2[idx]  = make_float2((float)cos(a2), (float)( sin(a2)));   // e^{+2pi i f0 r/16384}
  etab[idx] = make_float2((float)cos(a1), (float)( sin(a1)));   // e^{+2pi i u f0/128}
  int d = (k - m) & 127;                                        // stab[b2*128+r] = S[(r-b2)%128]
  double sr = 0.0, si = 0.0;
  for (int f1 = 0; f1 < 64; f1++){
    double a3 = P2 * (double)((f1*d) & 127) / 128.0;
    sr += cos(a3); si += sin(a3);
  }
  stab[idx] = make_float2((float)sr, (float)si);
  if (idx < 64){
    double acc = 0.0;
    for (int v = 1; v < 32; v++) acc += sin(P2 * (double)((v*idx) & 63) / 64.0);
    hm[idx] = (float)(-acc / 32.0);
  }
}

// ---------------- groupnorm stats, pass 1: per-channel partials (1024 blocks) ----------------
__global__ __launch_bounds__(256) void gn_part_k(const float* __restrict__ x, float2* __restrict__ part){
  int id = blockIdx.x;                      // b*256 + ch  (ch = g*8+s)
  const float4* p = (const float4*)(x + (size_t)id*HWSZ);
  int tid = threadIdx.x;
  float s = 0.f, sq = 0.f;
  #pragma unroll
  for (int i = 0; i < 16; i++){
    float4 v = p[tid + i*256];
    s  += v.x+v.y+v.z+v.w;
    sq += v.x*v.x+v.y*v.y+v.z*v.z+v.w*v.w;
  }
  __shared__ float r1[256], r2[256];
  r1[tid]=s; r2[tid]=sq; __syncthreads();
  for (int off=128; off; off>>=1){
    if (tid<off){ r1[tid]+=r1[tid+off]; r2[tid]+=r2[tid+off]; }
    __syncthreads();
  }
  if (tid==0) part[id] = make_float2(r1[0], r2[0]);
}

// ---------------- groupnorm stats, pass 2: finalize scale/shift ----------------
__global__ __launch_bounds__(128) void gn_fin_k(const float2* __restrict__ part, const float* __restrict__ gw,
                                                const float* __restrict__ gb, float* __restrict__ scale,
                                                float* __restrict__ shift){
  int bg = threadIdx.x;                     // 0..127 : b*32+g
  int b = bg >> 5, g = bg & 31;
  float s = 0.f, sq = 0.f;
  #pragma unroll
  for (int i = 0; i < 8; i++){
    float2 v = part[b*NC + g*8 + i];
    s += v.x; sq += v.y;
  }
  const float n = 8.0f*HWSZ;
  float mu = s/n, var = sq/n - mu*mu;
  float rs = rsqrtf(var + 1e-5f);
  for (int i = 0; i < 8; i++){
    int ch = g*8 + i;
    float sc = rs * gw[ch];
    scale[b*NC + ch] = sc;
    shift[b*NC + ch] = gb[ch] - mu*sc;
  }
}

// ---------------- split-bf16 MFMA GEMM: C[M x 16384] = A[M x 256] * B[256 x 16384] ----------------
// optional per-k scale/shift on B (GN fusion), optional bias on rows.
// grid (128, M/128), block 256 (4 waves 2x2), tile 128x128, BK=32.
__device__ inline unsigned short b16rn(float x){
  unsigned u = __float_as_uint(x);
  return (unsigned short)((u + 0x7FFFu + ((u>>16)&1u)) >> 16);
}
__global__ __launch_bounds__(256) void gemm_mfma_k(const float* __restrict__ A, const float* __restrict__ B,
                                                   const float* __restrict__ scale, const float* __restrict__ shift,
                                                   const float* __restrict__ bias, float* __restrict__ C){
  __shared__ unsigned int Ath[128][20], Atl[128][20], Bth[128][20], Btl[128][20];
  int tid = threadIdx.x;
  int lane = tid & 63, wid = tid >> 6;
  int m0 = blockIdx.y*128, n0 = blockIdx.x*128;
  int wr = (wid>>1)*64, wc = (wid&1)*64;
  int lr = lane & 15, lk = lane >> 4;
  f32x4 acc[4][4] = {};
  int bc = tid & 127, bg = tid >> 7;        // B staging: col, k-half
  for (int kt = 0; kt < 8; kt++){
    int k0 = kt*32;
    // stage A tile 128x32 (hi/lo packed per k-pair)
    #pragma unroll
    for (int i=0;i<4;i++){
      int id = tid + i*256;                  // 0..1023
      int r = id >> 3, q = id & 7;           // row, float4-quad (k=4q)
      float4 v = *(const float4*)&A[(size_t)(m0+r)*256 + k0 + 4*q];
      unsigned ux = __float_as_uint(v.x), uy = __float_as_uint(v.y);
      unsigned uz = __float_as_uint(v.z), uw = __float_as_uint(v.w);
      Ath[r][2*q]   = (ux>>16) | (uy & 0xFFFF0000u);
      Ath[r][2*q+1] = (uz>>16) | (uw & 0xFFFF0000u);
      float lx = v.x - __uint_as_float(ux & 0xFFFF0000u);
      float ly = v.y - __uint_as_float(uy & 0xFFFF0000u);
      float lz = v.z - __uint_as_float(uz & 0xFFFF0000u);
      float lw = v.w - __uint_as_float(uw & 0xFFFF0000u);
      Atl[r][2*q]   = (unsigned)b16rn(lx) | ((unsigned)b16rn(ly)<<16);
      Atl[r][2*q+1] = (unsigned)b16rn(lz) | ((unsigned)b16rn(lw)<<16);
    }
    // stage B tile 32x128 transposed (Bt[col][k]), hi/lo packed per k-pair
    #pragma unroll
    for (int p=0;p<8;p++){
      int kk = k0 + bg*16 + 2*p;
      float v0 = B[(size_t)kk*HWSZ + n0 + bc];
      float v1 = B[(size_t)(kk+1)*HWSZ + n0 + bc];
      if (scale){
        v0 = v0*scale[kk]   + shift[kk];
        v1 = v1*scale[kk+1] + shift[kk+1];
      }
      unsigned u0 = __float_as_uint(v0), u1 = __float_as_uint(v1);
      int kp = bg*8 + p;
      Bth[bc][kp] = (u0>>16) | (u1 & 0xFFFF0000u);
      float l0 = v0 - __uint_as_float(u0 & 0xFFFF0000u);
      float l1 = v1 - __uint_as_float(u1 & 0xFFFF0000u);
      Btl[bc][kp] = (unsigned)b16rn(l0) | ((unsigned)b16rn(l1)<<16);
    }
    __syncthreads();
    short8 ah[4], al[4], bh[4], bl[4];
    #pragma unroll
    for (int i=0;i<4;i++){
      ah[i] = *(const short8*)&Ath[wr + i*16 + lr][lk*4];
      al[i] = *(const short8*)&Atl[wr + i*16 + lr][lk*4];
    }
    #pragma unroll
    for (int j=0;j<4;j++){
      bh[j] = *(const short8*)&Bth[wc + j*16 + lr][lk*4];
      bl[j] = *(const short8*)&Btl[wc + j*16 + lr][lk*4];
    }
    #pragma unroll
    for (int i=0;i<4;i++)
      #pragma unroll
      for (int j=0;j<4;j++){
        acc[i][j] = __builtin_amdgcn_mfma_f32_16x16x32_bf16(ah[i], bh[j], acc[i][j], 0,0,0);
        acc[i][j] = __builtin_amdgcn_mfma_f32_16x16x32_bf16(ah[i], bl[j], acc[i][j], 0,0,0);
        acc[i][j] = __builtin_amdgcn_mfma_f32_16x16x32_bf16(al[i], bh[j], acc[i][j], 0,0,0);
      }
    __syncthreads();
  }
  #pragma unroll
  for (int i=0;i<4;i++){
    #pragma unroll
    for (int e=0;e<4;e++){
      int row = m0 + wr + i*16 + lk*4 + e;
      float bb = bias ? bias[row] : 0.0f;
      #pragma unroll
      for (int j=0;j<4;j++)
        C[(size_t)row*HWSZ + n0 + wc + j*16 + lr] = acc[i][j][e] + bb;
    }
  }
}

// ---------------- depthwise 3x3 + per-channel stats (one batch: 768 channels) ----------------
__global__ __launch_bounds__(256) void dwconv_stats_k(const float* __restrict__ qkv, const float* __restrict__ wdw,
                                                      float* __restrict__ outp, float* __restrict__ ssum,
                                                      float* __restrict__ salt, float* __restrict__ ssq){
  int ch = blockIdx.x;                 // 0..767
  const float* in = qkv + (size_t)ch * HWSZ;
  float w[9];
  #pragma unroll
  for (int i=0;i<9;i++) w[i] = wdw[ch*9+i];
  int tid = threadIdx.x;
  float s=0.f, sa=0.f, sq=0.f;
  for (int it=0; it<64; it++){
    int idx = it*256 + tid;
    int h = idx >> 7, xw = idx & 127;
    float acc = 0.f;
    #pragma unroll
    for (int ky=0; ky<3; ky++){
      int hh = h + ky - 1;
      if (hh < 0 || hh > 127) continue;
      #pragma unroll
      for (int kx=0; kx<3; kx++){
        int xx = xw + kx - 1;
        if (xx < 0 || xx > 127) continue;
        acc += in[hh*128 + xx] * w[ky*3+kx];
      }
    }
    outp[(size_t)ch*HWSZ + idx] = acc;
    s += acc; sa += (xw & 1) ? -acc : acc; sq += acc*acc;   // (-1)^s = (-1)^w since s=128h+w
  }
  __shared__ float r0[256], r1[256], r2[256];
  r0[tid]=s; r1[tid]=sa; r2[tid]=sq; __syncthreads();
  for (int off=128; off; off>>=1){
    if (tid<off){ r0[tid]+=r0[tid+off]; r1[tid]+=r1[tid+off]; r2[tid]+=r2[tid+off]; }
    __syncthreads();
  }
  if (tid==0){ ssum[ch]=r0[0]; salt[ch]=r1[0]; ssq[ch]=r2[0]; }
}

// ---------------- FFT stage 1: T'[f0][row][b2] = tw1 * sum_a D[f0,a] k[row][128a+b2] ----------------
// grid (256, 2): n = row_local*128+b2 (16384), m = f0 (128). chunk of 128 rows.
__global__ __launch_bounds__(256) void fft1_k(const float* __restrict__ Kb, const float* __restrict__ ws,
                                              float2* __restrict__ Tc, int rowBase){
  const float2* tabD = (const float2*)(ws + OFF_TABD);
  const float2* tw1  = (const float2*)(ws + OFF_TW1);
  int n0 = blockIdx.x*64, m0 = blockIdx.y*64;
  __shared__ float AsR[16][65], AsI[16][65], Bs[16][65];
  int tid=threadIdx.x, tx=tid&15, ty=tid>>4;
  float accR[4][4]={}, accI[4][4]={};
  for (int k0=0;k0<128;k0+=16){
    #pragma unroll
    for (int i=0;i<4;i++){ int id=tid+i*256; int k=id&15, mm=id>>4;
      float2 v = tabD[(m0+mm)*128 + k0+k]; AsR[k][mm]=v.x; AsI[k][mm]=v.y; }
    #pragma unroll
    for (int i=0;i<4;i++){ int id=tid+i*256; int nn=id&63, k=id>>6;
      int ng = n0+nn; int row = rowBase + (ng>>7);
      Bs[k][nn] = Kb[(size_t)row*HWSZ + (size_t)(k0+k)*128 + (ng&127)]; }
    __syncthreads();
    #pragma unroll
    for (int k=0;k<16;k++){
      float ar[4],ai[4],bv[4];
      #pragma unroll
      for (int i=0;i<4;i++){ ar[i]=AsR[k][ty*4+i]; ai[i]=AsI[k][ty*4+i]; }
      #pragma unroll
      for (int j=0;j<4;j++) bv[j]=Bs[k][tx*4+j];
      #pragma unroll
      for (int i=0;i<4;i++)
        #pragma unroll
        for (int j=0;j<4;j++){ accR[i][j] += ar[i]*bv[j]; accI[i][j] += ai[i]*bv[j]; }
    }
    __syncthreads();
  }
  #pragma unroll
  for (int i=0;i<4;i++)
    #pragma unroll
    for (int j=0;j<4;j++){
      int m = m0+ty*4+i, n = n0+tx*4+j;
      float2 t = tw1[m*128 + (n&127)];
      float r = accR[i][j], im = accI[i][j];
      Tc[(size_t)m*16384 + n] = make_float2(r*t.x - im*t.y, r*t.y + im*t.x);
    }
}

// ---------------- FFT stage 2: U'[f0][row][r] = tw2 * sum_b2 T'[f0,row,b2]*S[(r-b2)%128] ----------------
// grid (2, 256): n = r (128), m = f0*128+row_local (16384)
__global__ __launch_bounds__(256) void fft2_k(const float* __restrict__ ws, const float2* __restrict__ Tc,
                                              float2* __restrict__ U){
  const float2* stab = (const float2*)(ws + OFF_STAB);
  const float2* tw2  = (const float2*)(ws + OFF_TW2);
  int n0 = blockIdx.x*64, m0 = blockIdx.y*64;
  __shared__ float AsR[16][65], AsI[16][65], BsR[16][65], BsI[16][65];
  int tid=threadIdx.x, tx=tid&15, ty=tid>>4;
  float accR[4][4]={}, accI[4][4]={};
  for (int k0=0;k0<128;k0+=16){
    #pragma unroll
    for (int i=0;i<4;i++){ int id=tid+i*256; int k=id&15, mm=id>>4;
      float2 v = Tc[(size_t)(m0+mm)*128 + k0+k]; AsR[k][mm]=v.x; AsI[k][mm]=v.y; }
    #pragma unroll
    for (int i=0;i<4;i++){ int id=tid+i*256; int nn=id&63, k=id>>6;
      float2 v = stab[(k0+k)*128 + n0+nn]; BsR[k][nn]=v.x; BsI[k][nn]=v.y; }
    __syncthreads();
    #pragma unroll
    for (int k=0;k<16;k++){
      float ar[4],ai[4],br[4],bi[4];
      #pragma unroll
      for (int i=0;i<4;i++){ ar[i]=AsR[k][ty*4+i]; ai[i]=AsI[k][ty*4+i]; }
      #pragma unroll
      for (int j=0;j<4;j++){ br[j]=BsR[k][tx*4+j]; bi[j]=BsI[k][tx*4+j]; }
      #pragma unroll
      for (int i=0;i<4;i++)
        #pragma unroll
        for (int j=0;j<4;j++){
          accR[i][j] += ar[i]*br[j] - ai[i]*bi[j];
          accI[i][j] += ar[i]*bi[j] + ai[i]*br[j];
        }
    }
    __syncthreads();
  }
  #pragma unroll
  for (int i=0;i<4;i++)
    #pragma unroll
    for (int j=0;j<4;j++){
      int m = m0+ty*4+i, n = n0+tx*4+j;
      float2 t = tw2[((m>>7)<<7) + n];
      float r = accR[i][j], im = accI[i][j];
      U[(size_t)m*128 + n] = make_float2(r*t.x - im*t.y, r*t.y + im*t.x);
    }
}

// ---------------- FFT stage 3: H[u][rowBase+row][r] = Im sum_f0 E[u,f0]*U'[f0,row,r] ----------------
// grid (256, 2): n = row_local*128+r (16384), m = u (128)
__global__ __launch_bounds__(256) void fft3_k(const float* __restrict__ ws, const float2* __restrict__ U,
                                              float* __restrict__ Hb, int chunkBase){
  const float2* etab = (const float2*)(ws + OFF_ETAB);
  int n0 = blockIdx.x*64, m0 = blockIdx.y*64;
  __shared__ float AsR[16][65], AsI[16][65], BsR[16][65], BsI[16][65];
  int tid=threadIdx.x, tx=tid&15, ty=tid>>4;
  float acc[4][4]={};
  for (int k0=0;k0<128;k0+=16){
    #pragma unroll
    for (int i=0;i<4;i++){ int id=tid+i*256; int k=id&15, mm=id>>4;
      float2 v = etab[(m0+mm)*128 + k0+k]; AsR[k][mm]=v.x; AsI[k][mm]=v.y; }
    #pragma unroll
    for (int i=0;i<4;i++){ int id=tid+i*256; int nn=id&63, k=id>>6;
      float2 v = U[(size_t)(k0+k)*16384 + n0+nn]; BsR[k][nn]=v.x; BsI[k][nn]=v.y; }
    __syncthreads();
    #pragma unroll
    for (int k=0;k<16;k++){
      float ar[4],ai[4],br[4],bi[4];
      #pragma unroll
      for (int i=0;i<4;i++){ ar[i]=AsR[k][ty*4+i]; ai[i]=AsI[k][ty*4+i]; }
      #pragma unroll
      for (int j=0;j<4;j++){ br[j]=BsR[k][tx*4+j]; bi[j]=BsI[k][tx*4+j]; }
      #pragma unroll
      for (int i=0;i<4;i++)
        #pragma unroll
        for (int j=0;j<4;j++) acc[i][j] += ar[i]*bi[j] + ai[i]*br[j];
    }
    __syncthreads();
  }
  #pragma unroll
  for (int i=0;i<4;i++)
    #pragma unroll
    for (int j=0;j<4;j++)
      Hb[(size_t)(m0+ty*4+i)*32768 + chunkBase + n0+tx*4+j] = acc[i][j];
}

// ---------------- P & Ri split-K GEMMs (flip-addressed), one batch ----------------
// grid (64 splits, 4 heads)
__global__ __launch_bounds__(256) void pri_k(const float* __restrict__ qkvdw, const float* __restrict__ Hb,
                                             float* __restrict__ Pp, float* __restrict__ Rp){
  int sp = blockIdx.x, head = blockIdx.y;
  const float* Qb = qkvdw + (size_t)(head*64)*HWSZ;
  const float* Kb = qkvdw + (size_t)(256 + head*64)*HWSZ;
  int rowg0 = head*64;
  __shared__ float As[16][65], B1[16][65], B2[16][65];
  int tid=threadIdx.x, tx=tid&15, ty=tid>>4;
  float aP[4][4]={}, aR[4][4]={};
  for (int kc=0;kc<16;kc++){
    int s0 = sp*256 + kc*16;
    #pragma unroll
    for (int i=0;i<4;i++){ int id=tid+i*256; int kk=id&15, m=id>>4;
      As[kk][m] = Qb[(size_t)m*HWSZ + s0+kk]; }
    #pragma unroll
    for (int i=0;i<4;i++){ int id=tid+i*256; int kk=id&15, dd=id>>4;
      int t = (16384 - (s0+kk)) & 16383;
      B1[kk][dd] = Kb[(size_t)dd*HWSZ + t];
      int u = t>>7, r = t&127;
      B2[kk][dd] = Hb[(size_t)u*32768 + (size_t)(rowg0+dd)*128 + r]; }
    __syncthreads();
    #pragma unroll
    for (int k=0;k<16;k++){
      float a[4], b1[4], b2[4];
      #pragma unroll
      for (int i=0;i<4;i++) a[i]=As[k][ty*4+i];
      #pragma unroll
      for (int j=0;j<4;j++){ b1[j]=B1[k][tx*4+j]; b2[j]=B2[k][tx*4+j]; }
      #pragma unroll
      for (int i=0;i<4;i++)
        #pragma unroll
        for (int j=0;j<4;j++){ aP[i][j]+=a[i]*b1[j]; aR[i][j]+=a[i]*b2[j]; }
    }
    __syncthreads();
  }
  size_t base = ((size_t)(sp*4+head))<<12;
  #pragma unroll
  for (int i=0;i<4;i++)
    #pragma unroll
    for (int j=0;j<4;j++){
      size_t o = base + (size_t)(ty*4+i)*64 + tx*4+j;
      Pp[o]=aP[i][j]; Rp[o]=aR[i][j];
    }
}

// ---------------- attn build (one batch): reduce splits, rank-1 terms, norms, Hilbert mix ----------------
// grid 4 (heads)
__global__ __launch_bounds__(256) void attn_build_k(const float* __restrict__ ws, const float* __restrict__ temperature,
                                                    float* __restrict__ attn){
  const float* Pp   = ws + OFF_PP;
  const float* Rp   = ws + OFF_RP;
  const float* ssum = ws + OFF_SSUM;
  const float* salt = ws + OFF_SALT;
  const float* ssq  = ws + OFF_SSQ;
  const float* hmg  = ws + OFF_HM;
  __shared__ float Rn[64][65], Ril[64][65], hm[64];
  int head = blockIdx.x;
  int tid = threadIdx.x;
  if (tid < 64) hm[tid] = hmg[tid];
  for (int t=0;t<16;t++){
    int idx = tid + t*256; int c = idx>>6, d = idx&63;
    float P=0.f, Ri=0.f;
    for (int sp=0;sp<64;sp++){ size_t o = ((size_t)(sp*4+head)<<12) + idx; P += Pp[o]; Ri += Rp[o]; }
    int qch = head*64 + c;
    int kch = 256 + head*64 + d;
    float qs=ssum[qch], qa=salt[qch], qn=fmaxf(sqrtf(ssq[qch]), 1e-12f);
    float ks=ssum[kch], ka=salt[kch], kn=fmaxf(sqrtf(ssq[kch]), 1e-12f);
    float Rr = 0.5f*(16384.0f*P + qs*ks + qa*ka);
    float sc = 1.0f/(qn*kn);
    Rn[c][d]  = Rr*sc;
    Ril[c][d] = Ri*sc;
  }
  __syncthreads();
  float tmp2 = temperature[(head+2)&3];
  for (int t=0;t<16;t++){
    int idx = tid + t*256; int c = idx>>6, e = idx&63;
    float s = Rn[c][e];
    #pragma unroll 8
    for (int d=0; d<64; d++) s += Ril[c][d]*hm[(e-d)&63];
    attn[((size_t)head<<12) + (size_t)(c*64+e)] = s*tmp2;
  }
}

// ---------------- nested top-k masked softmax, combined over 4 branch weights ----------------
// grid 256 (head*64 + c)
__global__ __launch_bounds__(64) void topk_k(const float* __restrict__ attn, const float* __restrict__ attn_w,
                                             float* __restrict__ Acomb){
  int blk = blockIdx.x;
  int tid = threadIdx.x;
  __shared__ float row[64];
  float v = attn[(size_t)blk*64 + tid];
  row[tid] = v;
  __syncthreads();
  int rank = 0; float vmax = -1e30f;
  for (int l=0;l<64;l++){
    float w = row[l];
    if (w > v || (w == v && l < tid)) rank++;
    vmax = fmaxf(vmax, w);
  }
  float e = expf(v - vmax);
  const int kks[4] = {32,42,48,51};
  float denom[4];
  #pragma unroll
  for (int i=0;i<4;i++){
    float x = (rank < kks[i]) ? e : 0.0f;
    #pragma unroll
    for (int off=32; off; off>>=1) x += __shfl_xor(x, off);
    denom[i] = x;
  }
  float wgt = 0.f;
  #pragma unroll
  for (int i=0;i<4;i++) if (rank < kks[i]) wgt += attn_w[i] / denom[i];
  Acomb[(size_t)blk*64 + tid] = e * wgt;
}

// ---------------- out_head = A_comb @ v (one batch) ----------------
// grid (256, 4 heads)
__global__ __launch_bounds__(256) void av_k(const float* __restrict__ Acomb, const float* __restrict__ qkvdw,
                                            float* __restrict__ outh){
  int head = blockIdx.y;
  int n0 = blockIdx.x*64;
  const float* Vb = qkvdw + (size_t)(512 + head*64)*HWSZ;
  float* Op = outh + (size_t)(head*64)*HWSZ;
  __shared__ float As[64][65], Bs[16][65];
  int tid=threadIdx.x, tx=tid&15, ty=tid>>4;
  for (int t=0;t<16;t++){ int idx=tid+t*256; As[idx>>6][idx&63] = Acomb[((size_t)head<<12)+idx]; }
  __syncthreads();
  float acc[4][4]={};
  for (int k0=0;k0<64;k0+=16){
    #pragma unroll
    for (int i=0;i<4;i++){ int id=tid+i*256; int nn=id&63, k=id>>6;
      Bs[k][nn] = Vb[(size_t)(k0+k)*HWSZ + n0+nn]; }
    __syncthreads();
    #pragma unroll
    for (int k=0;k<16;k++){
      float a[4], bv[4];
      #pragma unroll
      for (int i=0;i<4;i++) a[i]=As[ty*4+i][k0+k];
      #pragma unroll
      for (int j=0;j<4;j++) bv[j]=Bs[k][tx*4+j];
      #pragma unroll
      for (int i=0;i<4;i++)
        #pragma unroll
        for (int j=0;j<4;j++) acc[i][j] += a[i]*bv[j];
    }
    __syncthreads();
  }
  #pragma unroll
  for (int i=0;i<4;i++)
    #pragma unroll
    for (int j=0;j<4;j++)
      Op[(size_t)(ty*4+i)*HWSZ + n0+tx*4+j] = acc[i][j];
}

extern "C" void kernel_launch(void* const* d_in, const int* in_sizes, int n_in,
                              void* d_out, int out_size, void* d_ws, size_t ws_size,
                              hipStream_t stream) {
  const float* x     = (const float*)d_in[0];
  const float* gn_w  = (const float*)d_in[1];
  const float* gn_b  = (const float*)d_in[2];
  const float* w_qkv = (const float*)d_in[3];
  const float* w_dw  = (const float*)d_in[4];
  const float* w_out = (const float*)d_in[5];
  const float* b_out = (const float*)d_in[6];
  const float* temperature = (const float*)d_in[7];
  const float* attn_w = (const float*)d_in[8];
  float* out = (float*)d_out;
  float* ws  = (float*)d_ws;

  init_tables_k<<<64,256,0,stream>>>(ws);
  gn_part_k<<<1024,256,0,stream>>>(x, (float2*)(ws+OFF_GNP));
  gn_fin_k<<<1,128,0,stream>>>((const float2*)(ws+OFF_GNP), gn_w, gn_b,
                               ws+OFF_SCALE, ws+OFF_SHIFT);

  for (int b = 0; b < 4; b++){
    const float* xb = x + (size_t)b*NC*HWSZ;
    // qkv = w_qkv @ groupnorm(x_b)   (GN fused into B-load), split-bf16 MFMA
    gemm_mfma_k<<<dim3(128,6),256,0,stream>>>(w_qkv, xb, ws+OFF_SCALE+b*NC, ws+OFF_SHIFT+b*NC,
                                              nullptr, ws+OFF_SCR);
    // depthwise 3x3 + channel stats
    dwconv_stats_k<<<CH3,256,0,stream>>>(ws+OFF_SCR, w_dw, ws+OFF_QKV,
                                         ws+OFF_SSUM, ws+OFF_SALT, ws+OFF_SSQ);
    // H = Im KA2 for this batch's 256 k-rows, 2 chunks of 128 rows (T/U reuse SCR)
    for (int ch = 0; ch < 2; ch++){
      fft1_k<<<dim3(256,2),256,0,stream>>>(ws+OFF_QKV + (size_t)256*HWSZ, ws,
                                           (float2*)(ws+OFF_SCR), ch*128);
      fft2_k<<<dim3(2,256),256,0,stream>>>(ws, (const float2*)(ws+OFF_SCR),
                                           (float2*)(ws+OFF_SCR+4194304));
      fft3_k<<<dim3(256,2),256,0,stream>>>(ws, (const float2*)(ws+OFF_SCR+4194304),
                                           ws+OFF_H, ch*16384);
    }
    pri_k<<<dim3(64,4),256,0,stream>>>(ws+OFF_QKV, ws+OFF_H, ws+OFF_PP, ws+OFF_RP);
    attn_build_k<<<4,256,0,stream>>>(ws, temperature, ws+OFF_ATTN);
    topk_k<<<256,64,0,stream>>>(ws+OFF_ATTN, attn_w, ws+OFF_ACOMB);
    av_k<<<dim3(256,4),256,0,stream>>>(ws+OFF_ACOMB, ws+OFF_QKV, ws+OFF_SCR);
    // out_b = w_out @ out_head_b + b_out
    gemm_mfma_k<<<dim3(128,2),256,0,stream>>>(w_out, ws+OFF_SCR, nullptr, nullptr,
                                              b_out, out + (size_t)b*NC*HWSZ);
  }
}

// Round 4
// 1388.628 us; speedup vs baseline: 2.1819x; 1.7872x over previous
//
#include <hip/hip_runtime.h>
#include <math.h>

#define NC 256
#define CH3 768
#define HWSZ 16384

typedef __attribute__((ext_vector_type(8))) short short8;
typedef __attribute__((ext_vector_type(4))) float f32x4;

// float-element offsets into workspace (total ~31.72M floats = 121.0 MiB)
static const size_t OFF_TW1   = 0;          // 32768 (16384 float2)
static const size_t OFF_TW2   = 32768;      // 32768
static const size_t OFF_HM    = 65536;      // 64
static const size_t OFF_SCALE = 65600;      // 1024
static const size_t OFF_SHIFT = 66624;      // 1024
static const size_t OFF_SSUM  = 67648;      // 768
static const size_t OFF_SALT  = 68416;      // 768
static const size_t OFF_SSQ   = 69184;      // 768
static const size_t OFF_DWP   = 69952;      // 9216 (3 x 3072)
static const size_t OFF_ATTN  = 79168;      // 16384
static const size_t OFF_ACOMB = 95552;      // 16384
static const size_t OFF_PS    = 111936;     // 16384
static const size_t OFF_RS    = 128320;     // 16384
static const size_t OFF_PACK  = 144704;     // 114688 u32 (packed bf16 tables)
static const size_t OFF_PP    = 259392;     // 1,048,576
static const size_t OFF_RP    = 1307968;    // 1,048,576
static const size_t OFF_H     = 2356544;    // 4,194,304
static const size_t OFF_QKV   = 6550848;    // 12,582,912 (per-batch post-dw)
static const size_t OFF_SCR   = 19133760;   // 12,582,912 (pre-dw qkv -> T/U -> out_head)
static const size_t OFF_GNP   = 31716672;   // 2048

// packed-plane u32 offsets (relative to OFF_PACK), each plane 128x64 u32
#define TDA_RH 0
#define TDA_RL 8192
#define TDA_IH 16384
#define TDA_IL 24576
#define ETA_RH 32768
#define ETA_RL 40960
#define ETA_IH 49152
#define ETA_IL 57344
#define STB_RH 65536
#define STB_RL 73728
#define STB_IH 81920
#define STB_IL 90112
#define STB_NIH 98304
#define STB_NIL 106496

__device__ inline unsigned short b16rn(float x){
  unsigned u = __float_as_uint(x);
  return (unsigned short)((u + 0x7FFFu + ((u>>16)&1u)) >> 16);
}
__device__ inline unsigned int pk_hi(float x, float y){
  return (__float_as_uint(x)>>16) | (__float_as_uint(y) & 0xFFFF0000u);
}
__device__ inline unsigned int pk_lo(float x, float y){
  float xl = x - __uint_as_float(__float_as_uint(x) & 0xFFFF0000u);
  float yl = y - __uint_as_float(__float_as_uint(y) & 0xFFFF0000u);
  return (unsigned)b16rn(xl) | ((unsigned)b16rn(yl)<<16);
}
__device__ inline short8 ld8g(const unsigned int* p){ return *(const short8*)p; }

// ---------------- tables: fp32 twiddles + pre-packed split-bf16 DFT matrices ----------------
__global__ __launch_bounds__(256) void init_tables_k(float* __restrict__ ws){
  int idx = blockIdx.x*256 + threadIdx.x;       // 0..16383
  float2* tw1 = (float2*)(ws + OFF_TW1);
  float2* tw2 = (float2*)(ws + OFF_TW2);
  unsigned int* pk = (unsigned int*)(ws + OFF_PACK);
  const double P2 = 6.283185307179586476925286766559005;
  int m = idx >> 7, k = idx & 127;
  double a2 = P2 * (double)(m*k) / 16384.0;
  tw1[idx] = make_float2((float)cos(a2), (float)(-sin(a2)));
  tw2[idx] = make_float2((float)cos(a2), (float)( sin(a2)));
  if (idx < 64){
    double acc = 0.0;
    for (int v = 1; v < 32; v++) acc += sin(P2 * (double)((v*idx) & 63) / 64.0);
    ws[OFF_HM + idx] = (float)(-acc / 32.0);
  }
  if (idx < 8192){
    int r = idx >> 6, kp = idx & 63;
    int k0 = 2*kp, k1 = 2*kp+1;
    double a0 = P2 * (double)((r*k0) & 127) / 128.0;
    double a1 = P2 * (double)((r*k1) & 127) / 128.0;
    float c0 = (float)cos(a0), c1 = (float)cos(a1);
    float s0 = (float)sin(a0), s1 = (float)sin(a1);
    // D = e^{-i..}: R=c, I=-s ; E = e^{+i..}: R=c, I=+s
    pk[TDA_RH + idx] = pk_hi(c0, c1);  pk[TDA_RL + idx] = pk_lo(c0, c1);
    pk[TDA_IH + idx] = pk_hi(-s0,-s1); pk[TDA_IL + idx] = pk_lo(-s0,-s1);
    pk[ETA_RH + idx] = pk_hi(c0, c1);  pk[ETA_RL + idx] = pk_lo(c0, c1);
    pk[ETA_IH + idx] = pk_hi(s0, s1);  pk[ETA_IL + idx] = pk_lo(s0, s1);
    // stab Bt layout: B[k][r] = S[(r-k)&127]; S[0]=64, S[even]=0, S[odd d]=1+i*cot(pi d/128)
    float sr0, si0, sr1, si1;
    {
      int d0 = (r - k0) & 127, d1 = (r - k1) & 127;
      if (d0 == 0){ sr0 = 64.f; si0 = 0.f; }
      else if ((d0 & 1) == 0){ sr0 = 0.f; si0 = 0.f; }
      else { double th = 3.1415926535897932384626 * (double)d0 / 128.0;
             sr0 = 1.f; si0 = (float)(cos(th)/sin(th)); }
      if (d1 == 0){ sr1 = 64.f; si1 = 0.f; }
      else if ((d1 & 1) == 0){ sr1 = 0.f; si1 = 0.f; }
      else { double th = 3.1415926535897932384626 * (double)d1 / 128.0;
             sr1 = 1.f; si1 = (float)(cos(th)/sin(th)); }
    }
    pk[STB_RH + idx]  = pk_hi(sr0, sr1);  pk[STB_RL + idx]  = pk_lo(sr0, sr1);
    pk[STB_IH + idx]  = pk_hi(si0, si1);  pk[STB_IL + idx]  = pk_lo(si0, si1);
    pk[STB_NIH + idx] = pk_hi(-si0,-si1); pk[STB_NIL + idx] = pk_lo(-si0,-si1);
  }
}

// ---------------- groupnorm stats ----------------
__global__ __launch_bounds__(256) void gn_part_k(const float* __restrict__ x, float2* __restrict__ part){
  int id = blockIdx.x;                      // b*256 + ch
  const float4* p = (const float4*)(x + (size_t)id*HWSZ);
  int tid = threadIdx.x;
  float s = 0.f, sq = 0.f;
  #pragma unroll
  for (int i = 0; i < 16; i++){
    float4 v = p[tid + i*256];
    s  += v.x+v.y+v.z+v.w;
    sq += v.x*v.x+v.y*v.y+v.z*v.z+v.w*v.w;
  }
  __shared__ float r1[256], r2[256];
  r1[tid]=s; r2[tid]=sq; __syncthreads();
  for (int off=128; off; off>>=1){
    if (tid<off){ r1[tid]+=r1[tid+off]; r2[tid]+=r2[tid+off]; }
    __syncthreads();
  }
  if (tid==0) part[id] = make_float2(r1[0], r2[0]);
}
__global__ __launch_bounds__(128) void gn_fin_k(const float2* __restrict__ part, const float* __restrict__ gw,
                                                const float* __restrict__ gb, float* __restrict__ scale,
                                                float* __restrict__ shift){
  int bg = threadIdx.x;                     // b*32+g
  int b = bg >> 5, g = bg & 31;
  float s = 0.f, sq = 0.f;
  #pragma unroll
  for (int i = 0; i < 8; i++){
    float2 v = part[b*NC + g*8 + i];
    s += v.x; sq += v.y;
  }
  const float n = 8.0f*HWSZ;
  float mu = s/n, var = sq/n - mu*mu;
  float rs = rsqrtf(var + 1e-5f);
  for (int i = 0; i < 8; i++){
    int ch = g*8 + i;
    float sc = rs * gw[ch];
    scale[b*NC + ch] = sc;
    shift[b*NC + ch] = gb[ch] - mu*sc;
  }
}

// ---------------- split-bf16 MFMA GEMM: C[M x 16384] = A[M x 256] * B[256 x 16384] ----------------
__global__ __launch_bounds__(256) void gemm_mfma_k(const float* __restrict__ A, const float* __restrict__ B,
                                                   const float* __restrict__ scale, const float* __restrict__ shift,
                                                   const float* __restrict__ bias, float* __restrict__ C){
  __shared__ unsigned int Ath[128][20], Atl[128][20], Bth[128][20], Btl[128][20];
  int tid = threadIdx.x;
  int lane = tid & 63, wid = tid >> 6;
  int m0 = blockIdx.y*128, n0 = blockIdx.x*128;
  int wr = (wid>>1)*64, wc = (wid&1)*64;
  int lr = lane & 15, lk = lane >> 4;
  f32x4 acc[4][4] = {};
  int bc = tid & 127, bg = tid >> 7;
  for (int kt = 0; kt < 8; kt++){
    int k0 = kt*32;
    #pragma unroll
    for (int i=0;i<4;i++){
      int id = tid + i*256;
      int r = id >> 3, q = id & 7;
      float4 v = *(const float4*)&A[(size_t)(m0+r)*256 + k0 + 4*q];
      Ath[r][2*q]   = pk_hi(v.x, v.y);
      Ath[r][2*q+1] = pk_hi(v.z, v.w);
      Atl[r][2*q]   = pk_lo(v.x, v.y);
      Atl[r][2*q+1] = pk_lo(v.z, v.w);
    }
    #pragma unroll
    for (int p=0;p<8;p++){
      int kk = k0 + bg*16 + 2*p;
      float v0 = B[(size_t)kk*HWSZ + n0 + bc];
      float v1 = B[(size_t)(kk+1)*HWSZ + n0 + bc];
      if (scale){
        v0 = v0*scale[kk]   + shift[kk];
        v1 = v1*scale[kk+1] + shift[kk+1];
      }
      int kp = bg*8 + p;
      Bth[bc][kp] = pk_hi(v0, v1);
      Btl[bc][kp] = pk_lo(v0, v1);
    }
    __syncthreads();
    short8 ah[4], al[4], bh[4], bl[4];
    #pragma unroll
    for (int i=0;i<4;i++){
      ah[i] = *(const short8*)&Ath[wr + i*16 + lr][lk*4];
      al[i] = *(const short8*)&Atl[wr + i*16 + lr][lk*4];
    }
    #pragma unroll
    for (int j=0;j<4;j++){
      bh[j] = *(const short8*)&Bth[wc + j*16 + lr][lk*4];
      bl[j] = *(const short8*)&Btl[wc + j*16 + lr][lk*4];
    }
    #pragma unroll
    for (int i=0;i<4;i++)
      #pragma unroll
      for (int j=0;j<4;j++){
        acc[i][j] = __builtin_amdgcn_mfma_f32_16x16x32_bf16(ah[i], bh[j], acc[i][j], 0,0,0);
        acc[i][j] = __builtin_amdgcn_mfma_f32_16x16x32_bf16(ah[i], bl[j], acc[i][j], 0,0,0);
        acc[i][j] = __builtin_amdgcn_mfma_f32_16x16x32_bf16(al[i], bh[j], acc[i][j], 0,0,0);
      }
    __syncthreads();
  }
  #pragma unroll
  for (int i=0;i<4;i++){
    #pragma unroll
    for (int e=0;e<4;e++){
      int row = m0 + wr + i*16 + lk*4 + e;
      float bb = bias ? bias[row] : 0.0f;
      #pragma unroll
      for (int j=0;j<4;j++)
        C[(size_t)row*HWSZ + n0 + wc + j*16 + lr] = acc[i][j][e] + bb;
    }
  }
}

// ---------------- depthwise 3x3, tiled (ch x 4 slices), LDS-staged, stat partials ----------------
__global__ __launch_bounds__(256) void dwconv_tiled_k(const float* __restrict__ qkv, const float* __restrict__ wdw,
                                                      float* __restrict__ outp, float* __restrict__ part){
  int blk = blockIdx.x;                 // ch*4 + slice
  int ch = blk >> 2, sl = blk & 3;
  int h0 = sl*32;
  const float* in = qkv + (size_t)ch*HWSZ;
  float w[9];
  #pragma unroll
  for (int i=0;i<9;i++) w[i] = wdw[ch*9+i];
  __shared__ float tile[34][132];
  __shared__ float r0[256], r1[256], r2[256];
  int tid = threadIdx.x;
  #pragma unroll
  for (int i = 0; i < 5; i++){
    int id = tid + i*256;
    if (id < 1088){
      int r = id >> 5, c4 = id & 31;
      int gh = h0 - 1 + r;
      float4 v = (gh >= 0 && gh < 128) ? *(const float4*)&in[gh*128 + c4*4]
                                       : make_float4(0.f,0.f,0.f,0.f);
      *(float4*)&tile[r][c4*4] = v;
    }
  }
  __syncthreads();
  float s=0.f, sa=0.f, sq=0.f;
  #pragma unroll
  for (int it=0; it<16; it++){
    int idx = it*256 + tid;
    int lh = idx >> 7, xw = idx & 127;
    float acc = 0.f;
    #pragma unroll
    for (int ky=0; ky<3; ky++){
      const float* tr = &tile[lh+ky][xw];
      if (xw > 0)   acc += tr[-1]*w[ky*3+0];
                    acc += tr[ 0]*w[ky*3+1];
      if (xw < 127) acc += tr[ 1]*w[ky*3+2];
    }
    outp[(size_t)ch*HWSZ + (h0+lh)*128 + xw] = acc;
    s += acc; sa += (xw & 1) ? -acc : acc; sq += acc*acc;
  }
  r0[tid]=s; r1[tid]=sa; r2[tid]=sq; __syncthreads();
  for (int off=128; off; off>>=1){
    if (tid<off){ r0[tid]+=r0[tid+off]; r1[tid]+=r1[tid+off]; r2[tid]+=r2[tid+off]; }
    __syncthreads();
  }
  if (tid==0){ part[blk]=r0[0]; part[3072+blk]=r1[0]; part[6144+blk]=r2[0]; }
}
__global__ __launch_bounds__(256) void dw_fin_k(const float* __restrict__ part, float* __restrict__ ssum,
                                                float* __restrict__ salt, float* __restrict__ ssq){
  for (int ch = threadIdx.x; ch < CH3; ch += 256){
    float s=0.f, sa=0.f, sq=0.f;
    #pragma unroll
    for (int sl=0; sl<4; sl++){
      s  += part[ch*4+sl];
      sa += part[3072+ch*4+sl];
      sq += part[6144+ch*4+sl];
    }
    ssum[ch]=s; salt[ch]=sa; ssq[ch]=sq;
  }
}

// ---------------- FFT stage 1 (MFMA): T'[f0][row][b2] = tw1 * sum_a D[f0,a] k[row][128a+b2] ----------------
// grid 128 = row_local; K=128 over a.
__global__ __launch_bounds__(256) void fft1_mfma_k(const float* __restrict__ Kb, const float* __restrict__ ws,
                                                   float2* __restrict__ Tc, int rowBase){
  const unsigned int* PK = (const unsigned int*)(ws + OFF_PACK);
  const float2* tw1 = (const float2*)(ws + OFF_TW1);
  __shared__ unsigned int Bth[128][20], Btl[128][20];
  int tid = threadIdx.x;
  int lane = tid & 63, wid = tid >> 6;
  int wr = (wid>>1)*64, wc = (wid&1)*64;
  int lr = lane & 15, lk = lane >> 4;
  int row_local = blockIdx.x;
  const float* src = Kb + (size_t)(rowBase + row_local)*HWSZ;
  f32x4 aR[4][4] = {}, aI[4][4] = {};
  int bc = tid & 127, grp = tid >> 7;
  for (int kt = 0; kt < 4; kt++){
    #pragma unroll
    for (int p=0;p<8;p++){
      int kp = grp*8 + p;
      int a = kt*32 + 2*kp;
      float v0 = src[a*128 + bc], v1 = src[(a+1)*128 + bc];
      Bth[bc][kp] = pk_hi(v0, v1);
      Btl[bc][kp] = pk_lo(v0, v1);
    }
    __syncthreads();
    short8 bh[4], bl[4];
    #pragma unroll
    for (int j=0;j<4;j++){
      bh[j] = *(const short8*)&Bth[wc + j*16 + lr][lk*4];
      bl[j] = *(const short8*)&Btl[wc + j*16 + lr][lk*4];
    }
    #pragma unroll
    for (int i=0;i<4;i++){
      int off = (wr + i*16 + lr)*64 + kt*16 + lk*4;
      short8 ahR = ld8g(PK + TDA_RH + off), alR = ld8g(PK + TDA_RL + off);
      short8 ahI = ld8g(PK + TDA_IH + off), alI = ld8g(PK + TDA_IL + off);
      #pragma unroll
      for (int j=0;j<4;j++){
        aR[i][j] = __builtin_amdgcn_mfma_f32_16x16x32_bf16(ahR, bh[j], aR[i][j], 0,0,0);
        aR[i][j] = __builtin_amdgcn_mfma_f32_16x16x32_bf16(ahR, bl[j], aR[i][j], 0,0,0);
        aR[i][j] = __builtin_amdgcn_mfma_f32_16x16x32_bf16(alR, bh[j], aR[i][j], 0,0,0);
        aI[i][j] = __builtin_amdgcn_mfma_f32_16x16x32_bf16(ahI, bh[j], aI[i][j], 0,0,0);
        aI[i][j] = __builtin_amdgcn_mfma_f32_16x16x32_bf16(ahI, bl[j], aI[i][j], 0,0,0);
        aI[i][j] = __builtin_amdgcn_mfma_f32_16x16x32_bf16(alI, bh[j], aI[i][j], 0,0,0);
      }
    }
    __syncthreads();
  }
  #pragma unroll
  for (int i=0;i<4;i++)
    #pragma unroll
    for (int e=0;e<4;e++){
      int m = wr + i*16 + lk*4 + e;
      #pragma unroll
      for (int j=0;j<4;j++){
        int col = wc + j*16 + lr;
        float2 t = tw1[m*128 + col];
        float r = aR[i][j][e], im = aI[i][j][e];
        Tc[(size_t)m*16384 + row_local*128 + col] = make_float2(r*t.x - im*t.y, r*t.y + im*t.x);
      }
    }
}

// ---------------- FFT stage 2 (MFMA): U'[f0,row][r] = tw2 * sum_b2 T'[f0,row,b2]*S[(r-b2)%128] ----------------
// grid 128 = m-tile over 16384 rows (f0*128+row); N=128.
__global__ __launch_bounds__(256) void fft2_mfma_k(const float* __restrict__ ws, const float2* __restrict__ Tc,
                                                   float2* __restrict__ U){
  const unsigned int* PK = (const unsigned int*)(ws + OFF_PACK);
  const float2* tw2 = (const float2*)(ws + OFF_TW2);
  __shared__ unsigned int ARh[128][20], ARl[128][20], AIh[128][20], AIl[128][20];
  int tid = threadIdx.x;
  int lane = tid & 63, wid = tid >> 6;
  int wr = (wid>>1)*64, wc = (wid&1)*64;
  int lr = lane & 15, lk = lane >> 4;
  int m0 = blockIdx.x*128;
  f32x4 aR[4][4] = {}, aI[4][4] = {};
  const float* Tf = (const float*)Tc;
  for (int kt = 0; kt < 4; kt++){
    #pragma unroll
    for (int s=0;s<8;s++){
      int id = tid + s*256;
      int r = id >> 4, kp = id & 15;
      int k = kt*32 + 2*kp;
      float4 v = *(const float4*)&Tf[((size_t)(m0+r)*128 + k)*2];   // R0 I0 R1 I1
      ARh[r][kp] = pk_hi(v.x, v.z); ARl[r][kp] = pk_lo(v.x, v.z);
      AIh[r][kp] = pk_hi(v.y, v.w); AIl[r][kp] = pk_lo(v.y, v.w);
    }
    __syncthreads();
    short8 ahR[4], alR[4], ahI[4], alI[4];
    #pragma unroll
    for (int i=0;i<4;i++){
      int ar = wr + i*16 + lr;
      ahR[i] = *(const short8*)&ARh[ar][lk*4];
      alR[i] = *(const short8*)&ARl[ar][lk*4];
      ahI[i] = *(const short8*)&AIh[ar][lk*4];
      alI[i] = *(const short8*)&AIl[ar][lk*4];
    }
    #pragma unroll
    for (int j=0;j<4;j++){
      int boff = (wc + j*16 + lr)*64 + kt*16 + lk*4;
      short8 bhR = ld8g(PK + STB_RH + boff), blR = ld8g(PK + STB_RL + boff);
      short8 bhI = ld8g(PK + STB_IH + boff), blI = ld8g(PK + STB_IL + boff);
      short8 bhN = ld8g(PK + STB_NIH + boff), blN = ld8g(PK + STB_NIL + boff);
      #pragma unroll
      for (int i=0;i<4;i++){
        aR[i][j] = __builtin_amdgcn_mfma_f32_16x16x32_bf16(ahR[i], bhR, aR[i][j], 0,0,0);
        aR[i][j] = __builtin_amdgcn_mfma_f32_16x16x32_bf16(ahR[i], blR, aR[i][j], 0,0,0);
        aR[i][j] = __builtin_amdgcn_mfma_f32_16x16x32_bf16(alR[i], bhR, aR[i][j], 0,0,0);
        aR[i][j] = __builtin_amdgcn_mfma_f32_16x16x32_bf16(ahI[i], bhN, aR[i][j], 0,0,0);
        aR[i][j] = __builtin_amdgcn_mfma_f32_16x16x32_bf16(ahI[i], blN, aR[i][j], 0,0,0);
        aR[i][j] = __builtin_amdgcn_mfma_f32_16x16x32_bf16(alI[i], bhN, aR[i][j], 0,0,0);
        aI[i][j] = __builtin_amdgcn_mfma_f32_16x16x32_bf16(ahR[i], bhI, aI[i][j], 0,0,0);
        aI[i][j] = __builtin_amdgcn_mfma_f32_16x16x32_bf16(ahR[i], blI, aI[i][j], 0,0,0);
        aI[i][j] = __builtin_amdgcn_mfma_f32_16x16x32_bf16(alR[i], bhI, aI[i][j], 0,0,0);
        aI[i][j] = __builtin_amdgcn_mfma_f32_16x16x32_bf16(ahI[i], bhR, aI[i][j], 0,0,0);
        aI[i][j] = __builtin_amdgcn_mfma_f32_16x16x32_bf16(ahI[i], blR, aI[i][j], 0,0,0);
        aI[i][j] = __builtin_amdgcn_mfma_f32_16x16x32_bf16(alI[i], bhR, aI[i][j], 0,0,0);
      }
    }
    __syncthreads();
  }
  #pragma unroll
  for (int i=0;i<4;i++)
    #pragma unroll
    for (int e=0;e<4;e++){
      int m = m0 + wr + i*16 + lk*4 + e;
      int f0 = m >> 7;
      #pragma unroll
      for (int j=0;j<4;j++){
        int col = wc + j*16 + lr;
        float2 t = tw2[f0*128 + col];
        float r = aR[i][j][e], im = aI[i][j][e];
        U[(size_t)m*128 + col] = make_float2(r*t.x - im*t.y, r*t.y + im*t.x);
      }
    }
}

// ---------------- FFT stage 3 (MFMA): H[u][chunk+row*128+r] = Im sum_f0 E[u,f0]*U'[f0, n] ----------------
// grid 128 = n-tile over 16384; M=128 (u).
__global__ __launch_bounds__(256) void fft3_mfma_k(const float* __restrict__ ws, const float2* __restrict__ U,
                                                   float* __restrict__ Hb, int chunkBase){
  const unsigned int* PK = (const unsigned int*)(ws + OFF_PACK);
  __shared__ unsigned int BRh[128][20], BRl[128][20], BIh[128][20], BIl[128][20];
  int tid = threadIdx.x;
  int lane = tid & 63, wid = tid >> 6;
  int wr = (wid>>1)*64, wc = (wid&1)*64;
  int lr = lane & 15, lk = lane >> 4;
  int n0 = blockIdx.x*128;
  f32x4 ac[4][4] = {};
  int bc = tid & 127, grp = tid >> 7;
  for (int kt = 0; kt < 4; kt++){
    #pragma unroll
    for (int p=0;p<8;p++){
      int kp = grp*8 + p;
      int k = kt*32 + 2*kp;
      float2 v0 = U[(size_t)k*16384 + n0 + bc];
      float2 v1 = U[(size_t)(k+1)*16384 + n0 + bc];
      BRh[bc][kp] = pk_hi(v0.x, v1.x); BRl[bc][kp] = pk_lo(v0.x, v1.x);
      BIh[bc][kp] = pk_hi(v0.y, v1.y); BIl[bc][kp] = pk_lo(v0.y, v1.y);
    }
    __syncthreads();
    short8 ahR[4], alR[4], ahI[4], alI[4];
    #pragma unroll
    for (int i=0;i<4;i++){
      int off = (wr + i*16 + lr)*64 + kt*16 + lk*4;
      ahR[i] = ld8g(PK + ETA_RH + off); alR[i] = ld8g(PK + ETA_RL + off);
      ahI[i] = ld8g(PK + ETA_IH + off); alI[i] = ld8g(PK + ETA_IL + off);
    }
    #pragma unroll
    for (int j=0;j<4;j++){
      int col = wc + j*16 + lr;
      short8 bhR = *(const short8*)&BRh[col][lk*4];
      short8 blR = *(const short8*)&BRl[col][lk*4];
      short8 bhI = *(const short8*)&BIh[col][lk*4];
      short8 blI = *(const short8*)&BIl[col][lk*4];
      #pragma unroll
      for (int i=0;i<4;i++){
        ac[i][j] = __builtin_amdgcn_mfma_f32_16x16x32_bf16(ahR[i], bhI, ac[i][j], 0,0,0);
        ac[i][j] = __builtin_amdgcn_mfma_f32_16x16x32_bf16(ahR[i], blI, ac[i][j], 0,0,0);
        ac[i][j] = __builtin_amdgcn_mfma_f32_16x16x32_bf16(alR[i], bhI, ac[i][j], 0,0,0);
        ac[i][j] = __builtin_amdgcn_mfma_f32_16x16x32_bf16(ahI[i], bhR, ac[i][j], 0,0,0);
        ac[i][j] = __builtin_amdgcn_mfma_f32_16x16x32_bf16(ahI[i], blR, ac[i][j], 0,0,0);
        ac[i][j] = __builtin_amdgcn_mfma_f32_16x16x32_bf16(alI[i], bhR, ac[i][j], 0,0,0);
      }
    }
    __syncthreads();
  }
  #pragma unroll
  for (int i=0;i<4;i++)
    #pragma unroll
    for (int e=0;e<4;e++){
      int m = wr + i*16 + lk*4 + e;
      #pragma unroll
      for (int j=0;j<4;j++)
        Hb[(size_t)m*32768 + chunkBase + n0 + wc + j*16 + lr] = ac[i][j][e];
    }
}

// ---------------- P & Ri split-K GEMMs (flip-addressed), one batch ----------------
__global__ __launch_bounds__(256) void pri_k(const float* __restrict__ qkvdw, const float* __restrict__ Hb,
                                             float* __restrict__ Pp, float* __restrict__ Rp){
  int sp = blockIdx.x, head = blockIdx.y;
  const float* Qb = qkvdw + (size_t)(head*64)*HWSZ;
  const float* Kb = qkvdw + (size_t)(256 + head*64)*HWSZ;
  int rowg0 = head*64;
  __shared__ float As[16][65], B1[16][65], B2[16][65];
  int tid=threadIdx.x, tx=tid&15, ty=tid>>4;
  float aP[4][4]={}, aR[4][4]={};
  for (int kc=0;kc<16;kc++){
    int s0 = sp*256 + kc*16;
    #pragma unroll
    for (int i=0;i<4;i++){ int id=tid+i*256; int kk=id&15, m=id>>4;
      As[kk][m] = Qb[(size_t)m*HWSZ + s0+kk]; }
    #pragma unroll
    for (int i=0;i<4;i++){ int id=tid+i*256; int kk=id&15, dd=id>>4;
      int t = (16384 - (s0+kk)) & 16383;
      B1[kk][dd] = Kb[(size_t)dd*HWSZ + t];
      int u = t>>7, r = t&127;
      B2[kk][dd] = Hb[(size_t)u*32768 + (size_t)(rowg0+dd)*128 + r]; }
    __syncthreads();
    #pragma unroll
    for (int k=0;k<16;k++){
      float a[4], b1[4], b2[4];
      #pragma unroll
      for (int i=0;i<4;i++) a[i]=As[k][ty*4+i];
      #pragma unroll
      for (int j=0;j<4;j++){ b1[j]=B1[k][tx*4+j]; b2[j]=B2[k][tx*4+j]; }
      #pragma unroll
      for (int i=0;i<4;i++)
        #pragma unroll
        for (int j=0;j<4;j++){ aP[i][j]+=a[i]*b1[j]; aR[i][j]+=a[i]*b2[j]; }
    }
    __syncthreads();
  }
  size_t base = ((size_t)(sp*4+head))<<12;
  #pragma unroll
  for (int i=0;i<4;i++)
    #pragma unroll
    for (int j=0;j<4;j++){
      size_t o = base + (size_t)(ty*4+i)*64 + tx*4+j;
      Pp[o]=aP[i][j]; Rp[o]=aR[i][j];
    }
}

// ---------------- split reduce of P/Ri partials ----------------
__global__ __launch_bounds__(256) void red_k(const float* __restrict__ ws, float* __restrict__ Ps,
                                             float* __restrict__ Rs){
  const float* Pp = ws + OFF_PP;
  const float* Rp = ws + OFF_RP;
  int tid = threadIdx.x;
  #pragma unroll
  for (int rep=0; rep<2; rep++){
    int g = blockIdx.x*512 + rep*256 + tid;
    int head = g >> 12, loc = g & 4095;
    float p = 0.f, ri = 0.f;
    for (int sp=0; sp<64; sp++){
      size_t o = ((size_t)(sp*4+head)<<12) + loc;
      p += Pp[o]; ri += Rp[o];
    }
    Ps[g] = p; Rs[g] = ri;
  }
}

// ---------------- attn build: rank-1 terms, norms, Hilbert mix, temperature ----------------
__global__ __launch_bounds__(256) void attn_build_k(const float* __restrict__ ws, const float* __restrict__ temperature,
                                                    float* __restrict__ attn){
  const float* Ps   = ws + OFF_PS;
  const float* Rs   = ws + OFF_RS;
  const float* ssum = ws + OFF_SSUM;
  const float* salt = ws + OFF_SALT;
  const float* ssq  = ws + OFF_SSQ;
  const float* hmg  = ws + OFF_HM;
  __shared__ float Rn[64][65], Ril[64][65], hm[64];
  int head = blockIdx.x;
  int tid = threadIdx.x;
  if (tid < 64) hm[tid] = hmg[tid];
  for (int t=0;t<16;t++){
    int idx = tid + t*256; int c = idx>>6, d = idx&63;
    float P = Ps[head*4096 + idx], Ri = Rs[head*4096 + idx];
    int qch = head*64 + c;
    int kch = 256 + head*64 + d;
    float qs=ssum[qch], qa=salt[qch], qn=fmaxf(sqrtf(ssq[qch]), 1e-12f);
    float ks=ssum[kch], ka=salt[kch], kn=fmaxf(sqrtf(ssq[kch]), 1e-12f);
    float Rr = 0.5f*(16384.0f*P + qs*ks + qa*ka);
    float sc = 1.0f/(qn*kn);
    Rn[c][d]  = Rr*sc;
    Ril[c][d] = Ri*sc;
  }
  __syncthreads();
  float tmp2 = temperature[(head+2)&3];
  for (int t=0;t<16;t++){
    int idx = tid + t*256; int c = idx>>6, e = idx&63;
    float s = Rn[c][e];
    #pragma unroll 8
    for (int d=0; d<64; d++) s += Ril[c][d]*hm[(e-d)&63];
    attn[((size_t)head<<12) + (size_t)(c*64+e)] = s*tmp2;
  }
}

// ---------------- nested top-k masked softmax, combined over 4 branch weights ----------------
__global__ __launch_bounds__(64) void topk_k(const float* __restrict__ attn, const float* __restrict__ attn_w,
                                             float* __restrict__ Acomb){
  int blk = blockIdx.x;
  int tid = threadIdx.x;
  __shared__ float row[64];
  float v = attn[(size_t)blk*64 + tid];
  row[tid] = v;
  __syncthreads();
  int rank = 0; float vmax = -1e30f;
  for (int l=0;l<64;l++){
    float w = row[l];
    if (w > v || (w == v && l < tid)) rank++;
    vmax = fmaxf(vmax, w);
  }
  float e = expf(v - vmax);
  const int kks[4] = {32,42,48,51};
  float denom[4];
  #pragma unroll
  for (int i=0;i<4;i++){
    float x = (rank < kks[i]) ? e : 0.0f;
    #pragma unroll
    for (int off=32; off; off>>=1) x += __shfl_xor(x, off);
    denom[i] = x;
  }
  float wgt = 0.f;
  #pragma unroll
  for (int i=0;i<4;i++) if (rank < kks[i]) wgt += attn_w[i] / denom[i];
  Acomb[(size_t)blk*64 + tid] = e * wgt;
}

// ---------------- out_head = A_comb @ v ----------------
__global__ __launch_bounds__(256) void av_k(const float* __restrict__ Acomb, const float* __restrict__ qkvdw,
                                            float* __restrict__ outh){
  int head = blockIdx.y;
  int n0 = blockIdx.x*64;
  const float* Vb = qkvdw + (size_t)(512 + head*64)*HWSZ;
  float* Op = outh + (size_t)(head*64)*HWSZ;
  __shared__ float As[64][65], Bs[16][65];
  int tid=threadIdx.x, tx=tid&15, ty=tid>>4;
  for (int t=0;t<16;t++){ int idx=tid+t*256; As[idx>>6][idx&63] = Acomb[((size_t)head<<12)+idx]; }
  __syncthreads();
  float acc[4][4]={};
  for (int k0=0;k0<64;k0+=16){
    #pragma unroll
    for (int i=0;i<4;i++){ int id=tid+i*256; int nn=id&63, k=id>>6;
      Bs[k][nn] = Vb[(size_t)(k0+k)*HWSZ + n0+nn]; }
    __syncthreads();
    #pragma unroll
    for (int k=0;k<16;k++){
      float a[4], bv[4];
      #pragma unroll
      for (int i=0;i<4;i++) a[i]=As[ty*4+i][k0+k];
      #pragma unroll
      for (int j=0;j<4;j++) bv[j]=Bs[k][tx*4+j];
      #pragma unroll
      for (int i=0;i<4;i++)
        #pragma unroll
        for (int j=0;j<4;j++) acc[i][j] += a[i]*bv[j];
    }
    __syncthreads();
  }
  #pragma unroll
  for (int i=0;i<4;i++)
    #pragma unroll
    for (int j=0;j<4;j++)
      Op[(size_t)(ty*4+i)*HWSZ + n0+tx*4+j] = acc[i][j];
}

extern "C" void kernel_launch(void* const* d_in, const int* in_sizes, int n_in,
                              void* d_out, int out_size, void* d_ws, size_t ws_size,
                              hipStream_t stream) {
  const float* x     = (const float*)d_in[0];
  const float* gn_w  = (const float*)d_in[1];
  const float* gn_b  = (const float*)d_in[2];
  const float* w_qkv = (const float*)d_in[3];
  const float* w_dw  = (const float*)d_in[4];
  const float* w_out = (const float*)d_in[5];
  const float* b_out = (const float*)d_in[6];
  const float* temperature = (const float*)d_in[7];
  const float* attn_w = (const float*)d_in[8];
  float* out = (float*)d_out;
  float* ws  = (float*)d_ws;

  init_tables_k<<<64,256,0,stream>>>(ws);
  gn_part_k<<<1024,256,0,stream>>>(x, (float2*)(ws+OFF_GNP));
  gn_fin_k<<<1,128,0,stream>>>((const float2*)(ws+OFF_GNP), gn_w, gn_b,
                               ws+OFF_SCALE, ws+OFF_SHIFT);

  for (int b = 0; b < 4; b++){
    const float* xb = x + (size_t)b*NC*HWSZ;
    gemm_mfma_k<<<dim3(128,6),256,0,stream>>>(w_qkv, xb, ws+OFF_SCALE+b*NC, ws+OFF_SHIFT+b*NC,
                                              nullptr, ws+OFF_SCR);
    dwconv_tiled_k<<<3072,256,0,stream>>>(ws+OFF_SCR, w_dw, ws+OFF_QKV, ws+OFF_DWP);
    dw_fin_k<<<1,256,0,stream>>>(ws+OFF_DWP, ws+OFF_SSUM, ws+OFF_SALT, ws+OFF_SSQ);
    for (int ch = 0; ch < 2; ch++){
      fft1_mfma_k<<<128,256,0,stream>>>(ws+OFF_QKV + (size_t)256*HWSZ, ws,
                                        (float2*)(ws+OFF_SCR), ch*128);
      fft2_mfma_k<<<128,256,0,stream>>>(ws, (const float2*)(ws+OFF_SCR),
                                        (float2*)(ws+OFF_SCR+4194304));
      fft3_mfma_k<<<128,256,0,stream>>>(ws, (const float2*)(ws+OFF_SCR+4194304),
                                        ws+OFF_H, ch*16384);
    }
    pri_k<<<dim3(64,4),256,0,stream>>>(ws+OFF_QKV, ws+OFF_H, ws+OFF_PP, ws+OFF_RP);
    red_k<<<32,256,0,stream>>>(ws, ws+OFF_PS, ws+OFF_RS);
    attn_build_k<<<4,256,0,stream>>>(ws, temperature, ws+OFF_ATTN);
    topk_k<<<256,64,0,stream>>>(ws+OFF_ATTN, attn_w, ws+OFF_ACOMB);
    av_k<<<dim3(256,4),256,0,stream>>>(ws+OFF_ACOMB, ws+OFF_QKV, ws+OFF_SCR);
    gemm_mfma_k<<<dim3(128,2),256,0,stream>>>(w_out, ws+OFF_SCR, nullptr, nullptr,
                                              b_out, out + (size_t)b*NC*HWSZ);
  }
}

// Round 5
// 1103.006 us; speedup vs baseline: 2.7469x; 1.2589x over previous
//
#include <hip/hip_runtime.h>
#include <math.h>

#define NC 256
#define CH3 768
#define HWSZ 16384

typedef __attribute__((ext_vector_type(8))) short short8;
typedef __attribute__((ext_vector_type(4))) float f32x4;
typedef __attribute__((ext_vector_type(4))) unsigned int u32x4;

// float-element offsets into workspace (total ~31.98M floats = 122 MiB)
static const size_t OFF_TW1   = 0;          // 32768 (16384 float2)
static const size_t OFF_TW2   = 32768;      // 32768
static const size_t OFF_HM    = 65536;      // 64
static const size_t OFF_SCALE = 65600;      // 1024
static const size_t OFF_SHIFT = 66624;      // 1024
static const size_t OFF_SSUM  = 67648;      // 768
static const size_t OFF_SALT  = 68416;      // 768
static const size_t OFF_SSQ   = 69184;      // 768
static const size_t OFF_DWP   = 69952;      // 9216
static const size_t OFF_ATTN  = 79168;      // 16384
static const size_t OFF_ACOMB = 95552;      // 16384
static const size_t OFF_PS    = 111936;     // 16384
static const size_t OFF_RS    = 128320;     // 16384
static const size_t OFF_PACK  = 144704;     // 114688 u32 (DFT bf16 planes)
static const size_t OFF_AW    = 259392;     // 262144 u32 (packed weights)
static const size_t OFF_PP    = 521536;     // 1,048,576
static const size_t OFF_RP    = 1570112;    // 1,048,576
static const size_t OFF_H     = 2618688;    // 4,194,304 (packx Bq -> H f32 -> packed out_head)
static const size_t OFF_QKV   = 6812992;    // 12,582,912 (per-batch post-dw)
static const size_t OFF_SCR   = 19395904;   // 12,582,912 (pre-dw qkv -> T/U in-place)
static const size_t OFF_GNP   = 31978816;   // 2048

// DFT plane u32 offsets (relative to OFF_PACK), each plane 128x64 u32
#define TDA_RH 0
#define TDA_RL 8192
#define TDA_IH 16384
#define TDA_IL 24576
#define ETA_RH 32768
#define ETA_RL 40960
#define ETA_IH 49152
#define ETA_IL 57344
#define STB_RH 65536
#define STB_RL 73728
#define STB_IH 81920
#define STB_IL 90112
#define STB_NIH 98304
#define STB_NIL 106496

// packed-weight u32 offsets (relative to OFF_AW)
#define AWQ_H 0
#define AWQ_L 98304
#define AWO_H 196608
#define AWO_L 229376

__device__ inline unsigned short b16rn(float x){
  unsigned u = __float_as_uint(x);
  return (unsigned short)((u + 0x7FFFu + ((u>>16)&1u)) >> 16);
}
__device__ inline unsigned int pk_hi(float x, float y){
  return (__float_as_uint(x)>>16) | (__float_as_uint(y) & 0xFFFF0000u);
}
__device__ inline unsigned int pk_lo(float x, float y){
  float xl = x - __uint_as_float(__float_as_uint(x) & 0xFFFF0000u);
  float yl = y - __uint_as_float(__float_as_uint(y) & 0xFFFF0000u);
  return (unsigned)b16rn(xl) | ((unsigned)b16rn(yl)<<16);
}
__device__ inline short8 ld8g(const unsigned int* p){ return *(const short8*)p; }

// ---------------- tables ----------------
__global__ __launch_bounds__(256) void init_tables_k(float* __restrict__ ws){
  int idx = blockIdx.x*256 + threadIdx.x;       // 0..16383
  float2* tw1 = (float2*)(ws + OFF_TW1);
  float2* tw2 = (float2*)(ws + OFF_TW2);
  unsigned int* pk = (unsigned int*)(ws + OFF_PACK);
  const double P2 = 6.283185307179586476925286766559005;
  int m = idx >> 7, k = idx & 127;
  double a2 = P2 * (double)(m*k) / 16384.0;
  tw1[idx] = make_float2((float)cos(a2), (float)(-sin(a2)));
  tw2[idx] = make_float2((float)cos(a2), (float)( sin(a2)));
  if (idx < 64){
    double acc = 0.0;
    for (int v = 1; v < 32; v++) acc += sin(P2 * (double)((v*idx) & 63) / 64.0);
    ws[OFF_HM + idx] = (float)(-acc / 32.0);
  }
  if (idx < 8192){
    int r = idx >> 6, kp = idx & 63;
    int k0 = 2*kp, k1 = 2*kp+1;
    double a0 = P2 * (double)((r*k0) & 127) / 128.0;
    double a1 = P2 * (double)((r*k1) & 127) / 128.0;
    float c0 = (float)cos(a0), c1 = (float)cos(a1);
    float s0 = (float)sin(a0), s1 = (float)sin(a1);
    pk[TDA_RH + idx] = pk_hi(c0, c1);  pk[TDA_RL + idx] = pk_lo(c0, c1);
    pk[TDA_IH + idx] = pk_hi(-s0,-s1); pk[TDA_IL + idx] = pk_lo(-s0,-s1);
    pk[ETA_RH + idx] = pk_hi(c0, c1);  pk[ETA_RL + idx] = pk_lo(c0, c1);
    pk[ETA_IH + idx] = pk_hi(s0, s1);  pk[ETA_IL + idx] = pk_lo(s0, s1);
    float sr0, si0, sr1, si1;
    {
      int d0 = (r - k0) & 127, d1 = (r - k1) & 127;
      if (d0 == 0){ sr0 = 64.f; si0 = 0.f; }
      else if ((d0 & 1) == 0){ sr0 = 0.f; si0 = 0.f; }
      else { double th = 3.1415926535897932384626 * (double)d0 / 128.0;
             sr0 = 1.f; si0 = (float)(cos(th)/sin(th)); }
      if (d1 == 0){ sr1 = 64.f; si1 = 0.f; }
      else if ((d1 & 1) == 0){ sr1 = 0.f; si1 = 0.f; }
      else { double th = 3.1415926535897932384626 * (double)d1 / 128.0;
             sr1 = 1.f; si1 = (float)(cos(th)/sin(th)); }
    }
    pk[STB_RH + idx]  = pk_hi(sr0, sr1);  pk[STB_RL + idx]  = pk_lo(sr0, sr1);
    pk[STB_IH + idx]  = pk_hi(si0, si1);  pk[STB_IL + idx]  = pk_lo(si0, si1);
    pk[STB_NIH + idx] = pk_hi(-si0,-si1); pk[STB_NIL + idx] = pk_lo(-si0,-si1);
  }
}

// ---------------- pack weights (once): hi/lo bf16 pair planes [row][kp] ----------------
__global__ __launch_bounds__(256) void wpack_k(const float* __restrict__ wqkv, const float* __restrict__ wout,
                                               unsigned int* __restrict__ aw){
  int id = blockIdx.x*256 + threadIdx.x;     // 0..131071 : row(1024) x kp(128)
  int row = id >> 7, kp = id & 127;
  if (row < CH3){
    float v0 = wqkv[row*256 + 2*kp], v1 = wqkv[row*256 + 2*kp + 1];
    aw[AWQ_H + row*128 + kp] = pk_hi(v0, v1);
    aw[AWQ_L + row*128 + kp] = pk_lo(v0, v1);
  } else {
    int r2 = row - CH3;
    float v0 = wout[r2*256 + 2*kp], v1 = wout[r2*256 + 2*kp + 1];
    aw[AWO_H + r2*128 + kp] = pk_hi(v0, v1);
    aw[AWO_L + r2*128 + kp] = pk_lo(v0, v1);
  }
}

// ---------------- groupnorm stats ----------------
__global__ __launch_bounds__(256) void gn_part_k(const float* __restrict__ x, float2* __restrict__ part){
  int id = blockIdx.x;
  const float4* p = (const float4*)(x + (size_t)id*HWSZ);
  int tid = threadIdx.x;
  float s = 0.f, sq = 0.f;
  #pragma unroll
  for (int i = 0; i < 16; i++){
    float4 v = p[tid + i*256];
    s  += v.x+v.y+v.z+v.w;
    sq += v.x*v.x+v.y*v.y+v.z*v.z+v.w*v.w;
  }
  __shared__ float r1[256], r2[256];
  r1[tid]=s; r2[tid]=sq; __syncthreads();
  for (int off=128; off; off>>=1){
    if (tid<off){ r1[tid]+=r1[tid+off]; r2[tid]+=r2[tid+off]; }
    __syncthreads();
  }
  if (tid==0) part[id] = make_float2(r1[0], r2[0]);
}
__global__ __launch_bounds__(128) void gn_fin_k(const float2* __restrict__ part, const float* __restrict__ gw,
                                                const float* __restrict__ gb, float* __restrict__ scale,
                                                float* __restrict__ shift){
  int bg = threadIdx.x;
  int b = bg >> 5, g = bg & 31;
  float s = 0.f, sq = 0.f;
  #pragma unroll
  for (int i = 0; i < 8; i++){
    float2 v = part[b*NC + g*8 + i];
    s += v.x; sq += v.y;
  }
  const float n = 8.0f*HWSZ;
  float mu = s/n, var = sq/n - mu*mu;
  float rs = rsqrtf(var + 1e-5f);
  for (int i = 0; i < 8; i++){
    int ch = g*8 + i;
    float sc = rs * gw[ch];
    scale[b*NC + ch] = sc;
    shift[b*NC + ch] = gb[ch] - mu*sc;
  }
}

// ---------------- pack GN(x) into Bq planes: [kb(32)][n(16384)][q(4)] u32, hi & lo ----------------
// grid (64, 32): blockIdx.y = kb, n = blockIdx.x*256+tid
__global__ __launch_bounds__(256) void packx_k(const float* __restrict__ xb, const float* __restrict__ scale,
                                               const float* __restrict__ shift, unsigned int* __restrict__ BqH){
  unsigned int* BqL = BqH + 2097152;
  int kb = blockIdx.y;
  int n = blockIdx.x*256 + threadIdx.x;
  float v[8];
  #pragma unroll
  for (int c = 0; c < 8; c++){
    int ch = kb*8 + c;
    v[c] = xb[(size_t)ch*HWSZ + n]*scale[ch] + shift[ch];
  }
  u32x4 h, l;
  #pragma unroll
  for (int q = 0; q < 4; q++){
    h[q] = pk_hi(v[2*q], v[2*q+1]);
    l[q] = pk_lo(v[2*q], v[2*q+1]);
  }
  *(u32x4*)&BqH[((size_t)kb*HWSZ + n)*4] = h;
  *(u32x4*)&BqL[((size_t)kb*HWSZ + n)*4] = l;
}

// ---------------- LDS-free packed split-bf16 MFMA GEMM ----------------
// C[M x 16384] = A[M x 256] * B[256 x 16384]; A planes [row][kp], B planes [kb][n][q].
// grid (128, M/128), block 256 (4 waves 2x2).
__global__ __launch_bounds__(256) void gemm_pk(const unsigned int* __restrict__ Ah, const unsigned int* __restrict__ Al,
                                               const unsigned int* __restrict__ Bh, const unsigned int* __restrict__ Bl,
                                               const float* __restrict__ bias, float* __restrict__ C){
  int tid = threadIdx.x;
  int lane = tid & 63, wid = tid >> 6;
  int m0 = blockIdx.y*128, n0 = blockIdx.x*128;
  int wr = (wid>>1)*64, wc = (wid&1)*64;
  int lr = lane & 15, lk = lane >> 4;
  f32x4 acc[4][4] = {};
  #pragma unroll 1
  for (int kt = 0; kt < 8; kt++){
    short8 ah[4], al[4], bh[4], bl[4];
    #pragma unroll
    for (int i=0;i<4;i++){
      size_t o = (size_t)(m0 + wr + i*16 + lr)*128 + kt*16 + lk*4;
      ah[i] = ld8g(Ah + o);
      al[i] = ld8g(Al + o);
    }
    int kb = kt*4 + lk;
    #pragma unroll
    for (int j=0;j<4;j++){
      size_t o = ((size_t)kb*HWSZ + n0 + wc + j*16 + lr)*4;
      bh[j] = ld8g(Bh + o);
      bl[j] = ld8g(Bl + o);
    }
    #pragma unroll
    for (int i=0;i<4;i++)
      #pragma unroll
      for (int j=0;j<4;j++){
        acc[i][j] = __builtin_amdgcn_mfma_f32_16x16x32_bf16(ah[i], bh[j], acc[i][j], 0,0,0);
        acc[i][j] = __builtin_amdgcn_mfma_f32_16x16x32_bf16(ah[i], bl[j], acc[i][j], 0,0,0);
        acc[i][j] = __builtin_amdgcn_mfma_f32_16x16x32_bf16(al[i], bh[j], acc[i][j], 0,0,0);
      }
  }
  #pragma unroll
  for (int i=0;i<4;i++){
    #pragma unroll
    for (int e=0;e<4;e++){
      int row = m0 + wr + i*16 + lk*4 + e;
      float bb = bias ? bias[row] : 0.0f;
      #pragma unroll
      for (int j=0;j<4;j++)
        C[(size_t)row*HWSZ + n0 + wc + j*16 + lr] = acc[i][j][e] + bb;
    }
  }
}

// ---------------- depthwise 3x3, tiled, LDS-staged, stat partials ----------------
__global__ __launch_bounds__(256) void dwconv_tiled_k(const float* __restrict__ qkv, const float* __restrict__ wdw,
                                                      float* __restrict__ outp, float* __restrict__ part){
  int blk = blockIdx.x;
  int ch = blk >> 2, sl = blk & 3;
  int h0 = sl*32;
  const float* in = qkv + (size_t)ch*HWSZ;
  float w[9];
  #pragma unroll
  for (int i=0;i<9;i++) w[i] = wdw[ch*9+i];
  __shared__ float tile[34][132];
  __shared__ float r0[256], r1[256], r2[256];
  int tid = threadIdx.x;
  #pragma unroll
  for (int i = 0; i < 5; i++){
    int id = tid + i*256;
    if (id < 1088){
      int r = id >> 5, c4 = id & 31;
      int gh = h0 - 1 + r;
      float4 v = (gh >= 0 && gh < 128) ? *(const float4*)&in[gh*128 + c4*4]
                                       : make_float4(0.f,0.f,0.f,0.f);
      *(float4*)&tile[r][c4*4] = v;
    }
  }
  __syncthreads();
  float s=0.f, sa=0.f, sq=0.f;
  #pragma unroll
  for (int it=0; it<16; it++){
    int idx = it*256 + tid;
    int lh = idx >> 7, xw = idx & 127;
    float acc = 0.f;
    #pragma unroll
    for (int ky=0; ky<3; ky++){
      const float* tr = &tile[lh+ky][xw];
      if (xw > 0)   acc += tr[-1]*w[ky*3+0];
                    acc += tr[ 0]*w[ky*3+1];
      if (xw < 127) acc += tr[ 1]*w[ky*3+2];
    }
    outp[(size_t)ch*HWSZ + (h0+lh)*128 + xw] = acc;
    s += acc; sa += (xw & 1) ? -acc : acc; sq += acc*acc;
  }
  r0[tid]=s; r1[tid]=sa; r2[tid]=sq; __syncthreads();
  for (int off=128; off; off>>=1){
    if (tid<off){ r0[tid]+=r0[tid+off]; r1[tid]+=r1[tid+off]; r2[tid]+=r2[tid+off]; }
    __syncthreads();
  }
  if (tid==0){ part[blk]=r0[0]; part[3072+blk]=r1[0]; part[6144+blk]=r2[0]; }
}
__global__ __launch_bounds__(256) void dw_fin_k(const float* __restrict__ part, float* __restrict__ ssum,
                                                float* __restrict__ salt, float* __restrict__ ssq){
  for (int ch = threadIdx.x; ch < CH3; ch += 256){
    float s=0.f, sa=0.f, sq=0.f;
    #pragma unroll
    for (int sl=0; sl<4; sl++){
      s  += part[ch*4+sl];
      sa += part[3072+ch*4+sl];
      sq += part[6144+ch*4+sl];
    }
    ssum[ch]=s; salt[ch]=sa; ssq[ch]=sq;
  }
}

// ---------------- FFT stage 1 (MFMA, 256 rows): T'[f0][row][b2] ----------------
__global__ __launch_bounds__(256) void fft1_mfma_k(const float* __restrict__ Kb, const float* __restrict__ ws,
                                                   float2* __restrict__ Tc){
  const unsigned int* PK = (const unsigned int*)(ws + OFF_PACK);
  const float2* tw1 = (const float2*)(ws + OFF_TW1);
  __shared__ unsigned int Bth[128][20], Btl[128][20];
  int tid = threadIdx.x;
  int lane = tid & 63, wid = tid >> 6;
  int wr = (wid>>1)*64, wc = (wid&1)*64;
  int lr = lane & 15, lk = lane >> 4;
  int row = blockIdx.x;                 // 0..255
  const float* src = Kb + (size_t)row*HWSZ;
  f32x4 aR[4][4] = {}, aI[4][4] = {};
  int bc = tid & 127, grp = tid >> 7;
  for (int kt = 0; kt < 4; kt++){
    #pragma unroll
    for (int p=0;p<8;p++){
      int kp = grp*8 + p;
      int a = kt*32 + 2*kp;
      float v0 = src[a*128 + bc], v1 = src[(a+1)*128 + bc];
      Bth[bc][kp] = pk_hi(v0, v1);
      Btl[bc][kp] = pk_lo(v0, v1);
    }
    __syncthreads();
    short8 bh[4], bl[4];
    #pragma unroll
    for (int j=0;j<4;j++){
      bh[j] = *(const short8*)&Bth[wc + j*16 + lr][lk*4];
      bl[j] = *(const short8*)&Btl[wc + j*16 + lr][lk*4];
    }
    #pragma unroll
    for (int i=0;i<4;i++){
      int off = (wr + i*16 + lr)*64 + kt*16 + lk*4;
      short8 ahR = ld8g(PK + TDA_RH + off), alR = ld8g(PK + TDA_RL + off);
      short8 ahI = ld8g(PK + TDA_IH + off), alI = ld8g(PK + TDA_IL + off);
      #pragma unroll
      for (int j=0;j<4;j++){
        aR[i][j] = __builtin_amdgcn_mfma_f32_16x16x32_bf16(ahR, bh[j], aR[i][j], 0,0,0);
        aR[i][j] = __builtin_amdgcn_mfma_f32_16x16x32_bf16(ahR, bl[j], aR[i][j], 0,0,0);
        aR[i][j] = __builtin_amdgcn_mfma_f32_16x16x32_bf16(alR, bh[j], aR[i][j], 0,0,0);
        aI[i][j] = __builtin_amdgcn_mfma_f32_16x16x32_bf16(ahI, bh[j], aI[i][j], 0,0,0);
        aI[i][j] = __builtin_amdgcn_mfma_f32_16x16x32_bf16(ahI, bl[j], aI[i][j], 0,0,0);
        aI[i][j] = __builtin_amdgcn_mfma_f32_16x16x32_bf16(alI, bh[j], aI[i][j], 0,0,0);
      }
    }
    __syncthreads();
  }
  #pragma unroll
  for (int i=0;i<4;i++)
    #pragma unroll
    for (int e=0;e<4;e++){
      int m = wr + i*16 + lk*4 + e;     // f0
      #pragma unroll
      for (int j=0;j<4;j++){
        int col = wc + j*16 + lr;       // b2
        float2 t = tw1[m*128 + col];
        float r = aR[i][j][e], im = aI[i][j][e];
        Tc[(size_t)m*32768 + row*128 + col] = make_float2(r*t.x - im*t.y, r*t.y + im*t.x);
      }
    }
}

// ---------------- FFT stage 2 (MFMA, in-place U over T): grid 256 m-tiles ----------------
__global__ __launch_bounds__(256) void fft2_mfma_k(const float* __restrict__ ws, float2* __restrict__ TU){
  const unsigned int* PK = (const unsigned int*)(ws + OFF_PACK);
  const float2* tw2 = (const float2*)(ws + OFF_TW2);
  __shared__ unsigned int ARh[128][20], ARl[128][20], AIh[128][20], AIl[128][20];
  int tid = threadIdx.x;
  int lane = tid & 63, wid = tid >> 6;
  int wr = (wid>>1)*64, wc = (wid&1)*64;
  int lr = lane & 15, lk = lane >> 4;
  int m0 = blockIdx.x*128;              // m = f0*256+row, 0..32767
  f32x4 aR[4][4] = {}, aI[4][4] = {};
  const float* Tf = (const float*)TU;
  for (int kt = 0; kt < 4; kt++){
    #pragma unroll
    for (int s=0;s<8;s++){
      int id = tid + s*256;
      int r = id >> 4, kp = id & 15;
      int k = kt*32 + 2*kp;
      float4 v = *(const float4*)&Tf[((size_t)(m0+r)*128 + k)*2];
      ARh[r][kp] = pk_hi(v.x, v.z); ARl[r][kp] = pk_lo(v.x, v.z);
      AIh[r][kp] = pk_hi(v.y, v.w); AIl[r][kp] = pk_lo(v.y, v.w);
    }
    __syncthreads();
    short8 ahR[4], alR[4], ahI[4], alI[4];
    #pragma unroll
    for (int i=0;i<4;i++){
      int ar = wr + i*16 + lr;
      ahR[i] = *(const short8*)&ARh[ar][lk*4];
      alR[i] = *(const short8*)&ARl[ar][lk*4];
      ahI[i] = *(const short8*)&AIh[ar][lk*4];
      alI[i] = *(const short8*)&AIl[ar][lk*4];
    }
    #pragma unroll
    for (int j=0;j<4;j++){
      int boff = (wc + j*16 + lr)*64 + kt*16 + lk*4;
      short8 bhR = ld8g(PK + STB_RH + boff), blR = ld8g(PK + STB_RL + boff);
      short8 bhI = ld8g(PK + STB_IH + boff), blI = ld8g(PK + STB_IL + boff);
      short8 bhN = ld8g(PK + STB_NIH + boff), blN = ld8g(PK + STB_NIL + boff);
      #pragma unroll
      for (int i=0;i<4;i++){
        aR[i][j] = __builtin_amdgcn_mfma_f32_16x16x32_bf16(ahR[i], bhR, aR[i][j], 0,0,0);
        aR[i][j] = __builtin_amdgcn_mfma_f32_16x16x32_bf16(ahR[i], blR, aR[i][j], 0,0,0);
        aR[i][j] = __builtin_amdgcn_mfma_f32_16x16x32_bf16(alR[i], bhR, aR[i][j], 0,0,0);
        aR[i][j] = __builtin_amdgcn_mfma_f32_16x16x32_bf16(ahI[i], bhN, aR[i][j], 0,0,0);
        aR[i][j] = __builtin_amdgcn_mfma_f32_16x16x32_bf16(ahI[i], blN, aR[i][j], 0,0,0);
        aR[i][j] = __builtin_amdgcn_mfma_f32_16x16x32_bf16(alI[i], bhN, aR[i][j], 0,0,0);
        aI[i][j] = __builtin_amdgcn_mfma_f32_16x16x32_bf16(ahR[i], bhI, aI[i][j], 0,0,0);
        aI[i][j] = __builtin_amdgcn_mfma_f32_16x16x32_bf16(ahR[i], blI, aI[i][j], 0,0,0);
        aI[i][j] = __builtin_amdgcn_mfma_f32_16x16x32_bf16(alR[i], bhI, aI[i][j], 0,0,0);
        aI[i][j] = __builtin_amdgcn_mfma_f32_16x16x32_bf16(ahI[i], bhR, aI[i][j], 0,0,0);
        aI[i][j] = __builtin_amdgcn_mfma_f32_16x16x32_bf16(ahI[i], blR, aI[i][j], 0,0,0);
        aI[i][j] = __builtin_amdgcn_mfma_f32_16x16x32_bf16(alI[i], bhR, aI[i][j], 0,0,0);
      }
    }
    __syncthreads();
  }
  #pragma unroll
  for (int i=0;i<4;i++)
    #pragma unroll
    for (int e=0;e<4;e++){
      int m = m0 + wr + i*16 + lk*4 + e;
      int f0 = m >> 8;
      #pragma unroll
      for (int j=0;j<4;j++){
        int col = wc + j*16 + lr;
        float2 t = tw2[f0*128 + col];
        float r = aR[i][j][e], im = aI[i][j][e];
        TU[(size_t)m*128 + col] = make_float2(r*t.x - im*t.y, r*t.y + im*t.x);
      }
    }
}

// ---------------- FFT stage 3 (MFMA): H[u][row*128+r] = Im sum_f0 E[u,f0]*U'[f0,row,r] ----------------
__global__ __launch_bounds__(256) void fft3_mfma_k(const float* __restrict__ ws, const float2* __restrict__ U,
                                                   float* __restrict__ Hb){
  const unsigned int* PK = (const unsigned int*)(ws + OFF_PACK);
  __shared__ unsigned int BRh[128][20], BRl[128][20], BIh[128][20], BIl[128][20];
  int tid = threadIdx.x;
  int lane = tid & 63, wid = tid >> 6;
  int wr = (wid>>1)*64, wc = (wid&1)*64;
  int lr = lane & 15, lk = lane >> 4;
  int brow = blockIdx.x;                // 0..255 (spatial row block)
  f32x4 ac[4][4] = {};
  int bc = tid & 127, grp = tid >> 7;
  for (int kt = 0; kt < 4; kt++){
    #pragma unroll
    for (int p=0;p<8;p++){
      int kp = grp*8 + p;
      int k = kt*32 + 2*kp;             // f0 pair
      float2 v0 = U[((size_t)k*256 + brow)*128 + bc];
      float2 v1 = U[((size_t)(k+1)*256 + brow)*128 + bc];
      BRh[bc][kp] = pk_hi(v0.x, v1.x); BRl[bc][kp] = pk_lo(v0.x, v1.x);
      BIh[bc][kp] = pk_hi(v0.y, v1.y); BIl[bc][kp] = pk_lo(v0.y, v1.y);
    }
    __syncthreads();
    short8 ahR[4], alR[4], ahI[4], alI[4];
    #pragma unroll
    for (int i=0;i<4;i++){
      int off = (wr + i*16 + lr)*64 + kt*16 + lk*4;
      ahR[i] = ld8g(PK + ETA_RH + off); alR[i] = ld8g(PK + ETA_RL + off);
      ahI[i] = ld8g(PK + ETA_IH + off); alI[i] = ld8g(PK + ETA_IL + off);
    }
    #pragma unroll
    for (int j=0;j<4;j++){
      int col = wc + j*16 + lr;
      short8 bhR = *(const short8*)&BRh[col][lk*4];
      short8 blR = *(const short8*)&BRl[col][lk*4];
      short8 bhI = *(const short8*)&BIh[col][lk*4];
      short8 blI = *(const short8*)&BIl[col][lk*4];
      #pragma unroll
      for (int i=0;i<4;i++){
        ac[i][j] = __builtin_amdgcn_mfma_f32_16x16x32_bf16(ahR[i], bhI, ac[i][j], 0,0,0);
        ac[i][j] = __builtin_amdgcn_mfma_f32_16x16x32_bf16(ahR[i], blI, ac[i][j], 0,0,0);
        ac[i][j] = __builtin_amdgcn_mfma_f32_16x16x32_bf16(alR[i], bhI, ac[i][j], 0,0,0);
        ac[i][j] = __builtin_amdgcn_mfma_f32_16x16x32_bf16(ahI[i], bhR, ac[i][j], 0,0,0);
        ac[i][j] = __builtin_amdgcn_mfma_f32_16x16x32_bf16(ahI[i], blR, ac[i][j], 0,0,0);
        ac[i][j] = __builtin_amdgcn_mfma_f32_16x16x32_bf16(alI[i], bhR, ac[i][j], 0,0,0);
      }
    }
    __syncthreads();
  }
  #pragma unroll
  for (int i=0;i<4;i++)
    #pragma unroll
    for (int e=0;e<4;e++){
      int m = wr + i*16 + lk*4 + e;     // u
      #pragma unroll
      for (int j=0;j<4;j++)
        Hb[(size_t)m*32768 + brow*128 + wc + j*16 + lr] = ac[i][j][e];
    }
}

// ---------------- P & Ri split-K GEMMs (flip-addressed) ----------------
__global__ __launch_bounds__(256) void pri_k(const float* __restrict__ qkvdw, const float* __restrict__ Hb,
                                             float* __restrict__ Pp, float* __restrict__ Rp){
  int sp = blockIdx.x, head = blockIdx.y;
  const float* Qb = qkvdw + (size_t)(head*64)*HWSZ;
  const float* Kb = qkvdw + (size_t)(256 + head*64)*HWSZ;
  int rowg0 = head*64;
  __shared__ float As[16][65], B1[16][65], B2[16][65];
  int tid=threadIdx.x, tx=tid&15, ty=tid>>4;
  float aP[4][4]={}, aR[4][4]={};
  for (int kc=0;kc<16;kc++){
    int s0 = sp*256 + kc*16;
    #pragma unroll
    for (int i=0;i<4;i++){ int id=tid+i*256; int kk=id&15, m=id>>4;
      As[kk][m] = Qb[(size_t)m*HWSZ + s0+kk]; }
    #pragma unroll
    for (int i=0;i<4;i++){ int id=tid+i*256; int kk=id&15, dd=id>>4;
      int t = (16384 - (s0+kk)) & 16383;
      B1[kk][dd] = Kb[(size_t)dd*HWSZ + t];
      int u = t>>7, r = t&127;
      B2[kk][dd] = Hb[(size_t)u*32768 + (size_t)(rowg0+dd)*128 + r]; }
    __syncthreads();
    #pragma unroll
    for (int k=0;k<16;k++){
      float a[4], b1[4], b2[4];
      #pragma unroll
      for (int i=0;i<4;i++) a[i]=As[k][ty*4+i];
      #pragma unroll
      for (int j=0;j<4;j++){ b1[j]=B1[k][tx*4+j]; b2[j]=B2[k][tx*4+j]; }
      #pragma unroll
      for (int i=0;i<4;i++)
        #pragma unroll
        for (int j=0;j<4;j++){ aP[i][j]+=a[i]*b1[j]; aR[i][j]+=a[i]*b2[j]; }
    }
    __syncthreads();
  }
  size_t base = ((size_t)(sp*4+head))<<12;
  #pragma unroll
  for (int i=0;i<4;i++)
    #pragma unroll
    for (int j=0;j<4;j++){
      size_t o = base + (size_t)(ty*4+i)*64 + tx*4+j;
      Pp[o]=aP[i][j]; Rp[o]=aR[i][j];
    }
}

// ---------------- split reduce ----------------
__global__ __launch_bounds__(256) void red_k(const float* __restrict__ ws, float* __restrict__ Ps,
                                             float* __restrict__ Rs){
  const float* Pp = ws + OFF_PP;
  const float* Rp = ws + OFF_RP;
  int tid = threadIdx.x;
  #pragma unroll
  for (int rep=0; rep<2; rep++){
    int g = blockIdx.x*512 + rep*256 + tid;
    int head = g >> 12, loc = g & 4095;
    float p = 0.f, ri = 0.f;
    for (int sp=0; sp<64; sp++){
      size_t o = ((size_t)(sp*4+head)<<12) + loc;
      p += Pp[o]; ri += Rp[o];
    }
    Ps[g] = p; Rs[g] = ri;
  }
}

// ---------------- attn build ----------------
__global__ __launch_bounds__(256) void attn_build_k(const float* __restrict__ ws, const float* __restrict__ temperature,
                                                    float* __restrict__ attn){
  const float* Ps   = ws + OFF_PS;
  const float* Rs   = ws + OFF_RS;
  const float* ssum = ws + OFF_SSUM;
  const float* salt = ws + OFF_SALT;
  const float* ssq  = ws + OFF_SSQ;
  const float* hmg  = ws + OFF_HM;
  __shared__ float Rn[64][65], Ril[64][65], hm[64];
  int head = blockIdx.x;
  int tid = threadIdx.x;
  if (tid < 64) hm[tid] = hmg[tid];
  for (int t=0;t<16;t++){
    int idx = tid + t*256; int c = idx>>6, d = idx&63;
    float P = Ps[head*4096 + idx], Ri = Rs[head*4096 + idx];
    int qch = head*64 + c;
    int kch = 256 + head*64 + d;
    float qs=ssum[qch], qa=salt[qch], qn=fmaxf(sqrtf(ssq[qch]), 1e-12f);
    float ks=ssum[kch], ka=salt[kch], kn=fmaxf(sqrtf(ssq[kch]), 1e-12f);
    float Rr = 0.5f*(16384.0f*P + qs*ks + qa*ka);
    float sc = 1.0f/(qn*kn);
    Rn[c][d]  = Rr*sc;
    Ril[c][d] = Ri*sc;
  }
  __syncthreads();
  float tmp2 = temperature[(head+2)&3];
  for (int t=0;t<16;t++){
    int idx = tid + t*256; int c = idx>>6, e = idx&63;
    float s = Rn[c][e];
    #pragma unroll 8
    for (int d=0; d<64; d++) s += Ril[c][d]*hm[(e-d)&63];
    attn[((size_t)head<<12) + (size_t)(c*64+e)] = s*tmp2;
  }
}

// ---------------- nested top-k masked softmax ----------------
__global__ __launch_bounds__(64) void topk_k(const float* __restrict__ attn, const float* __restrict__ attn_w,
                                             float* __restrict__ Acomb){
  int blk = blockIdx.x;
  int tid = threadIdx.x;
  __shared__ float row[64];
  float v = attn[(size_t)blk*64 + tid];
  row[tid] = v;
  __syncthreads();
  int rank = 0; float vmax = -1e30f;
  for (int l=0;l<64;l++){
    float w = row[l];
    if (w > v || (w == v && l < tid)) rank++;
    vmax = fmaxf(vmax, w);
  }
  float e = expf(v - vmax);
  const int kks[4] = {32,42,48,51};
  float denom[4];
  #pragma unroll
  for (int i=0;i<4;i++){
    float x = (rank < kks[i]) ? e : 0.0f;
    #pragma unroll
    for (int off=32; off; off>>=1) x += __shfl_xor(x, off);
    denom[i] = x;
  }
  float wgt = 0.f;
  #pragma unroll
  for (int i=0;i<4;i++) if (rank < kks[i]) wgt += attn_w[i] / denom[i];
  Acomb[(size_t)blk*64 + tid] = e * wgt;
}

// ---------------- out_head = A_comb @ v, written as packed Bq planes ----------------
__global__ __launch_bounds__(256) void av_k(const float* __restrict__ Acomb, const float* __restrict__ qkvdw,
                                            unsigned int* __restrict__ BqH){
  unsigned int* BqL = BqH + 2097152;
  int head = blockIdx.y;
  int n0 = blockIdx.x*64;
  const float* Vb = qkvdw + (size_t)(512 + head*64)*HWSZ;
  __shared__ float As[64][65], Bs[16][65];
  int tid=threadIdx.x, tx=tid&15, ty=tid>>4;
  for (int t=0;t<16;t++){ int idx=tid+t*256; As[idx>>6][idx&63] = Acomb[((size_t)head<<12)+idx]; }
  __syncthreads();
  float acc[4][4]={};
  for (int k0=0;k0<64;k0+=16){
    #pragma unroll
    for (int i=0;i<4;i++){ int id=tid+i*256; int nn=id&63, k=id>>6;
      Bs[k][nn] = Vb[(size_t)(k0+k)*HWSZ + n0+nn]; }
    __syncthreads();
    #pragma unroll
    for (int k=0;k<16;k++){
      float a[4], bv[4];
      #pragma unroll
      for (int i=0;i<4;i++) a[i]=As[ty*4+i][k0+k];
      #pragma unroll
      for (int j=0;j<4;j++) bv[j]=Bs[k][tx*4+j];
      #pragma unroll
      for (int i=0;i<4;i++)
        #pragma unroll
        for (int j=0;j<4;j++) acc[i][j] += a[i]*bv[j];
    }
    __syncthreads();
  }
  // rows ty*4+0..3 are two channel-pairs: kp = head*32 + ty*2 + {0,1}
  int kpa = head*32 + ty*2;
  int kba = kpa >> 2, qa = kpa & 3;
  int kpb = kpa + 1;
  int kbb = kpb >> 2, qb = kpb & 3;
  #pragma unroll
  for (int j=0;j<4;j++){
    int n = n0 + tx*4 + j;
    BqH[((size_t)kba*HWSZ + n)*4 + qa] = pk_hi(acc[0][j], acc[1][j]);
    BqL[((size_t)kba*HWSZ + n)*4 + qa] = pk_lo(acc[0][j], acc[1][j]);
    BqH[((size_t)kbb*HWSZ + n)*4 + qb] = pk_hi(acc[2][j], acc[3][j]);
    BqL[((size_t)kbb*HWSZ + n)*4 + qb] = pk_lo(acc[2][j], acc[3][j]);
  }
}

extern "C" void kernel_launch(void* const* d_in, const int* in_sizes, int n_in,
                              void* d_out, int out_size, void* d_ws, size_t ws_size,
                              hipStream_t stream) {
  const float* x     = (const float*)d_in[0];
  const float* gn_w  = (const float*)d_in[1];
  const float* gn_b  = (const float*)d_in[2];
  const float* w_qkv = (const float*)d_in[3];
  const float* w_dw  = (const float*)d_in[4];
  const float* w_out = (const float*)d_in[5];
  const float* b_out = (const float*)d_in[6];
  const float* temperature = (const float*)d_in[7];
  const float* attn_w = (const float*)d_in[8];
  float* out = (float*)d_out;
  float* ws  = (float*)d_ws;
  unsigned int* AW = (unsigned int*)(ws + OFF_AW);
  unsigned int* Bq = (unsigned int*)(ws + OFF_H);

  init_tables_k<<<64,256,0,stream>>>(ws);
  wpack_k<<<512,256,0,stream>>>(w_qkv, w_out, AW);
  gn_part_k<<<1024,256,0,stream>>>(x, (float2*)(ws+OFF_GNP));
  gn_fin_k<<<1,128,0,stream>>>((const float2*)(ws+OFF_GNP), gn_w, gn_b,
                               ws+OFF_SCALE, ws+OFF_SHIFT);

  for (int b = 0; b < 4; b++){
    const float* xb = x + (size_t)b*NC*HWSZ;
    packx_k<<<dim3(64,32),256,0,stream>>>(xb, ws+OFF_SCALE+b*NC, ws+OFF_SHIFT+b*NC, Bq);
    gemm_pk<<<dim3(128,6),256,0,stream>>>(AW+AWQ_H, AW+AWQ_L, Bq, Bq+2097152,
                                          nullptr, ws+OFF_SCR);
    dwconv_tiled_k<<<3072,256,0,stream>>>(ws+OFF_SCR, w_dw, ws+OFF_QKV, ws+OFF_DWP);
    dw_fin_k<<<1,256,0,stream>>>(ws+OFF_DWP, ws+OFF_SSUM, ws+OFF_SALT, ws+OFF_SSQ);
    fft1_mfma_k<<<256,256,0,stream>>>(ws+OFF_QKV + (size_t)256*HWSZ, ws, (float2*)(ws+OFF_SCR));
    fft2_mfma_k<<<256,256,0,stream>>>(ws, (float2*)(ws+OFF_SCR));
    fft3_mfma_k<<<256,256,0,stream>>>(ws, (const float2*)(ws+OFF_SCR), ws+OFF_H);
    pri_k<<<dim3(64,4),256,0,stream>>>(ws+OFF_QKV, ws+OFF_H, ws+OFF_PP, ws+OFF_RP);
    red_k<<<32,256,0,stream>>>(ws, ws+OFF_PS, ws+OFF_RS);
    attn_build_k<<<4,256,0,stream>>>(ws, temperature, ws+OFF_ATTN);
    topk_k<<<256,64,0,stream>>>(ws+OFF_ATTN, attn_w, ws+OFF_ACOMB);
    av_k<<<dim3(256,4),256,0,stream>>>(ws+OFF_ACOMB, ws+OFF_QKV, Bq);
    gemm_pk<<<dim3(128,2),256,0,stream>>>(AW+AWO_H, AW+AWO_L, Bq, Bq+2097152,
                                          b_out, out + (size_t)b*NC*HWSZ);
  }
}

// Round 6
// 859.052 us; speedup vs baseline: 3.5270x; 1.2840x over previous
//
#include <hip/hip_runtime.h>
#include <math.h>

#define NC 256
#define CH3 768
#define HWSZ 16384

typedef __attribute__((ext_vector_type(8))) short short8;
typedef __attribute__((ext_vector_type(4))) float f32x4;
typedef __attribute__((ext_vector_type(4))) unsigned int u32x4;

// ---- shared (table) region: float-element offsets into ws ----
static const size_t OFF_TW1   = 0;          // 32768 (16384 float2)
static const size_t OFF_TW2   = 32768;      // 32768
static const size_t OFF_HM    = 65536;      // 64
static const size_t OFF_SCALE = 65600;      // 1024
static const size_t OFF_SHIFT = 66624;      // 1024
static const size_t OFF_PACK  = 67648;      // 114688 u32 (DFT bf16 planes)
static const size_t OFF_AW    = 182336;     // 262144 u32 (packed weights)
static const size_t OFF_GNP   = 444480;     // 2048
static const size_t SHARED_END= 446528;

// ---- per-batch region: float-element offsets relative to region base ----
static const size_t R_QKV  = 0;             // 12,582,912 (post-dw qkv fp32)
static const size_t R_SCR  = 12582912;      // 12,582,912 (pre-dw qkv -> T/U in-place)
static const size_t R_H    = 25165824;      // 4,194,304 (Bq packed -> H fp32 -> Bq2 packed)
static const size_t R_PP   = 29360128;      // 1,048,576
static const size_t R_RP   = 30408704;      // 1,048,576
static const size_t R_ATTN = 31457280;      // 16384
static const size_t R_ACOMB= 31473664;      // 16384
static const size_t R_PS   = 31490048;      // 16384
static const size_t R_RS   = 31506432;      // 16384
static const size_t R_DWP  = 31522816;      // 9216
static const size_t R_SSUM = 31532032;      // 768
static const size_t R_SALT = 31532800;      // 768
static const size_t R_SSQ  = 31533568;      // 768
static const size_t RSTRIDE= 31534336;

// DFT plane u32 offsets (relative to OFF_PACK), each plane 128x64 u32
#define TDA_RH 0
#define TDA_RL 8192
#define TDA_IH 16384
#define TDA_IL 24576
#define ETA_RH 32768
#define ETA_RL 40960
#define ETA_IH 49152
#define ETA_IL 57344
#define STB_RH 65536
#define STB_RL 73728
#define STB_IH 81920
#define STB_IL 90112
#define STB_NIH 98304
#define STB_NIL 106496

// packed-weight u32 offsets (relative to OFF_AW)
#define AWQ_H 0
#define AWQ_L 98304
#define AWO_H 196608
#define AWO_L 229376

__device__ inline unsigned short b16rn(float x){
  unsigned u = __float_as_uint(x);
  return (unsigned short)((u + 0x7FFFu + ((u>>16)&1u)) >> 16);
}
__device__ inline unsigned int pk_hi(float x, float y){
  return (__float_as_uint(x)>>16) | (__float_as_uint(y) & 0xFFFF0000u);
}
__device__ inline unsigned int pk_lo(float x, float y){
  float xl = x - __uint_as_float(__float_as_uint(x) & 0xFFFF0000u);
  float yl = y - __uint_as_float(__float_as_uint(y) & 0xFFFF0000u);
  return (unsigned)b16rn(xl) | ((unsigned)b16rn(yl)<<16);
}
__device__ inline short8 ld8g(const unsigned int* p){ return *(const short8*)p; }

// ---------------- tables ----------------
__global__ __launch_bounds__(256) void init_tables_k(float* __restrict__ ws){
  int idx = blockIdx.x*256 + threadIdx.x;       // 0..16383
  float2* tw1 = (float2*)(ws + OFF_TW1);
  float2* tw2 = (float2*)(ws + OFF_TW2);
  unsigned int* pk = (unsigned int*)(ws + OFF_PACK);
  const double P2 = 6.283185307179586476925286766559005;
  int m = idx >> 7, k = idx & 127;
  double a2 = P2 * (double)(m*k) / 16384.0;
  tw1[idx] = make_float2((float)cos(a2), (float)(-sin(a2)));
  tw2[idx] = make_float2((float)cos(a2), (float)( sin(a2)));
  if (idx < 64){
    double acc = 0.0;
    for (int v = 1; v < 32; v++) acc += sin(P2 * (double)((v*idx) & 63) / 64.0);
    ws[OFF_HM + idx] = (float)(-acc / 32.0);
  }
  if (idx < 8192){
    int r = idx >> 6, kp = idx & 63;
    int k0 = 2*kp, k1 = 2*kp+1;
    double a0 = P2 * (double)((r*k0) & 127) / 128.0;
    double a1 = P2 * (double)((r*k1) & 127) / 128.0;
    float c0 = (float)cos(a0), c1 = (float)cos(a1);
    float s0 = (float)sin(a0), s1 = (float)sin(a1);
    pk[TDA_RH + idx] = pk_hi(c0, c1);  pk[TDA_RL + idx] = pk_lo(c0, c1);
    pk[TDA_IH + idx] = pk_hi(-s0,-s1); pk[TDA_IL + idx] = pk_lo(-s0,-s1);
    pk[ETA_RH + idx] = pk_hi(c0, c1);  pk[ETA_RL + idx] = pk_lo(c0, c1);
    pk[ETA_IH + idx] = pk_hi(s0, s1);  pk[ETA_IL + idx] = pk_lo(s0, s1);
    float sr0, si0, sr1, si1;
    {
      int d0 = (r - k0) & 127, d1 = (r - k1) & 127;
      if (d0 == 0){ sr0 = 64.f; si0 = 0.f; }
      else if ((d0 & 1) == 0){ sr0 = 0.f; si0 = 0.f; }
      else { double th = 3.1415926535897932384626 * (double)d0 / 128.0;
             sr0 = 1.f; si0 = (float)(cos(th)/sin(th)); }
      if (d1 == 0){ sr1 = 64.f; si1 = 0.f; }
      else if ((d1 & 1) == 0){ sr1 = 0.f; si1 = 0.f; }
      else { double th = 3.1415926535897932384626 * (double)d1 / 128.0;
             sr1 = 1.f; si1 = (float)(cos(th)/sin(th)); }
    }
    pk[STB_RH + idx]  = pk_hi(sr0, sr1);  pk[STB_RL + idx]  = pk_lo(sr0, sr1);
    pk[STB_IH + idx]  = pk_hi(si0, si1);  pk[STB_IL + idx]  = pk_lo(si0, si1);
    pk[STB_NIH + idx] = pk_hi(-si0,-si1); pk[STB_NIL + idx] = pk_lo(-si0,-si1);
  }
}

// ---------------- pack weights (once) ----------------
__global__ __launch_bounds__(256) void wpack_k(const float* __restrict__ wqkv, const float* __restrict__ wout,
                                               unsigned int* __restrict__ aw){
  int id = blockIdx.x*256 + threadIdx.x;     // row(1024) x kp(128)
  int row = id >> 7, kp = id & 127;
  if (row < CH3){
    float v0 = wqkv[row*256 + 2*kp], v1 = wqkv[row*256 + 2*kp + 1];
    aw[AWQ_H + row*128 + kp] = pk_hi(v0, v1);
    aw[AWQ_L + row*128 + kp] = pk_lo(v0, v1);
  } else {
    int r2 = row - CH3;
    float v0 = wout[r2*256 + 2*kp], v1 = wout[r2*256 + 2*kp + 1];
    aw[AWO_H + r2*128 + kp] = pk_hi(v0, v1);
    aw[AWO_L + r2*128 + kp] = pk_lo(v0, v1);
  }
}

// ---------------- groupnorm stats ----------------
__global__ __launch_bounds__(256) void gn_part_k(const float* __restrict__ x, float2* __restrict__ part){
  int id = blockIdx.x;
  const float4* p = (const float4*)(x + (size_t)id*HWSZ);
  int tid = threadIdx.x;
  float s = 0.f, sq = 0.f;
  #pragma unroll
  for (int i = 0; i < 16; i++){
    float4 v = p[tid + i*256];
    s  += v.x+v.y+v.z+v.w;
    sq += v.x*v.x+v.y*v.y+v.z*v.z+v.w*v.w;
  }
  __shared__ float r1[256], r2[256];
  r1[tid]=s; r2[tid]=sq; __syncthreads();
  for (int off=128; off; off>>=1){
    if (tid<off){ r1[tid]+=r1[tid+off]; r2[tid]+=r2[tid+off]; }
    __syncthreads();
  }
  if (tid==0) part[id] = make_float2(r1[0], r2[0]);
}
__global__ __launch_bounds__(128) void gn_fin_k(const float2* __restrict__ part, const float* __restrict__ gw,
                                                const float* __restrict__ gb, float* __restrict__ scale,
                                                float* __restrict__ shift){
  int bg = threadIdx.x;
  int b = bg >> 5, g = bg & 31;
  float s = 0.f, sq = 0.f;
  #pragma unroll
  for (int i = 0; i < 8; i++){
    float2 v = part[b*NC + g*8 + i];
    s += v.x; sq += v.y;
  }
  const float n = 8.0f*HWSZ;
  float mu = s/n, var = sq/n - mu*mu;
  float rs = rsqrtf(var + 1e-5f);
  for (int i = 0; i < 8; i++){
    int ch = g*8 + i;
    float sc = rs * gw[ch];
    scale[b*NC + ch] = sc;
    shift[b*NC + ch] = gb[ch] - mu*sc;
  }
}

// ---------------- pack GN(x) into Bq planes [kb(32)][n(16384)][q(4)] ----------------
// grid (64, 32, zb)
__global__ __launch_bounds__(256) void packx_k(const float* __restrict__ xbase, const float* __restrict__ scale,
                                               const float* __restrict__ shift, float* __restrict__ R0,
                                               size_t rstride){
  int bz = blockIdx.z;
  const float* xb = xbase + (size_t)bz*NC*HWSZ;
  const float* sc = scale + bz*NC;
  const float* sh = shift + bz*NC;
  unsigned int* BqH = (unsigned int*)(R0 + (size_t)bz*rstride + R_H);
  unsigned int* BqL = BqH + 2097152;
  int kb = blockIdx.y;
  int n = blockIdx.x*256 + threadIdx.x;
  float v[8];
  #pragma unroll
  for (int c = 0; c < 8; c++){
    int ch = kb*8 + c;
    v[c] = xb[(size_t)ch*HWSZ + n]*sc[ch] + sh[ch];
  }
  u32x4 h, l;
  #pragma unroll
  for (int q = 0; q < 4; q++){
    h[q] = pk_hi(v[2*q], v[2*q+1]);
    l[q] = pk_lo(v[2*q], v[2*q+1]);
  }
  *(u32x4*)&BqH[((size_t)kb*HWSZ + n)*4] = h;
  *(u32x4*)&BqL[((size_t)kb*HWSZ + n)*4] = l;
}

// ---------------- LDS-free packed split-bf16 MFMA GEMM with register double-buffer ----------------
// grid (128, M/128, zb)
__global__ __launch_bounds__(256) void gemm_pk(const unsigned int* __restrict__ Ah, const unsigned int* __restrict__ Al,
                                               const unsigned int* __restrict__ Bh0, const unsigned int* __restrict__ Bl0,
                                               const float* __restrict__ bias, float* __restrict__ C0,
                                               size_t bstride, size_t cstride){
  const unsigned int* Bh = Bh0 + (size_t)blockIdx.z*bstride;
  const unsigned int* Bl = Bl0 + (size_t)blockIdx.z*bstride;
  float* C = C0 + (size_t)blockIdx.z*cstride;
  int tid = threadIdx.x;
  int lane = tid & 63, wid = tid >> 6;
  int m0 = blockIdx.y*128, n0 = blockIdx.x*128;
  int wr = (wid>>1)*64, wc = (wid&1)*64;
  int lr = lane & 15, lk = lane >> 4;
  f32x4 acc[4][4] = {};
  size_t aoff[4], boff[4];
  #pragma unroll
  for (int i=0;i<4;i++) aoff[i] = (size_t)(m0 + wr + i*16 + lr)*128 + lk*4;
  #pragma unroll
  for (int j=0;j<4;j++) boff[j] = ((size_t)lk*HWSZ + n0 + wc + j*16 + lr)*4;
  short8 aH[2][4], aL[2][4], bH[2][4], bL[2][4];
  #pragma unroll
  for (int i=0;i<4;i++){ aH[0][i] = ld8g(Ah + aoff[i]); aL[0][i] = ld8g(Al + aoff[i]); }
  #pragma unroll
  for (int j=0;j<4;j++){ bH[0][j] = ld8g(Bh + boff[j]); bL[0][j] = ld8g(Bl + boff[j]); }
  #pragma unroll
  for (int kt = 0; kt < 8; kt++){
    int cur = kt & 1, nxt = cur ^ 1;
    if (kt < 7){
      size_t da = (size_t)(kt+1)*16;
      size_t db = (size_t)(kt+1)*4*HWSZ*4;
      #pragma unroll
      for (int i=0;i<4;i++){ aH[nxt][i] = ld8g(Ah + aoff[i] + da); aL[nxt][i] = ld8g(Al + aoff[i] + da); }
      #pragma unroll
      for (int j=0;j<4;j++){ bH[nxt][j] = ld8g(Bh + boff[j] + db); bL[nxt][j] = ld8g(Bl + boff[j] + db); }
    }
    #pragma unroll
    for (int i=0;i<4;i++)
      #pragma unroll
      for (int j=0;j<4;j++){
        acc[i][j] = __builtin_amdgcn_mfma_f32_16x16x32_bf16(aH[cur][i], bH[cur][j], acc[i][j], 0,0,0);
        acc[i][j] = __builtin_amdgcn_mfma_f32_16x16x32_bf16(aH[cur][i], bL[cur][j], acc[i][j], 0,0,0);
        acc[i][j] = __builtin_amdgcn_mfma_f32_16x16x32_bf16(aL[cur][i], bH[cur][j], acc[i][j], 0,0,0);
      }
  }
  #pragma unroll
  for (int i=0;i<4;i++){
    #pragma unroll
    for (int e=0;e<4;e++){
      int row = m0 + wr + i*16 + lk*4 + e;
      float bb = bias ? bias[row] : 0.0f;
      #pragma unroll
      for (int j=0;j<4;j++)
        C[(size_t)row*HWSZ + n0 + wc + j*16 + lr] = acc[i][j][e] + bb;
    }
  }
}

// ---------------- depthwise 3x3, tiled, float4 in/out, stat partials ----------------
// grid (3072, zb)
__global__ __launch_bounds__(256) void dwconv_tiled_k(float* __restrict__ R0, size_t rstride,
                                                      const float* __restrict__ wdw){
  float* Rb = R0 + (size_t)blockIdx.y*rstride;
  int blk = blockIdx.x;
  int ch = blk >> 2, sl = blk & 3;
  int h0 = sl*32;
  const float* in = Rb + R_SCR + (size_t)ch*HWSZ;
  float* outp = Rb + R_QKV + (size_t)ch*HWSZ;
  float* part = Rb + R_DWP;
  float w[9];
  #pragma unroll
  for (int i=0;i<9;i++) w[i] = wdw[ch*9+i];
  __shared__ float tile[34][132];
  __shared__ float r0[256], r1[256], r2[256];
  int tid = threadIdx.x;
  #pragma unroll
  for (int i = 0; i < 5; i++){
    int id = tid + i*256;
    if (id < 1088){
      int r = id >> 5, c4 = id & 31;
      int gh = h0 - 1 + r;
      float4 v = (gh >= 0 && gh < 128) ? *(const float4*)&in[gh*128 + c4*4]
                                       : make_float4(0.f,0.f,0.f,0.f);
      *(float4*)&tile[r][c4*4] = v;
    }
  }
  __syncthreads();
  float s=0.f, sa=0.f, sq=0.f;
  #pragma unroll
  for (int it=0; it<4; it++){
    int idx = it*256 + tid;          // 0..1023
    int lh = idx >> 5;               // 0..31
    int xq = idx & 31;
    int xb4 = xq*4;
    float o[4];
    #pragma unroll
    for (int e=0;e<4;e++){
      int xw = xb4 + e;
      float acc = 0.f;
      #pragma unroll
      for (int ky=0; ky<3; ky++){
        const float* tr = &tile[lh+1+ky-1][xw];
        if (xw > 0)   acc += tr[-1]*w[ky*3+0];
                      acc += tr[ 0]*w[ky*3+1];
        if (xw < 127) acc += tr[ 1]*w[ky*3+2];
      }
      o[e] = acc;
      s += acc; sq += acc*acc;
      sa += (e & 1) ? -acc : acc;
    }
    *(float4*)&outp[(h0+lh)*128 + xb4] = make_float4(o[0],o[1],o[2],o[3]);
  }
  r0[tid]=s; r1[tid]=sa; r2[tid]=sq; __syncthreads();
  for (int off=128; off; off>>=1){
    if (tid<off){ r0[tid]+=r0[tid+off]; r1[tid]+=r1[tid+off]; r2[tid]+=r2[tid+off]; }
    __syncthreads();
  }
  if (tid==0){ part[blk]=r0[0]; part[3072+blk]=r1[0]; part[6144+blk]=r2[0]; }
}

// ---------------- FFT stage 1 (MFMA): grid (256, zb) ----------------
__global__ __launch_bounds__(256) void fft1_mfma_k(const float* __restrict__ ws, float* __restrict__ R0,
                                                   size_t rstride){
  float* Rb = R0 + (size_t)blockIdx.y*rstride;
  const float* Kb = Rb + R_QKV + (size_t)256*HWSZ;
  float2* Tc = (float2*)(Rb + R_SCR);
  const unsigned int* PK = (const unsigned int*)(ws + OFF_PACK);
  const float2* tw1 = (const float2*)(ws + OFF_TW1);
  __shared__ unsigned int Bth[128][20], Btl[128][20];
  int tid = threadIdx.x;
  int lane = tid & 63, wid = tid >> 6;
  int wr = (wid>>1)*64, wc = (wid&1)*64;
  int lr = lane & 15, lk = lane >> 4;
  int row = blockIdx.x;
  const float* src = Kb + (size_t)row*HWSZ;
  f32x4 aR[4][4] = {}, aI[4][4] = {};
  int bc = tid & 127, grp = tid >> 7;
  for (int kt = 0; kt < 4; kt++){
    #pragma unroll
    for (int p=0;p<8;p++){
      int kp = grp*8 + p;
      int a = kt*32 + 2*kp;
      float v0 = src[a*128 + bc], v1 = src[(a+1)*128 + bc];
      Bth[bc][kp] = pk_hi(v0, v1);
      Btl[bc][kp] = pk_lo(v0, v1);
    }
    __syncthreads();
    short8 bh[4], bl[4];
    #pragma unroll
    for (int j=0;j<4;j++){
      bh[j] = *(const short8*)&Bth[wc + j*16 + lr][lk*4];
      bl[j] = *(const short8*)&Btl[wc + j*16 + lr][lk*4];
    }
    #pragma unroll
    for (int i=0;i<4;i++){
      int off = (wr + i*16 + lr)*64 + kt*16 + lk*4;
      short8 ahR = ld8g(PK + TDA_RH + off), alR = ld8g(PK + TDA_RL + off);
      short8 ahI = ld8g(PK + TDA_IH + off), alI = ld8g(PK + TDA_IL + off);
      #pragma unroll
      for (int j=0;j<4;j++){
        aR[i][j] = __builtin_amdgcn_mfma_f32_16x16x32_bf16(ahR, bh[j], aR[i][j], 0,0,0);
        aR[i][j] = __builtin_amdgcn_mfma_f32_16x16x32_bf16(ahR, bl[j], aR[i][j], 0,0,0);
        aR[i][j] = __builtin_amdgcn_mfma_f32_16x16x32_bf16(alR, bh[j], aR[i][j], 0,0,0);
        aI[i][j] = __builtin_amdgcn_mfma_f32_16x16x32_bf16(ahI, bh[j], aI[i][j], 0,0,0);
        aI[i][j] = __builtin_amdgcn_mfma_f32_16x16x32_bf16(ahI, bl[j], aI[i][j], 0,0,0);
        aI[i][j] = __builtin_amdgcn_mfma_f32_16x16x32_bf16(alI, bh[j], aI[i][j], 0,0,0);
      }
    }
    __syncthreads();
  }
  #pragma unroll
  for (int i=0;i<4;i++)
    #pragma unroll
    for (int e=0;e<4;e++){
      int m = wr + i*16 + lk*4 + e;     // f0
      #pragma unroll
      for (int j=0;j<4;j++){
        int col = wc + j*16 + lr;       // b2
        float2 t = tw1[m*128 + col];
        float r = aR[i][j][e], im = aI[i][j][e];
        Tc[(size_t)m*32768 + row*128 + col] = make_float2(r*t.x - im*t.y, r*t.y + im*t.x);
      }
    }
}

// ---------------- FFT stage 2 (MFMA, in-place): grid (256, zb) ----------------
__global__ __launch_bounds__(256) void fft2_mfma_k(const float* __restrict__ ws, float* __restrict__ R0,
                                                   size_t rstride){
  float* Rb = R0 + (size_t)blockIdx.y*rstride;
  float2* TU = (float2*)(Rb + R_SCR);
  const unsigned int* PK = (const unsigned int*)(ws + OFF_PACK);
  const float2* tw2 = (const float2*)(ws + OFF_TW2);
  __shared__ unsigned int ARh[128][20], ARl[128][20], AIh[128][20], AIl[128][20];
  int tid = threadIdx.x;
  int lane = tid & 63, wid = tid >> 6;
  int wr = (wid>>1)*64, wc = (wid&1)*64;
  int lr = lane & 15, lk = lane >> 4;
  int m0 = blockIdx.x*128;
  f32x4 aR[4][4] = {}, aI[4][4] = {};
  const float* Tf = (const float*)TU;
  for (int kt = 0; kt < 4; kt++){
    #pragma unroll
    for (int s=0;s<8;s++){
      int id = tid + s*256;
      int r = id >> 4, kp = id & 15;
      int k = kt*32 + 2*kp;
      float4 v = *(const float4*)&Tf[((size_t)(m0+r)*128 + k)*2];
      ARh[r][kp] = pk_hi(v.x, v.z); ARl[r][kp] = pk_lo(v.x, v.z);
      AIh[r][kp] = pk_hi(v.y, v.w); AIl[r][kp] = pk_lo(v.y, v.w);
    }
    __syncthreads();
    short8 ahR[4], alR[4], ahI[4], alI[4];
    #pragma unroll
    for (int i=0;i<4;i++){
      int ar = wr + i*16 + lr;
      ahR[i] = *(const short8*)&ARh[ar][lk*4];
      alR[i] = *(const short8*)&ARl[ar][lk*4];
      ahI[i] = *(const short8*)&AIh[ar][lk*4];
      alI[i] = *(const short8*)&AIl[ar][lk*4];
    }
    #pragma unroll
    for (int j=0;j<4;j++){
      int boff = (wc + j*16 + lr)*64 + kt*16 + lk*4;
      short8 bhR = ld8g(PK + STB_RH + boff), blR = ld8g(PK + STB_RL + boff);
      short8 bhI = ld8g(PK + STB_IH + boff), blI = ld8g(PK + STB_IL + boff);
      short8 bhN = ld8g(PK + STB_NIH + boff), blN = ld8g(PK + STB_NIL + boff);
      #pragma unroll
      for (int i=0;i<4;i++){
        aR[i][j] = __builtin_amdgcn_mfma_f32_16x16x32_bf16(ahR[i], bhR, aR[i][j], 0,0,0);
        aR[i][j] = __builtin_amdgcn_mfma_f32_16x16x32_bf16(ahR[i], blR, aR[i][j], 0,0,0);
        aR[i][j] = __builtin_amdgcn_mfma_f32_16x16x32_bf16(alR[i], bhR, aR[i][j], 0,0,0);
        aR[i][j] = __builtin_amdgcn_mfma_f32_16x16x32_bf16(ahI[i], bhN, aR[i][j], 0,0,0);
        aR[i][j] = __builtin_amdgcn_mfma_f32_16x16x32_bf16(ahI[i], blN, aR[i][j], 0,0,0);
        aR[i][j] = __builtin_amdgcn_mfma_f32_16x16x32_bf16(alI[i], bhN, aR[i][j], 0,0,0);
        aI[i][j] = __builtin_amdgcn_mfma_f32_16x16x32_bf16(ahR[i], bhI, aI[i][j], 0,0,0);
        aI[i][j] = __builtin_amdgcn_mfma_f32_16x16x32_bf16(ahR[i], blI, aI[i][j], 0,0,0);
        aI[i][j] = __builtin_amdgcn_mfma_f32_16x16x32_bf16(alR[i], bhI, aI[i][j], 0,0,0);
        aI[i][j] = __builtin_amdgcn_mfma_f32_16x16x32_bf16(ahI[i], bhR, aI[i][j], 0,0,0);
        aI[i][j] = __builtin_amdgcn_mfma_f32_16x16x32_bf16(ahI[i], blR, aI[i][j], 0,0,0);
        aI[i][j] = __builtin_amdgcn_mfma_f32_16x16x32_bf16(alI[i], bhR, aI[i][j], 0,0,0);
      }
    }
    __syncthreads();
  }
  #pragma unroll
  for (int i=0;i<4;i++)
    #pragma unroll
    for (int e=0;e<4;e++){
      int m = m0 + wr + i*16 + lk*4 + e;
      int f0 = m >> 8;
      #pragma unroll
      for (int j=0;j<4;j++){
        int col = wc + j*16 + lr;
        float2 t = tw2[f0*128 + col];
        float r = aR[i][j][e], im = aI[i][j][e];
        TU[(size_t)m*128 + col] = make_float2(r*t.x - im*t.y, r*t.y + im*t.x);
      }
    }
}

// ---------------- FFT stage 3 (MFMA): grid (256, zb) ----------------
__global__ __launch_bounds__(256) void fft3_mfma_k(const float* __restrict__ ws, float* __restrict__ R0,
                                                   size_t rstride){
  float* Rb = R0 + (size_t)blockIdx.y*rstride;
  const float2* U = (const float2*)(Rb + R_SCR);
  float* Hb = Rb + R_H;
  const unsigned int* PK = (const unsigned int*)(ws + OFF_PACK);
  __shared__ unsigned int BRh[128][20], BRl[128][20], BIh[128][20], BIl[128][20];
  int tid = threadIdx.x;
  int lane = tid & 63, wid = tid >> 6;
  int wr = (wid>>1)*64, wc = (wid&1)*64;
  int lr = lane & 15, lk = lane >> 4;
  int brow = blockIdx.x;                // d row 0..255
  f32x4 ac[4][4] = {};
  int bc = tid & 127, grp = tid >> 7;
  for (int kt = 0; kt < 4; kt++){
    #pragma unroll
    for (int p=0;p<8;p++){
      int kp = grp*8 + p;
      int k = kt*32 + 2*kp;
      float2 v0 = U[((size_t)k*256 + brow)*128 + bc];
      float2 v1 = U[((size_t)(k+1)*256 + brow)*128 + bc];
      BRh[bc][kp] = pk_hi(v0.x, v1.x); BRl[bc][kp] = pk_lo(v0.x, v1.x);
      BIh[bc][kp] = pk_hi(v0.y, v1.y); BIl[bc][kp] = pk_lo(v0.y, v1.y);
    }
    __syncthreads();
    short8 ahR[4], alR[4], ahI[4], alI[4];
    #pragma unroll
    for (int i=0;i<4;i++){
      int off = (wr + i*16 + lr)*64 + kt*16 + lk*4;
      ahR[i] = ld8g(PK + ETA_RH + off); alR[i] = ld8g(PK + ETA_RL + off);
      ahI[i] = ld8g(PK + ETA_IH + off); alI[i] = ld8g(PK + ETA_IL + off);
    }
    #pragma unroll
    for (int j=0;j<4;j++){
      int col = wc + j*16 + lr;
      short8 bhR = *(const short8*)&BRh[col][lk*4];
      short8 blR = *(const short8*)&BRl[col][lk*4];
      short8 bhI = *(const short8*)&BIh[col][lk*4];
      short8 blI = *(const short8*)&BIl[col][lk*4];
      #pragma unroll
      for (int i=0;i<4;i++){
        ac[i][j] = __builtin_amdgcn_mfma_f32_16x16x32_bf16(ahR[i], bhI, ac[i][j], 0,0,0);
        ac[i][j] = __builtin_amdgcn_mfma_f32_16x16x32_bf16(ahR[i], blI, ac[i][j], 0,0,0);
        ac[i][j] = __builtin_amdgcn_mfma_f32_16x16x32_bf16(alR[i], bhI, ac[i][j], 0,0,0);
        ac[i][j] = __builtin_amdgcn_mfma_f32_16x16x32_bf16(ahI[i], bhR, ac[i][j], 0,0,0);
        ac[i][j] = __builtin_amdgcn_mfma_f32_16x16x32_bf16(ahI[i], blR, ac[i][j], 0,0,0);
        ac[i][j] = __builtin_amdgcn_mfma_f32_16x16x32_bf16(alI[i], bhR, ac[i][j], 0,0,0);
      }
    }
    __syncthreads();
  }
  #pragma unroll
  for (int i=0;i<4;i++)
    #pragma unroll
    for (int e=0;e<4;e++){
      int m = wr + i*16 + lk*4 + e;     // u
      #pragma unroll
      for (int j=0;j<4;j++)
        Hb[(size_t)m*32768 + brow*128 + wc + j*16 + lr] = ac[i][j][e];
    }
}

// ---------------- P & Ri split-K GEMMs (flip-addressed): grid (64, 4, zb) ----------------
__global__ __launch_bounds__(256) void pri_k(float* __restrict__ R0, size_t rstride){
  float* Rb = R0 + (size_t)blockIdx.z*rstride;
  const float* qkvdw = Rb + R_QKV;
  const float* Hb = Rb + R_H;
  float* Pp = Rb + R_PP;
  float* Rp = Rb + R_RP;
  int sp = blockIdx.x, head = blockIdx.y;
  const float* Qb = qkvdw + (size_t)(head*64)*HWSZ;
  const float* Kb = qkvdw + (size_t)(256 + head*64)*HWSZ;
  int rowg0 = head*64;
  __shared__ float As[16][65], B1[16][65], B2[16][65];
  int tid=threadIdx.x, tx=tid&15, ty=tid>>4;
  float aP[4][4]={}, aR[4][4]={};
  for (int kc=0;kc<16;kc++){
    int s0 = sp*256 + kc*16;
    #pragma unroll
    for (int i=0;i<4;i++){ int id=tid+i*256; int kk=id&15, m=id>>4;
      As[kk][m] = Qb[(size_t)m*HWSZ + s0+kk]; }
    #pragma unroll
    for (int i=0;i<4;i++){ int id=tid+i*256; int kk=id&15, dd=id>>4;
      int t = (16384 - (s0+kk)) & 16383;
      B1[kk][dd] = Kb[(size_t)dd*HWSZ + t];
      int u = t>>7, r = t&127;
      B2[kk][dd] = Hb[(size_t)u*32768 + (size_t)(rowg0+dd)*128 + r]; }
    __syncthreads();
    #pragma unroll
    for (int k=0;k<16;k++){
      float a[4], b1[4], b2[4];
      #pragma unroll
      for (int i=0;i<4;i++) a[i]=As[k][ty*4+i];
      #pragma unroll
      for (int j=0;j<4;j++){ b1[j]=B1[k][tx*4+j]; b2[j]=B2[k][tx*4+j]; }
      #pragma unroll
      for (int i=0;i<4;i++)
        #pragma unroll
        for (int j=0;j<4;j++){ aP[i][j]+=a[i]*b1[j]; aR[i][j]+=a[i]*b2[j]; }
    }
    __syncthreads();
  }
  size_t base = ((size_t)(sp*4+head))<<12;
  #pragma unroll
  for (int i=0;i<4;i++)
    #pragma unroll
    for (int j=0;j<4;j++){
      size_t o = base + (size_t)(ty*4+i)*64 + tx*4+j;
      Pp[o]=aP[i][j]; Rp[o]=aR[i][j];
    }
}

// ---------------- split reduce + dw stat fold: grid (32, zb) ----------------
__global__ __launch_bounds__(256) void red_k(float* __restrict__ R0, size_t rstride){
  float* Rb = R0 + (size_t)blockIdx.y*rstride;
  const float* Pp = Rb + R_PP;
  const float* Rp = Rb + R_RP;
  float* Ps = Rb + R_PS;
  float* Rs = Rb + R_RS;
  int tid = threadIdx.x;
  #pragma unroll
  for (int rep=0; rep<2; rep++){
    int g = blockIdx.x*512 + rep*256 + tid;
    int head = g >> 12, loc = g & 4095;
    float p = 0.f, ri = 0.f;
    for (int sp=0; sp<64; sp++){
      size_t o = ((size_t)(sp*4+head)<<12) + loc;
      p += Pp[o]; ri += Rp[o];
    }
    Ps[g] = p; Rs[g] = ri;
  }
  if (blockIdx.x == 0){
    const float* part = Rb + R_DWP;
    for (int ch = tid; ch < CH3; ch += 256){
      float s=0.f, sa=0.f, sq=0.f;
      #pragma unroll
      for (int sl=0; sl<4; sl++){
        s  += part[ch*4+sl];
        sa += part[3072+ch*4+sl];
        sq += part[6144+ch*4+sl];
      }
      Rb[R_SSUM+ch]=s; Rb[R_SALT+ch]=sa; Rb[R_SSQ+ch]=sq;
    }
  }
}

// ---------------- attn build: grid (4, zb) ----------------
__global__ __launch_bounds__(256) void attn_build_k(const float* __restrict__ ws, float* __restrict__ R0,
                                                    size_t rstride, const float* __restrict__ temperature){
  float* Rb = R0 + (size_t)blockIdx.y*rstride;
  const float* Ps   = Rb + R_PS;
  const float* Rs   = Rb + R_RS;
  const float* ssum = Rb + R_SSUM;
  const float* salt = Rb + R_SALT;
  const float* ssq  = Rb + R_SSQ;
  float* attn = Rb + R_ATTN;
  const float* hmg  = ws + OFF_HM;
  __shared__ float Rn[64][65], Ril[64][65], hm[64];
  int head = blockIdx.x;
  int tid = threadIdx.x;
  if (tid < 64) hm[tid] = hmg[tid];
  for (int t=0;t<16;t++){
    int idx = tid + t*256; int c = idx>>6, d = idx&63;
    float P = Ps[head*4096 + idx], Ri = Rs[head*4096 + idx];
    int qch = head*64 + c;
    int kch = 256 + head*64 + d;
    float qs=ssum[qch], qa=salt[qch], qn=fmaxf(sqrtf(ssq[qch]), 1e-12f);
    float ks=ssum[kch], ka=salt[kch], kn=fmaxf(sqrtf(ssq[kch]), 1e-12f);
    float Rr = 0.5f*(16384.0f*P + qs*ks + qa*ka);
    float sc = 1.0f/(qn*kn);
    Rn[c][d]  = Rr*sc;
    Ril[c][d] = Ri*sc;
  }
  __syncthreads();
  float tmp2 = temperature[(head+2)&3];
  for (int t=0;t<16;t++){
    int idx = tid + t*256; int c = idx>>6, e = idx&63;
    float s = Rn[c][e];
    #pragma unroll 8
    for (int d=0; d<64; d++) s += Ril[c][d]*hm[(e-d)&63];
    attn[((size_t)head<<12) + (size_t)(c*64+e)] = s*tmp2;
  }
}

// ---------------- nested top-k masked softmax: grid (256, zb) ----------------
__global__ __launch_bounds__(64) void topk_k(float* __restrict__ R0, size_t rstride,
                                             const float* __restrict__ attn_w){
  float* Rb = R0 + (size_t)blockIdx.y*rstride;
  const float* attn = Rb + R_ATTN;
  float* Acomb = Rb + R_ACOMB;
  int blk = blockIdx.x;
  int tid = threadIdx.x;
  __shared__ float row[64];
  float v = attn[(size_t)blk*64 + tid];
  row[tid] = v;
  __syncthreads();
  int rank = 0; float vmax = -1e30f;
  for (int l=0;l<64;l++){
    float w = row[l];
    if (w > v || (w == v && l < tid)) rank++;
    vmax = fmaxf(vmax, w);
  }
  float e = expf(v - vmax);
  const int kks[4] = {32,42,48,51};
  float denom[4];
  #pragma unroll
  for (int i=0;i<4;i++){
    float x = (rank < kks[i]) ? e : 0.0f;
    #pragma unroll
    for (int off=32; off; off>>=1) x += __shfl_xor(x, off);
    denom[i] = x;
  }
  float wgt = 0.f;
  #pragma unroll
  for (int i=0;i<4;i++) if (rank < kks[i]) wgt += attn_w[i] / denom[i];
  Acomb[(size_t)blk*64 + tid] = e * wgt;
}

// ---------------- out_head = A_comb @ v, packed output: grid (256, 4, zb) ----------------
__global__ __launch_bounds__(256) void av_k(float* __restrict__ R0, size_t rstride){
  float* Rb = R0 + (size_t)blockIdx.z*rstride;
  const float* Acomb = Rb + R_ACOMB;
  unsigned int* BqH = (unsigned int*)(Rb + R_H);
  unsigned int* BqL = BqH + 2097152;
  int head = blockIdx.y;
  int n0 = blockIdx.x*64;
  const float* Vb = Rb + R_QKV + (size_t)(512 + head*64)*HWSZ;
  __shared__ float As[64][65], Bs[16][65];
  int tid=threadIdx.x, tx=tid&15, ty=tid>>4;
  for (int t=0;t<16;t++){ int idx=tid+t*256; As[idx>>6][idx&63] = Acomb[((size_t)head<<12)+idx]; }
  __syncthreads();
  float acc[4][4]={};
  for (int k0=0;k0<64;k0+=16){
    #pragma unroll
    for (int i=0;i<4;i++){ int id=tid+i*256; int nn=id&63, k=id>>6;
      Bs[k][nn] = Vb[(size_t)(k0+k)*HWSZ + n0+nn]; }
    __syncthreads();
    #pragma unroll
    for (int k=0;k<16;k++){
      float a[4], bv[4];
      #pragma unroll
      for (int i=0;i<4;i++) a[i]=As[ty*4+i][k0+k];
      #pragma unroll
      for (int j=0;j<4;j++) bv[j]=Bs[k][tx*4+j];
      #pragma unroll
      for (int i=0;i<4;i++)
        #pragma unroll
        for (int j=0;j<4;j++) acc[i][j] += a[i]*bv[j];
    }
    __syncthreads();
  }
  int kpa = head*32 + ty*2;
  int kba = kpa >> 2, qa = kpa & 3;
  int kpb = kpa + 1;
  int kbb = kpb >> 2, qb = kpb & 3;
  #pragma unroll
  for (int j=0;j<4;j++){
    int n = n0 + tx*4 + j;
    BqH[((size_t)kba*HWSZ + n)*4 + qa] = pk_hi(acc[0][j], acc[1][j]);
    BqL[((size_t)kba*HWSZ + n)*4 + qa] = pk_lo(acc[0][j], acc[1][j]);
    BqH[((size_t)kbb*HWSZ + n)*4 + qb] = pk_hi(acc[2][j], acc[3][j]);
    BqL[((size_t)kbb*HWSZ + n)*4 + qb] = pk_lo(acc[2][j], acc[3][j]);
  }
}

extern "C" void kernel_launch(void* const* d_in, const int* in_sizes, int n_in,
                              void* d_out, int out_size, void* d_ws, size_t ws_size,
                              hipStream_t stream) {
  const float* x     = (const float*)d_in[0];
  const float* gn_w  = (const float*)d_in[1];
  const float* gn_b  = (const float*)d_in[2];
  const float* w_qkv = (const float*)d_in[3];
  const float* w_dw  = (const float*)d_in[4];
  const float* w_out = (const float*)d_in[5];
  const float* b_out = (const float*)d_in[6];
  const float* temperature = (const float*)d_in[7];
  const float* attn_w = (const float*)d_in[8];
  float* out = (float*)d_out;
  float* ws  = (float*)d_ws;
  unsigned int* AW = (unsigned int*)(ws + OFF_AW);
  float* R0 = ws + SHARED_END;
  const size_t CHW = (size_t)NC*HWSZ;

  size_t need2 = (SHARED_END + 2*RSTRIDE)*sizeof(float);
  size_t need4 = (SHARED_END + 4*RSTRIDE)*sizeof(float);
  int zb = (ws_size >= need4) ? 4 : (ws_size >= need2) ? 2 : 1;

  init_tables_k<<<64,256,0,stream>>>(ws);
  wpack_k<<<512,256,0,stream>>>(w_qkv, w_out, AW);
  gn_part_k<<<1024,256,0,stream>>>(x, (float2*)(ws+OFF_GNP));
  gn_fin_k<<<1,128,0,stream>>>((const float2*)(ws+OFF_GNP), gn_w, gn_b,
                               ws+OFF_SCALE, ws+OFF_SHIFT);

  for (int b0 = 0; b0 < 4; b0 += zb){
    packx_k<<<dim3(64,32,zb),256,0,stream>>>(x + (size_t)b0*CHW, ws+OFF_SCALE+b0*NC,
                                             ws+OFF_SHIFT+b0*NC, R0, RSTRIDE);
    gemm_pk<<<dim3(128,6,zb),256,0,stream>>>(AW+AWQ_H, AW+AWQ_L,
                                             (unsigned int*)(R0+R_H), (unsigned int*)(R0+R_H)+2097152,
                                             nullptr, R0+R_SCR, RSTRIDE, RSTRIDE);
    dwconv_tiled_k<<<dim3(3072,zb),256,0,stream>>>(R0, RSTRIDE, w_dw);
    fft1_mfma_k<<<dim3(256,zb),256,0,stream>>>(ws, R0, RSTRIDE);
    fft2_mfma_k<<<dim3(256,zb),256,0,stream>>>(ws, R0, RSTRIDE);
    fft3_mfma_k<<<dim3(256,zb),256,0,stream>>>(ws, R0, RSTRIDE);
    pri_k<<<dim3(64,4,zb),256,0,stream>>>(R0, RSTRIDE);
    red_k<<<dim3(32,zb),256,0,stream>>>(R0, RSTRIDE);
    attn_build_k<<<dim3(4,zb),256,0,stream>>>(ws, R0, RSTRIDE, temperature);
    topk_k<<<dim3(256,zb),64,0,stream>>>(R0, RSTRIDE, attn_w);
    av_k<<<dim3(256,4,zb),256,0,stream>>>(R0, RSTRIDE);
    gemm_pk<<<dim3(128,2,zb),256,0,stream>>>(AW+AWO_H, AW+AWO_L,
                                             (unsigned int*)(R0+R_H), (unsigned int*)(R0+R_H)+2097152,
                                             b_out, out + (size_t)b0*CHW, RSTRIDE, CHW);
  }
}

// Round 7
// 828.414 us; speedup vs baseline: 3.6574x; 1.0370x over previous
//
#include <hip/hip_runtime.h>
#include <math.h>

#define NC 256
#define CH3 768
#define HWSZ 16384

typedef __attribute__((ext_vector_type(8))) short short8;
typedef __attribute__((ext_vector_type(4))) float f32x4;
typedef __attribute__((ext_vector_type(4))) unsigned int u32x4;

// ---- shared (table) region ----
static const size_t OFF_TW1   = 0;
static const size_t OFF_TW2   = 32768;
static const size_t OFF_HM    = 65536;
static const size_t OFF_SCALE = 65600;
static const size_t OFF_SHIFT = 66624;
static const size_t OFF_PACK  = 67648;
static const size_t OFF_AW    = 182336;
static const size_t OFF_GNP   = 444480;
static const size_t SHARED_END= 446528;

// ---- per-batch region ----
static const size_t R_QKV  = 0;
static const size_t R_SCR  = 12582912;
static const size_t R_H    = 25165824;     // Bq packed -> Hf fp32 [d][s] -> Bq2 packed
static const size_t R_PP   = 29360128;
static const size_t R_RP   = 30408704;
static const size_t R_ATTN = 31457280;
static const size_t R_ACOMB= 31473664;
static const size_t R_PS   = 31490048;
static const size_t R_RS   = 31506432;
static const size_t R_DWP  = 31522816;
static const size_t R_SSUM = 31532032;
static const size_t R_SALT = 31532800;
static const size_t R_SSQ  = 31533568;
static const size_t RSTRIDE= 31534336;

#define TDA_RH 0
#define TDA_RL 8192
#define TDA_IH 16384
#define TDA_IL 24576
#define ETA_RH 32768
#define ETA_RL 40960
#define ETA_IH 49152
#define ETA_IL 57344
#define STB_RH 65536
#define STB_RL 73728
#define STB_IH 81920
#define STB_IL 90112
#define STB_NIH 98304
#define STB_NIL 106496

#define AWQ_H 0
#define AWQ_L 98304
#define AWO_H 196608
#define AWO_L 229376

__device__ inline unsigned short b16rn(float x){
  unsigned u = __float_as_uint(x);
  return (unsigned short)((u + 0x7FFFu + ((u>>16)&1u)) >> 16);
}
__device__ inline unsigned int pk_hi(float x, float y){
  return (__float_as_uint(x)>>16) | (__float_as_uint(y) & 0xFFFF0000u);
}
__device__ inline unsigned int pk_lo(float x, float y){
  float xl = x - __uint_as_float(__float_as_uint(x) & 0xFFFF0000u);
  float yl = y - __uint_as_float(__float_as_uint(y) & 0xFFFF0000u);
  return (unsigned)b16rn(xl) | ((unsigned)b16rn(yl)<<16);
}
__device__ inline short8 ld8g(const unsigned int* p){ return *(const short8*)p; }

// ---------------- tables ----------------
__global__ __launch_bounds__(256) void init_tables_k(float* __restrict__ ws){
  int idx = blockIdx.x*256 + threadIdx.x;
  float2* tw1 = (float2*)(ws + OFF_TW1);
  float2* tw2 = (float2*)(ws + OFF_TW2);
  unsigned int* pk = (unsigned int*)(ws + OFF_PACK);
  const double P2 = 6.283185307179586476925286766559005;
  int m = idx >> 7, k = idx & 127;
  double a2 = P2 * (double)(m*k) / 16384.0;
  tw1[idx] = make_float2((float)cos(a2), (float)(-sin(a2)));
  tw2[idx] = make_float2((float)cos(a2), (float)( sin(a2)));
  if (idx < 64){
    double acc = 0.0;
    for (int v = 1; v < 32; v++) acc += sin(P2 * (double)((v*idx) & 63) / 64.0);
    ws[OFF_HM + idx] = (float)(-acc / 32.0);
  }
  if (idx < 8192){
    int r = idx >> 6, kp = idx & 63;
    int k0 = 2*kp, k1 = 2*kp+1;
    double a0 = P2 * (double)((r*k0) & 127) / 128.0;
    double a1 = P2 * (double)((r*k1) & 127) / 128.0;
    float c0 = (float)cos(a0), c1 = (float)cos(a1);
    float s0 = (float)sin(a0), s1 = (float)sin(a1);
    pk[TDA_RH + idx] = pk_hi(c0, c1);  pk[TDA_RL + idx] = pk_lo(c0, c1);
    pk[TDA_IH + idx] = pk_hi(-s0,-s1); pk[TDA_IL + idx] = pk_lo(-s0,-s1);
    pk[ETA_RH + idx] = pk_hi(c0, c1);  pk[ETA_RL + idx] = pk_lo(c0, c1);
    pk[ETA_IH + idx] = pk_hi(s0, s1);  pk[ETA_IL + idx] = pk_lo(s0, s1);
    float sr0, si0, sr1, si1;
    {
      int d0 = (r - k0) & 127, d1 = (r - k1) & 127;
      if (d0 == 0){ sr0 = 64.f; si0 = 0.f; }
      else if ((d0 & 1) == 0){ sr0 = 0.f; si0 = 0.f; }
      else { double th = 3.1415926535897932384626 * (double)d0 / 128.0;
             sr0 = 1.f; si0 = (float)(cos(th)/sin(th)); }
      if (d1 == 0){ sr1 = 64.f; si1 = 0.f; }
      else if ((d1 & 1) == 0){ sr1 = 0.f; si1 = 0.f; }
      else { double th = 3.1415926535897932384626 * (double)d1 / 128.0;
             sr1 = 1.f; si1 = (float)(cos(th)/sin(th)); }
    }
    pk[STB_RH + idx]  = pk_hi(sr0, sr1);  pk[STB_RL + idx]  = pk_lo(sr0, sr1);
    pk[STB_IH + idx]  = pk_hi(si0, si1);  pk[STB_IL + idx]  = pk_lo(si0, si1);
    pk[STB_NIH + idx] = pk_hi(-si0,-si1); pk[STB_NIL + idx] = pk_lo(-si0,-si1);
  }
}

// ---------------- pack weights (once) ----------------
__global__ __launch_bounds__(256) void wpack_k(const float* __restrict__ wqkv, const float* __restrict__ wout,
                                               unsigned int* __restrict__ aw){
  int id = blockIdx.x*256 + threadIdx.x;
  int row = id >> 7, kp = id & 127;
  if (row < CH3){
    float v0 = wqkv[row*256 + 2*kp], v1 = wqkv[row*256 + 2*kp + 1];
    aw[AWQ_H + row*128 + kp] = pk_hi(v0, v1);
    aw[AWQ_L + row*128 + kp] = pk_lo(v0, v1);
  } else {
    int r2 = row - CH3;
    float v0 = wout[r2*256 + 2*kp], v1 = wout[r2*256 + 2*kp + 1];
    aw[AWO_H + r2*128 + kp] = pk_hi(v0, v1);
    aw[AWO_L + r2*128 + kp] = pk_lo(v0, v1);
  }
}

// ---------------- groupnorm stats ----------------
__global__ __launch_bounds__(256) void gn_part_k(const float* __restrict__ x, float2* __restrict__ part){
  int id = blockIdx.x;
  const float4* p = (const float4*)(x + (size_t)id*HWSZ);
  int tid = threadIdx.x;
  float s = 0.f, sq = 0.f;
  #pragma unroll
  for (int i = 0; i < 16; i++){
    float4 v = p[tid + i*256];
    s  += v.x+v.y+v.z+v.w;
    sq += v.x*v.x+v.y*v.y+v.z*v.z+v.w*v.w;
  }
  __shared__ float r1[256], r2[256];
  r1[tid]=s; r2[tid]=sq; __syncthreads();
  for (int off=128; off; off>>=1){
    if (tid<off){ r1[tid]+=r1[tid+off]; r2[tid]+=r2[tid+off]; }
    __syncthreads();
  }
  if (tid==0) part[id] = make_float2(r1[0], r2[0]);
}
__global__ __launch_bounds__(128) void gn_fin_k(const float2* __restrict__ part, const float* __restrict__ gw,
                                                const float* __restrict__ gb, float* __restrict__ scale,
                                                float* __restrict__ shift){
  int bg = threadIdx.x;
  int b = bg >> 5, g = bg & 31;
  float s = 0.f, sq = 0.f;
  #pragma unroll
  for (int i = 0; i < 8; i++){
    float2 v = part[b*NC + g*8 + i];
    s += v.x; sq += v.y;
  }
  const float n = 8.0f*HWSZ;
  float mu = s/n, var = sq/n - mu*mu;
  float rs = rsqrtf(var + 1e-5f);
  for (int i = 0; i < 8; i++){
    int ch = g*8 + i;
    float sc = rs * gw[ch];
    scale[b*NC + ch] = sc;
    shift[b*NC + ch] = gb[ch] - mu*sc;
  }
}

// ---------------- pack GN(x) into Bq planes ----------------
__global__ __launch_bounds__(256) void packx_k(const float* __restrict__ xbase, const float* __restrict__ scale,
                                               const float* __restrict__ shift, float* __restrict__ R0,
                                               size_t rstride){
  int bz = blockIdx.z;
  const float* xb = xbase + (size_t)bz*NC*HWSZ;
  const float* sc = scale + bz*NC;
  const float* sh = shift + bz*NC;
  unsigned int* BqH = (unsigned int*)(R0 + (size_t)bz*rstride + R_H);
  unsigned int* BqL = BqH + 2097152;
  int kb = blockIdx.y;
  int n = blockIdx.x*256 + threadIdx.x;
  float v[8];
  #pragma unroll
  for (int c = 0; c < 8; c++){
    int ch = kb*8 + c;
    v[c] = xb[(size_t)ch*HWSZ + n]*sc[ch] + sh[ch];
  }
  u32x4 h, l;
  #pragma unroll
  for (int q = 0; q < 4; q++){
    h[q] = pk_hi(v[2*q], v[2*q+1]);
    l[q] = pk_lo(v[2*q], v[2*q+1]);
  }
  *(u32x4*)&BqH[((size_t)kb*HWSZ + n)*4] = h;
  *(u32x4*)&BqL[((size_t)kb*HWSZ + n)*4] = l;
}

// ---------------- LDS-free packed split-bf16 MFMA GEMM, depth-2 register pipeline ----------------
__global__ __launch_bounds__(256) void gemm_pk(const unsigned int* __restrict__ Ah, const unsigned int* __restrict__ Al,
                                               const unsigned int* __restrict__ Bh0, const unsigned int* __restrict__ Bl0,
                                               const float* __restrict__ bias, float* __restrict__ C0,
                                               size_t bstride, size_t cstride){
  const unsigned int* Bh = Bh0 + (size_t)blockIdx.z*bstride;
  const unsigned int* Bl = Bl0 + (size_t)blockIdx.z*bstride;
  float* C = C0 + (size_t)blockIdx.z*cstride;
  int tid = threadIdx.x;
  int lane = tid & 63, wid = tid >> 6;
  int m0 = blockIdx.y*128, n0 = blockIdx.x*128;
  int wr = (wid>>1)*64, wc = (wid&1)*64;
  int lr = lane & 15, lk = lane >> 4;
  f32x4 acc[4][4] = {};
  size_t aoff[4], boff[4];
  #pragma unroll
  for (int i=0;i<4;i++) aoff[i] = (size_t)(m0 + wr + i*16 + lr)*128 + lk*4;
  #pragma unroll
  for (int j=0;j<4;j++) boff[j] = ((size_t)lk*HWSZ + n0 + wc + j*16 + lr)*4;
  short8 aH[3][4], aL[3][4], bH[3][4], bL[3][4];
#define LOADT(B,T) { \
    size_t da = (size_t)(T)*16, db = (size_t)(T)*4*HWSZ*4; \
    _Pragma("unroll") \
    for (int i=0;i<4;i++){ aH[B][i] = ld8g(Ah + aoff[i] + da); aL[B][i] = ld8g(Al + aoff[i] + da); } \
    _Pragma("unroll") \
    for (int j=0;j<4;j++){ bH[B][j] = ld8g(Bh + boff[j] + db); bL[B][j] = ld8g(Bl + boff[j] + db); } \
  }
  LOADT(0,0); LOADT(1,1);
  #pragma unroll
  for (int kt = 0; kt < 8; kt++){
    int cur = kt % 3;
    if (kt < 6){ int nb = (kt+2) % 3; LOADT(nb, kt+2); }
    #pragma unroll
    for (int i=0;i<4;i++)
      #pragma unroll
      for (int j=0;j<4;j++){
        acc[i][j] = __builtin_amdgcn_mfma_f32_16x16x32_bf16(aH[cur][i], bH[cur][j], acc[i][j], 0,0,0);
        acc[i][j] = __builtin_amdgcn_mfma_f32_16x16x32_bf16(aH[cur][i], bL[cur][j], acc[i][j], 0,0,0);
        acc[i][j] = __builtin_amdgcn_mfma_f32_16x16x32_bf16(aL[cur][i], bH[cur][j], acc[i][j], 0,0,0);
      }
  }
#undef LOADT
  #pragma unroll
  for (int i=0;i<4;i++){
    #pragma unroll
    for (int e=0;e<4;e++){
      int row = m0 + wr + i*16 + lk*4 + e;
      float bb = bias ? bias[row] : 0.0f;
      #pragma unroll
      for (int j=0;j<4;j++)
        C[(size_t)row*HWSZ + n0 + wc + j*16 + lr] = acc[i][j][e] + bb;
    }
  }
}

// ---------------- depthwise 3x3, tiled ----------------
__global__ __launch_bounds__(256) void dwconv_tiled_k(float* __restrict__ R0, size_t rstride,
                                                      const float* __restrict__ wdw){
  float* Rb = R0 + (size_t)blockIdx.y*rstride;
  int blk = blockIdx.x;
  int ch = blk >> 2, sl = blk & 3;
  int h0 = sl*32;
  const float* in = Rb + R_SCR + (size_t)ch*HWSZ;
  float* outp = Rb + R_QKV + (size_t)ch*HWSZ;
  float* part = Rb + R_DWP;
  float w[9];
  #pragma unroll
  for (int i=0;i<9;i++) w[i] = wdw[ch*9+i];
  __shared__ float tile[34][132];
  __shared__ float r0[256], r1[256], r2[256];
  int tid = threadIdx.x;
  #pragma unroll
  for (int i = 0; i < 5; i++){
    int id = tid + i*256;
    if (id < 1088){
      int r = id >> 5, c4 = id & 31;
      int gh = h0 - 1 + r;
      float4 v = (gh >= 0 && gh < 128) ? *(const float4*)&in[gh*128 + c4*4]
                                       : make_float4(0.f,0.f,0.f,0.f);
      *(float4*)&tile[r][c4*4] = v;
    }
  }
  __syncthreads();
  float s=0.f, sa=0.f, sq=0.f;
  #pragma unroll
  for (int it=0; it<4; it++){
    int idx = it*256 + tid;
    int lh = idx >> 5;
    int xq = idx & 31;
    int xb4 = xq*4;
    float o[4];
    #pragma unroll
    for (int e=0;e<4;e++){
      int xw = xb4 + e;
      float acc = 0.f;
      #pragma unroll
      for (int ky=0; ky<3; ky++){
        const float* tr = &tile[lh+ky][xw];
        if (xw > 0)   acc += tr[-1]*w[ky*3+0];
                      acc += tr[ 0]*w[ky*3+1];
        if (xw < 127) acc += tr[ 1]*w[ky*3+2];
      }
      o[e] = acc;
      s += acc; sq += acc*acc;
      sa += (e & 1) ? -acc : acc;
    }
    *(float4*)&outp[(h0+lh)*128 + xb4] = make_float4(o[0],o[1],o[2],o[3]);
  }
  r0[tid]=s; r1[tid]=sa; r2[tid]=sq; __syncthreads();
  for (int off=128; off; off>>=1){
    if (tid<off){ r0[tid]+=r0[tid+off]; r1[tid]+=r1[tid+off]; r2[tid]+=r2[tid+off]; }
    __syncthreads();
  }
  if (tid==0){ part[blk]=r0[0]; part[3072+blk]=r1[0]; part[6144+blk]=r2[0]; }
}

// ---------------- FFT stage 1 (MFMA) ----------------
__global__ __launch_bounds__(256) void fft1_mfma_k(const float* __restrict__ ws, float* __restrict__ R0,
                                                   size_t rstride){
  float* Rb = R0 + (size_t)blockIdx.y*rstride;
  const float* Kb = Rb + R_QKV + (size_t)256*HWSZ;
  float2* Tc = (float2*)(Rb + R_SCR);
  const unsigned int* PK = (const unsigned int*)(ws + OFF_PACK);
  const float2* tw1 = (const float2*)(ws + OFF_TW1);
  __shared__ unsigned int Bth[128][20], Btl[128][20];
  int tid = threadIdx.x;
  int lane = tid & 63, wid = tid >> 6;
  int wr = (wid>>1)*64, wc = (wid&1)*64;
  int lr = lane & 15, lk = lane >> 4;
  int row = blockIdx.x;
  const float* src = Kb + (size_t)row*HWSZ;
  f32x4 aR[4][4] = {}, aI[4][4] = {};
  int bc = tid & 127, grp = tid >> 7;
  for (int kt = 0; kt < 4; kt++){
    #pragma unroll
    for (int p=0;p<8;p++){
      int kp = grp*8 + p;
      int a = kt*32 + 2*kp;
      float v0 = src[a*128 + bc], v1 = src[(a+1)*128 + bc];
      Bth[bc][kp] = pk_hi(v0, v1);
      Btl[bc][kp] = pk_lo(v0, v1);
    }
    __syncthreads();
    short8 bh[4], bl[4];
    #pragma unroll
    for (int j=0;j<4;j++){
      bh[j] = *(const short8*)&Bth[wc + j*16 + lr][lk*4];
      bl[j] = *(const short8*)&Btl[wc + j*16 + lr][lk*4];
    }
    #pragma unroll
    for (int i=0;i<4;i++){
      int off = (wr + i*16 + lr)*64 + kt*16 + lk*4;
      short8 ahR = ld8g(PK + TDA_RH + off), alR = ld8g(PK + TDA_RL + off);
      short8 ahI = ld8g(PK + TDA_IH + off), alI = ld8g(PK + TDA_IL + off);
      #pragma unroll
      for (int j=0;j<4;j++){
        aR[i][j] = __builtin_amdgcn_mfma_f32_16x16x32_bf16(ahR, bh[j], aR[i][j], 0,0,0);
        aR[i][j] = __builtin_amdgcn_mfma_f32_16x16x32_bf16(ahR, bl[j], aR[i][j], 0,0,0);
        aR[i][j] = __builtin_amdgcn_mfma_f32_16x16x32_bf16(alR, bh[j], aR[i][j], 0,0,0);
        aI[i][j] = __builtin_amdgcn_mfma_f32_16x16x32_bf16(ahI, bh[j], aI[i][j], 0,0,0);
        aI[i][j] = __builtin_amdgcn_mfma_f32_16x16x32_bf16(ahI, bl[j], aI[i][j], 0,0,0);
        aI[i][j] = __builtin_amdgcn_mfma_f32_16x16x32_bf16(alI, bh[j], aI[i][j], 0,0,0);
      }
    }
    __syncthreads();
  }
  #pragma unroll
  for (int i=0;i<4;i++)
    #pragma unroll
    for (int e=0;e<4;e++){
      int m = wr + i*16 + lk*4 + e;
      #pragma unroll
      for (int j=0;j<4;j++){
        int col = wc + j*16 + lr;
        float2 t = tw1[m*128 + col];
        float r = aR[i][j][e], im = aI[i][j][e];
        Tc[(size_t)m*32768 + row*128 + col] = make_float2(r*t.x - im*t.y, r*t.y + im*t.x);
      }
    }
}

// ---------------- FFT stage 2 (MFMA, in-place) ----------------
__global__ __launch_bounds__(256) void fft2_mfma_k(const float* __restrict__ ws, float* __restrict__ R0,
                                                   size_t rstride){
  float* Rb = R0 + (size_t)blockIdx.y*rstride;
  float2* TU = (float2*)(Rb + R_SCR);
  const unsigned int* PK = (const unsigned int*)(ws + OFF_PACK);
  const float2* tw2 = (const float2*)(ws + OFF_TW2);
  __shared__ unsigned int ARh[128][20], ARl[128][20], AIh[128][20], AIl[128][20];
  int tid = threadIdx.x;
  int lane = tid & 63, wid = tid >> 6;
  int wr = (wid>>1)*64, wc = (wid&1)*64;
  int lr = lane & 15, lk = lane >> 4;
  int m0 = blockIdx.x*128;
  f32x4 aR[4][4] = {}, aI[4][4] = {};
  const float* Tf = (const float*)TU;
  for (int kt = 0; kt < 4; kt++){
    #pragma unroll
    for (int s=0;s<8;s++){
      int id = tid + s*256;
      int r = id >> 4, kp = id & 15;
      int k = kt*32 + 2*kp;
      float4 v = *(const float4*)&Tf[((size_t)(m0+r)*128 + k)*2];
      ARh[r][kp] = pk_hi(v.x, v.z); ARl[r][kp] = pk_lo(v.x, v.z);
      AIh[r][kp] = pk_hi(v.y, v.w); AIl[r][kp] = pk_lo(v.y, v.w);
    }
    __syncthreads();
    short8 ahR[4], alR[4], ahI[4], alI[4];
    #pragma unroll
    for (int i=0;i<4;i++){
      int ar = wr + i*16 + lr;
      ahR[i] = *(const short8*)&ARh[ar][lk*4];
      alR[i] = *(const short8*)&ARl[ar][lk*4];
      ahI[i] = *(const short8*)&AIh[ar][lk*4];
      alI[i] = *(const short8*)&AIl[ar][lk*4];
    }
    #pragma unroll
    for (int j=0;j<4;j++){
      int boff = (wc + j*16 + lr)*64 + kt*16 + lk*4;
      short8 bhR = ld8g(PK + STB_RH + boff), blR = ld8g(PK + STB_RL + boff);
      short8 bhI = ld8g(PK + STB_IH + boff), blI = ld8g(PK + STB_IL + boff);
      short8 bhN = ld8g(PK + STB_NIH + boff), blN = ld8g(PK + STB_NIL + boff);
      #pragma unroll
      for (int i=0;i<4;i++){
        aR[i][j] = __builtin_amdgcn_mfma_f32_16x16x32_bf16(ahR[i], bhR, aR[i][j], 0,0,0);
        aR[i][j] = __builtin_amdgcn_mfma_f32_16x16x32_bf16(ahR[i], blR, aR[i][j], 0,0,0);
        aR[i][j] = __builtin_amdgcn_mfma_f32_16x16x32_bf16(alR[i], bhR, aR[i][j], 0,0,0);
        aR[i][j] = __builtin_amdgcn_mfma_f32_16x16x32_bf16(ahI[i], bhN, aR[i][j], 0,0,0);
        aR[i][j] = __builtin_amdgcn_mfma_f32_16x16x32_bf16(ahI[i], blN, aR[i][j], 0,0,0);
        aR[i][j] = __builtin_amdgcn_mfma_f32_16x16x32_bf16(alI[i], bhN, aR[i][j], 0,0,0);
        aI[i][j] = __builtin_amdgcn_mfma_f32_16x16x32_bf16(ahR[i], bhI, aI[i][j], 0,0,0);
        aI[i][j] = __builtin_amdgcn_mfma_f32_16x16x32_bf16(ahR[i], blI, aI[i][j], 0,0,0);
        aI[i][j] = __builtin_amdgcn_mfma_f32_16x16x32_bf16(alR[i], bhI, aI[i][j], 0,0,0);
        aI[i][j] = __builtin_amdgcn_mfma_f32_16x16x32_bf16(ahI[i], bhR, aI[i][j], 0,0,0);
        aI[i][j] = __builtin_amdgcn_mfma_f32_16x16x32_bf16(ahI[i], blR, aI[i][j], 0,0,0);
        aI[i][j] = __builtin_amdgcn_mfma_f32_16x16x32_bf16(alI[i], bhR, aI[i][j], 0,0,0);
      }
    }
    __syncthreads();
  }
  #pragma unroll
  for (int i=0;i<4;i++)
    #pragma unroll
    for (int e=0;e<4;e++){
      int m = m0 + wr + i*16 + lk*4 + e;
      int f0 = m >> 8;
      #pragma unroll
      for (int j=0;j<4;j++){
        int col = wc + j*16 + lr;
        float2 t = tw2[f0*128 + col];
        float r = aR[i][j][e], im = aI[i][j][e];
        TU[(size_t)m*128 + col] = make_float2(r*t.x - im*t.y, r*t.y + im*t.x);
      }
    }
}

// ---------------- FFT stage 3 (MFMA), writes flip layout Hf[d][s] ----------------
__global__ __launch_bounds__(256) void fft3_mfma_k(const float* __restrict__ ws, float* __restrict__ R0,
                                                   size_t rstride){
  float* Rb = R0 + (size_t)blockIdx.y*rstride;
  const float2* U = (const float2*)(Rb + R_SCR);
  float* Hf = Rb + R_H;
  const unsigned int* PK = (const unsigned int*)(ws + OFF_PACK);
  __shared__ unsigned int BRh[128][20], BRl[128][20], BIh[128][20], BIl[128][20];
  int tid = threadIdx.x;
  int lane = tid & 63, wid = tid >> 6;
  int wr = (wid>>1)*64, wc = (wid&1)*64;
  int lr = lane & 15, lk = lane >> 4;
  int brow = blockIdx.x;                // d row 0..255
  f32x4 ac[4][4] = {};
  int bc = tid & 127, grp = tid >> 7;
  for (int kt = 0; kt < 4; kt++){
    #pragma unroll
    for (int p=0;p<8;p++){
      int kp = grp*8 + p;
      int k = kt*32 + 2*kp;
      float2 v0 = U[((size_t)k*256 + brow)*128 + bc];
      float2 v1 = U[((size_t)(k+1)*256 + brow)*128 + bc];
      BRh[bc][kp] = pk_hi(v0.x, v1.x); BRl[bc][kp] = pk_lo(v0.x, v1.x);
      BIh[bc][kp] = pk_hi(v0.y, v1.y); BIl[bc][kp] = pk_lo(v0.y, v1.y);
    }
    __syncthreads();
    short8 ahR[4], alR[4], ahI[4], alI[4];
    #pragma unroll
    for (int i=0;i<4;i++){
      int off = (wr + i*16 + lr)*64 + kt*16 + lk*4;
      ahR[i] = ld8g(PK + ETA_RH + off); alR[i] = ld8g(PK + ETA_RL + off);
      ahI[i] = ld8g(PK + ETA_IH + off); alI[i] = ld8g(PK + ETA_IL + off);
    }
    #pragma unroll
    for (int j=0;j<4;j++){
      int col = wc + j*16 + lr;
      short8 bhR = *(const short8*)&BRh[col][lk*4];
      short8 blR = *(const short8*)&BRl[col][lk*4];
      short8 bhI = *(const short8*)&BIh[col][lk*4];
      short8 blI = *(const short8*)&BIl[col][lk*4];
      #pragma unroll
      for (int i=0;i<4;i++){
        ac[i][j] = __builtin_amdgcn_mfma_f32_16x16x32_bf16(ahR[i], bhI, ac[i][j], 0,0,0);
        ac[i][j] = __builtin_amdgcn_mfma_f32_16x16x32_bf16(ahR[i], blI, ac[i][j], 0,0,0);
        ac[i][j] = __builtin_amdgcn_mfma_f32_16x16x32_bf16(alR[i], bhI, ac[i][j], 0,0,0);
        ac[i][j] = __builtin_amdgcn_mfma_f32_16x16x32_bf16(ahI[i], bhR, ac[i][j], 0,0,0);
        ac[i][j] = __builtin_amdgcn_mfma_f32_16x16x32_bf16(ahI[i], blR, ac[i][j], 0,0,0);
        ac[i][j] = __builtin_amdgcn_mfma_f32_16x16x32_bf16(alI[i], bhR, ac[i][j], 0,0,0);
      }
    }
    __syncthreads();
  }
  // flip write: Hf[d][s] with s = (16384 - (u*128 + r)) & 16383
  #pragma unroll
  for (int i=0;i<4;i++)
    #pragma unroll
    for (int e=0;e<4;e++){
      int m = wr + i*16 + lk*4 + e;     // u
      #pragma unroll
      for (int j=0;j<4;j++){
        int col = wc + j*16 + lr;       // r
        int s = (16384 - (m*128 + col)) & 16383;
        Hf[(size_t)brow*16384 + s] = ac[i][j][e];
      }
    }
}

// ---------------- P & Ri via MFMA: grid (64 sp, 4 head, zb) ----------------
__global__ __launch_bounds__(256) void pri2_k(float* __restrict__ R0, size_t rstride){
  float* Rb = R0 + (size_t)blockIdx.z*rstride;
  int sp = blockIdx.x, head = blockIdx.y;
  const float* Qb = Rb + R_QKV + (size_t)(head*64)*HWSZ;
  const float* Kb = Rb + R_QKV + (size_t)(256 + head*64)*HWSZ;
  const float* Hf = Rb + R_H + (size_t)(head*64)*16384;
  float* Pp = Rb + R_PP;
  float* Rp = Rb + R_RP;
  __shared__ unsigned int Qh[64][17], Ql[64][17], K1h[64][17], K1l[64][17], K2h[64][17], K2l[64][17];
  int tid = threadIdx.x, lane = tid & 63, wid = tid >> 6;
  int wr = (wid>>1)*32, wc = (wid&1)*32;
  int lr = lane & 15, lk = lane >> 4;
  int sd = tid >> 2, sk0 = (tid & 3)*8;
  f32x4 aP[2][2] = {}, aR[2][2] = {};
  for (int kt = 0; kt < 8; kt++){
    int s0 = sp*256 + kt*32;
    float q[8], k1[8], k2[8];
    #pragma unroll
    for (int e=0;e<8;e++){
      int s = s0 + sk0 + e;
      q[e]  = Qb[(size_t)sd*HWSZ + s];
      k1[e] = Kb[(size_t)sd*HWSZ + ((16384 - s) & 16383)];
      k2[e] = Hf[(size_t)sd*16384 + s];
    }
    __syncthreads();
    #pragma unroll
    for (int p=0;p<4;p++){
      int kp = (sk0>>1) + p;
      Qh[sd][kp]  = pk_hi(q[2*p],  q[2*p+1]);  Ql[sd][kp]  = pk_lo(q[2*p],  q[2*p+1]);
      K1h[sd][kp] = pk_hi(k1[2*p], k1[2*p+1]); K1l[sd][kp] = pk_lo(k1[2*p], k1[2*p+1]);
      K2h[sd][kp] = pk_hi(k2[2*p], k2[2*p+1]); K2l[sd][kp] = pk_lo(k2[2*p], k2[2*p+1]);
    }
    __syncthreads();
    short8 qh[2], ql[2], b1h[2], b1l[2], b2h[2], b2l[2];
    #pragma unroll
    for (int i=0;i<2;i++){
      qh[i]  = *(const short8*)&Qh[wr + i*16 + lr][lk*4];
      ql[i]  = *(const short8*)&Ql[wr + i*16 + lr][lk*4];
      b1h[i] = *(const short8*)&K1h[wc + i*16 + lr][lk*4];
      b1l[i] = *(const short8*)&K1l[wc + i*16 + lr][lk*4];
      b2h[i] = *(const short8*)&K2h[wc + i*16 + lr][lk*4];
      b2l[i] = *(const short8*)&K2l[wc + i*16 + lr][lk*4];
    }
    #pragma unroll
    for (int i=0;i<2;i++)
      #pragma unroll
      for (int j=0;j<2;j++){
        aP[i][j] = __builtin_amdgcn_mfma_f32_16x16x32_bf16(qh[i], b1h[j], aP[i][j], 0,0,0);
        aP[i][j] = __builtin_amdgcn_mfma_f32_16x16x32_bf16(qh[i], b1l[j], aP[i][j], 0,0,0);
        aP[i][j] = __builtin_amdgcn_mfma_f32_16x16x32_bf16(ql[i], b1h[j], aP[i][j], 0,0,0);
        aR[i][j] = __builtin_amdgcn_mfma_f32_16x16x32_bf16(qh[i], b2h[j], aR[i][j], 0,0,0);
        aR[i][j] = __builtin_amdgcn_mfma_f32_16x16x32_bf16(qh[i], b2l[j], aR[i][j], 0,0,0);
        aR[i][j] = __builtin_amdgcn_mfma_f32_16x16x32_bf16(ql[i], b2h[j], aR[i][j], 0,0,0);
      }
  }
  size_t base = ((size_t)(sp*4 + head)) << 12;
  #pragma unroll
  for (int i=0;i<2;i++)
    #pragma unroll
    for (int e=0;e<4;e++){
      int row = wr + i*16 + lk*4 + e;
      #pragma unroll
      for (int j=0;j<2;j++){
        int col = wc + j*16 + lr;
        size_t o = base + (size_t)row*64 + col;
        Pp[o] = aP[i][j][e];
        Rp[o] = aR[i][j][e];
      }
    }
}

// ---------------- split reduce + dw stat fold ----------------
__global__ __launch_bounds__(256) void red_k(float* __restrict__ R0, size_t rstride){
  float* Rb = R0 + (size_t)blockIdx.y*rstride;
  const float* Pp = Rb + R_PP;
  const float* Rp = Rb + R_RP;
  float* Ps = Rb + R_PS;
  float* Rs = Rb + R_RS;
  int tid = threadIdx.x;
  #pragma unroll
  for (int rep=0; rep<2; rep++){
    int g = blockIdx.x*512 + rep*256 + tid;
    int head = g >> 12, loc = g & 4095;
    float p = 0.f, ri = 0.f;
    for (int sp=0; sp<64; sp++){
      size_t o = ((size_t)(sp*4+head)<<12) + loc;
      p += Pp[o]; ri += Rp[o];
    }
    Ps[g] = p; Rs[g] = ri;
  }
  if (blockIdx.x == 0){
    const float* part = Rb + R_DWP;
    for (int ch = tid; ch < CH3; ch += 256){
      float s=0.f, sa=0.f, sq=0.f;
      #pragma unroll
      for (int sl=0; sl<4; sl++){
        s  += part[ch*4+sl];
        sa += part[3072+ch*4+sl];
        sq += part[6144+ch*4+sl];
      }
      Rb[R_SSUM+ch]=s; Rb[R_SALT+ch]=sa; Rb[R_SSQ+ch]=sq;
    }
  }
}

// ---------------- attn build ----------------
__global__ __launch_bounds__(256) void attn_build_k(const float* __restrict__ ws, float* __restrict__ R0,
                                                    size_t rstride, const float* __restrict__ temperature){
  float* Rb = R0 + (size_t)blockIdx.y*rstride;
  const float* Ps   = Rb + R_PS;
  const float* Rs   = Rb + R_RS;
  const float* ssum = Rb + R_SSUM;
  const float* salt = Rb + R_SALT;
  const float* ssq  = Rb + R_SSQ;
  float* attn = Rb + R_ATTN;
  const float* hmg  = ws + OFF_HM;
  __shared__ float Rn[64][65], Ril[64][65], hm[64];
  int head = blockIdx.x;
  int tid = threadIdx.x;
  if (tid < 64) hm[tid] = hmg[tid];
  for (int t=0;t<16;t++){
    int idx = tid + t*256; int c = idx>>6, d = idx&63;
    float P = Ps[head*4096 + idx], Ri = Rs[head*4096 + idx];
    int qch = head*64 + c;
    int kch = 256 + head*64 + d;
    float qs=ssum[qch], qa=salt[qch], qn=fmaxf(sqrtf(ssq[qch]), 1e-12f);
    float ks=ssum[kch], ka=salt[kch], kn=fmaxf(sqrtf(ssq[kch]), 1e-12f);
    float Rr = 0.5f*(16384.0f*P + qs*ks + qa*ka);
    float sc = 1.0f/(qn*kn);
    Rn[c][d]  = Rr*sc;
    Ril[c][d] = Ri*sc;
  }
  __syncthreads();
  float tmp2 = temperature[(head+2)&3];
  for (int t=0;t<16;t++){
    int idx = tid + t*256; int c = idx>>6, e = idx&63;
    float s = Rn[c][e];
    #pragma unroll 8
    for (int d=0; d<64; d++) s += Ril[c][d]*hm[(e-d)&63];
    attn[((size_t)head<<12) + (size_t)(c*64+e)] = s*tmp2;
  }
}

// ---------------- nested top-k masked softmax ----------------
__global__ __launch_bounds__(64) void topk_k(float* __restrict__ R0, size_t rstride,
                                             const float* __restrict__ attn_w){
  float* Rb = R0 + (size_t)blockIdx.y*rstride;
  const float* attn = Rb + R_ATTN;
  float* Acomb = Rb + R_ACOMB;
  int blk = blockIdx.x;
  int tid = threadIdx.x;
  __shared__ float row[64];
  float v = attn[(size_t)blk*64 + tid];
  row[tid] = v;
  __syncthreads();
  int rank = 0; float vmax = -1e30f;
  for (int l=0;l<64;l++){
    float w = row[l];
    if (w > v || (w == v && l < tid)) rank++;
    vmax = fmaxf(vmax, w);
  }
  float e = expf(v - vmax);
  const int kks[4] = {32,42,48,51};
  float denom[4];
  #pragma unroll
  for (int i=0;i<4;i++){
    float x = (rank < kks[i]) ? e : 0.0f;
    #pragma unroll
    for (int off=32; off; off>>=1) x += __shfl_xor(x, off);
    denom[i] = x;
  }
  float wgt = 0.f;
  #pragma unroll
  for (int i=0;i<4;i++) if (rank < kks[i]) wgt += attn_w[i] / denom[i];
  Acomb[(size_t)blk*64 + tid] = e * wgt;
}

// ---------------- out_head = A_comb @ v, packed output ----------------
__global__ __launch_bounds__(256) void av_k(float* __restrict__ R0, size_t rstride){
  float* Rb = R0 + (size_t)blockIdx.z*rstride;
  const float* Acomb = Rb + R_ACOMB;
  unsigned int* BqH = (unsigned int*)(Rb + R_H);
  unsigned int* BqL = BqH + 2097152;
  int head = blockIdx.y;
  int n0 = blockIdx.x*64;
  const float* Vb = Rb + R_QKV + (size_t)(512 + head*64)*HWSZ;
  __shared__ float As[64][65], Bs[16][65];
  int tid=threadIdx.x, tx=tid&15, ty=tid>>4;
  for (int t=0;t<16;t++){ int idx=tid+t*256; As[idx>>6][idx&63] = Acomb[((size_t)head<<12)+idx]; }
  __syncthreads();
  float acc[4][4]={};
  for (int k0=0;k0<64;k0+=16){
    #pragma unroll
    for (int i=0;i<4;i++){ int id=tid+i*256; int nn=id&63, k=id>>6;
      Bs[k][nn] = Vb[(size_t)(k0+k)*HWSZ + n0+nn]; }
    __syncthreads();
    #pragma unroll
    for (int k=0;k<16;k++){
      float a[4], bv[4];
      #pragma unroll
      for (int i=0;i<4;i++) a[i]=As[ty*4+i][k0+k];
      #pragma unroll
      for (int j=0;j<4;j++) bv[j]=Bs[k][tx*4+j];
      #pragma unroll
      for (int i=0;i<4;i++)
        #pragma unroll
        for (int j=0;j<4;j++) acc[i][j] += a[i]*bv[j];
    }
    __syncthreads();
  }
  int kpa = head*32 + ty*2;
  int kba = kpa >> 2, qa = kpa & 3;
  int kpb = kpa + 1;
  int kbb = kpb >> 2, qb = kpb & 3;
  #pragma unroll
  for (int j=0;j<4;j++){
    int n = n0 + tx*4 + j;
    BqH[((size_t)kba*HWSZ + n)*4 + qa] = pk_hi(acc[0][j], acc[1][j]);
    BqL[((size_t)kba*HWSZ + n)*4 + qa] = pk_lo(acc[0][j], acc[1][j]);
    BqH[((size_t)kbb*HWSZ + n)*4 + qb] = pk_hi(acc[2][j], acc[3][j]);
    BqL[((size_t)kbb*HWSZ + n)*4 + qb] = pk_lo(acc[2][j], acc[3][j]);
  }
}

extern "C" void kernel_launch(void* const* d_in, const int* in_sizes, int n_in,
                              void* d_out, int out_size, void* d_ws, size_t ws_size,
                              hipStream_t stream) {
  const float* x     = (const float*)d_in[0];
  const float* gn_w  = (const float*)d_in[1];
  const float* gn_b  = (const float*)d_in[2];
  const float* w_qkv = (const float*)d_in[3];
  const float* w_dw  = (const float*)d_in[4];
  const float* w_out = (const float*)d_in[5];
  const float* b_out = (const float*)d_in[6];
  const float* temperature = (const float*)d_in[7];
  const float* attn_w = (const float*)d_in[8];
  float* out = (float*)d_out;
  float* ws  = (float*)d_ws;
  unsigned int* AW = (unsigned int*)(ws + OFF_AW);
  float* R0 = ws + SHARED_END;
  const size_t CHW = (size_t)NC*HWSZ;

  size_t need2 = (SHARED_END + 2*RSTRIDE)*sizeof(float);
  size_t need4 = (SHARED_END + 4*RSTRIDE)*sizeof(float);
  int zb = (ws_size >= need4) ? 4 : (ws_size >= need2) ? 2 : 1;

  init_tables_k<<<64,256,0,stream>>>(ws);
  wpack_k<<<512,256,0,stream>>>(w_qkv, w_out, AW);
  gn_part_k<<<1024,256,0,stream>>>(x, (float2*)(ws+OFF_GNP));
  gn_fin_k<<<1,128,0,stream>>>((const float2*)(ws+OFF_GNP), gn_w, gn_b,
                               ws+OFF_SCALE, ws+OFF_SHIFT);

  for (int b0 = 0; b0 < 4; b0 += zb){
    packx_k<<<dim3(64,32,zb),256,0,stream>>>(x + (size_t)b0*CHW, ws+OFF_SCALE+b0*NC,
                                             ws+OFF_SHIFT+b0*NC, R0, RSTRIDE);
    gemm_pk<<<dim3(128,6,zb),256,0,stream>>>(AW+AWQ_H, AW+AWQ_L,
                                             (unsigned int*)(R0+R_H), (unsigned int*)(R0+R_H)+2097152,
                                             nullptr, R0+R_SCR, RSTRIDE, RSTRIDE);
    dwconv_tiled_k<<<dim3(3072,zb),256,0,stream>>>(R0, RSTRIDE, w_dw);
    fft1_mfma_k<<<dim3(256,zb),256,0,stream>>>(ws, R0, RSTRIDE);
    fft2_mfma_k<<<dim3(256,zb),256,0,stream>>>(ws, R0, RSTRIDE);
    fft3_mfma_k<<<dim3(256,zb),256,0,stream>>>(ws, R0, RSTRIDE);
    pri2_k<<<dim3(64,4,zb),256,0,stream>>>(R0, RSTRIDE);
    red_k<<<dim3(32,zb),256,0,stream>>>(R0, RSTRIDE);
    attn_build_k<<<dim3(4,zb),256,0,stream>>>(ws, R0, RSTRIDE, temperature);
    topk_k<<<dim3(256,zb),64,0,stream>>>(R0, RSTRIDE, attn_w);
    av_k<<<dim3(256,4,zb),256,0,stream>>>(R0, RSTRIDE);
    gemm_pk<<<dim3(128,2,zb),256,0,stream>>>(AW+AWO_H, AW+AWO_L,
                                             (unsigned int*)(R0+R_H), (unsigned int*)(R0+R_H)+2097152,
                                             b_out, out + (size_t)b0*CHW, RSTRIDE, CHW);
  }
}

// Round 8
// 825.075 us; speedup vs baseline: 3.6722x; 1.0040x over previous
//
#include <hip/hip_runtime.h>
#include <math.h>

#define NC 256
#define CH3 768
#define HWSZ 16384

typedef __attribute__((ext_vector_type(8))) short short8;
typedef __attribute__((ext_vector_type(4))) float f32x4;
typedef __attribute__((ext_vector_type(4))) unsigned int u32x4;

// ---- shared (table) region ----
static const size_t OFF_TW1   = 0;
static const size_t OFF_TW2   = 32768;
static const size_t OFF_HM    = 65536;
static const size_t OFF_SCALE = 65600;
static const size_t OFF_SHIFT = 66624;
static const size_t OFF_PACK  = 67648;
static const size_t OFF_AW    = 182336;
static const size_t OFF_GNP   = 444480;
static const size_t SHARED_END= 446528;

// ---- per-batch region ----
// R_QKV: [0..2M) Qf_hi ushort, [2M..4M) Qf_lo ushort (q slot reused),
//        [4M..8M) K fp32, [8M..12.58M) V fp32
// R_SCR: [0..8.39M) pre-dw qkv -> T/U complex, [8.39M..10.49M) Hn_hi, [+2M) Hn_lo
// R_H  : Bq packed (gemm input) -> Kn_hi/lo ushort planes -> Bq2 packed (av out)
static const size_t R_QKV  = 0;
static const size_t R_SCR  = 12582912;
static const size_t R_H    = 25165824;
static const size_t R_PP   = 29360128;
static const size_t R_RP   = 30408704;
static const size_t R_ATTN = 31457280;
static const size_t R_ACOMB= 31473664;
static const size_t R_PS   = 31490048;
static const size_t R_RS   = 31506432;
static const size_t R_DWP  = 31522816;
static const size_t R_SSUM = 31532032;
static const size_t R_SALT = 31532800;
static const size_t R_SSQ  = 31533568;
static const size_t RSTRIDE= 31534336;
static const size_t HNOFF  = 8388608;       // floats into R_SCR

#define TDA_RH 0
#define TDA_RL 8192
#define TDA_IH 16384
#define TDA_IL 24576
#define ETA_RH 32768
#define ETA_RL 40960
#define ETA_IH 49152
#define ETA_IL 57344
#define STB_RH 65536
#define STB_RL 73728
#define STB_IH 81920
#define STB_IL 90112
#define STB_NIH 98304
#define STB_NIL 106496

#define AWQ_H 0
#define AWQ_L 98304
#define AWO_H 196608
#define AWO_L 229376

__device__ inline unsigned short b16rn(float x){
  unsigned u = __float_as_uint(x);
  return (unsigned short)((u + 0x7FFFu + ((u>>16)&1u)) >> 16);
}
__device__ inline unsigned int pk_hi(float x, float y){
  return (__float_as_uint(x)>>16) | (__float_as_uint(y) & 0xFFFF0000u);
}
__device__ inline unsigned int pk_lo(float x, float y){
  float xl = x - __uint_as_float(__float_as_uint(x) & 0xFFFF0000u);
  float yl = y - __uint_as_float(__float_as_uint(y) & 0xFFFF0000u);
  return (unsigned)b16rn(xl) | ((unsigned)b16rn(yl)<<16);
}
__device__ inline short8 ld8g(const unsigned int* p){ return *(const short8*)p; }

// ---------------- tables ----------------
__global__ __launch_bounds__(256) void init_tables_k(float* __restrict__ ws){
  int idx = blockIdx.x*256 + threadIdx.x;
  float2* tw1 = (float2*)(ws + OFF_TW1);
  float2* tw2 = (float2*)(ws + OFF_TW2);
  unsigned int* pk = (unsigned int*)(ws + OFF_PACK);
  const double P2 = 6.283185307179586476925286766559005;
  int m = idx >> 7, k = idx & 127;
  double a2 = P2 * (double)(m*k) / 16384.0;
  tw1[idx] = make_float2((float)cos(a2), (float)(-sin(a2)));
  tw2[idx] = make_float2((float)cos(a2), (float)( sin(a2)));
  if (idx < 64){
    double acc = 0.0;
    for (int v = 1; v < 32; v++) acc += sin(P2 * (double)((v*idx) & 63) / 64.0);
    ws[OFF_HM + idx] = (float)(-acc / 32.0);
  }
  if (idx < 8192){
    int r = idx >> 6, kp = idx & 63;
    int k0 = 2*kp, k1 = 2*kp+1;
    double a0 = P2 * (double)((r*k0) & 127) / 128.0;
    double a1 = P2 * (double)((r*k1) & 127) / 128.0;
    float c0 = (float)cos(a0), c1 = (float)cos(a1);
    float s0 = (float)sin(a0), s1 = (float)sin(a1);
    pk[TDA_RH + idx] = pk_hi(c0, c1);  pk[TDA_RL + idx] = pk_lo(c0, c1);
    pk[TDA_IH + idx] = pk_hi(-s0,-s1); pk[TDA_IL + idx] = pk_lo(-s0,-s1);
    pk[ETA_RH + idx] = pk_hi(c0, c1);  pk[ETA_RL + idx] = pk_lo(c0, c1);
    pk[ETA_IH + idx] = pk_hi(s0, s1);  pk[ETA_IL + idx] = pk_lo(s0, s1);
    float sr0, si0, sr1, si1;
    {
      int d0 = (r - k0) & 127, d1 = (r - k1) & 127;
      if (d0 == 0){ sr0 = 64.f; si0 = 0.f; }
      else if ((d0 & 1) == 0){ sr0 = 0.f; si0 = 0.f; }
      else { double th = 3.1415926535897932384626 * (double)d0 / 128.0;
             sr0 = 1.f; si0 = (float)(cos(th)/sin(th)); }
      if (d1 == 0){ sr1 = 64.f; si1 = 0.f; }
      else if ((d1 & 1) == 0){ sr1 = 0.f; si1 = 0.f; }
      else { double th = 3.1415926535897932384626 * (double)d1 / 128.0;
             sr1 = 1.f; si1 = (float)(cos(th)/sin(th)); }
    }
    pk[STB_RH + idx]  = pk_hi(sr0, sr1);  pk[STB_RL + idx]  = pk_lo(sr0, sr1);
    pk[STB_IH + idx]  = pk_hi(si0, si1);  pk[STB_IL + idx]  = pk_lo(si0, si1);
    pk[STB_NIH + idx] = pk_hi(-si0,-si1); pk[STB_NIL + idx] = pk_lo(-si0,-si1);
  }
}

// ---------------- pack weights (once) ----------------
__global__ __launch_bounds__(256) void wpack_k(const float* __restrict__ wqkv, const float* __restrict__ wout,
                                               unsigned int* __restrict__ aw){
  int id = blockIdx.x*256 + threadIdx.x;
  int row = id >> 7, kp = id & 127;
  if (row < CH3){
    float v0 = wqkv[row*256 + 2*kp], v1 = wqkv[row*256 + 2*kp + 1];
    aw[AWQ_H + row*128 + kp] = pk_hi(v0, v1);
    aw[AWQ_L + row*128 + kp] = pk_lo(v0, v1);
  } else {
    int r2 = row - CH3;
    float v0 = wout[r2*256 + 2*kp], v1 = wout[r2*256 + 2*kp + 1];
    aw[AWO_H + r2*128 + kp] = pk_hi(v0, v1);
    aw[AWO_L + r2*128 + kp] = pk_lo(v0, v1);
  }
}

// ---------------- groupnorm stats ----------------
__global__ __launch_bounds__(256) void gn_part_k(const float* __restrict__ x, float2* __restrict__ part){
  int id = blockIdx.x;
  const float4* p = (const float4*)(x + (size_t)id*HWSZ);
  int tid = threadIdx.x;
  float s = 0.f, sq = 0.f;
  #pragma unroll
  for (int i = 0; i < 16; i++){
    float4 v = p[tid + i*256];
    s  += v.x+v.y+v.z+v.w;
    sq += v.x*v.x+v.y*v.y+v.z*v.z+v.w*v.w;
  }
  __shared__ float r1[256], r2[256];
  r1[tid]=s; r2[tid]=sq; __syncthreads();
  for (int off=128; off; off>>=1){
    if (tid<off){ r1[tid]+=r1[tid+off]; r2[tid]+=r2[tid+off]; }
    __syncthreads();
  }
  if (tid==0) part[id] = make_float2(r1[0], r2[0]);
}
__global__ __launch_bounds__(128) void gn_fin_k(const float2* __restrict__ part, const float* __restrict__ gw,
                                                const float* __restrict__ gb, float* __restrict__ scale,
                                                float* __restrict__ shift){
  int bg = threadIdx.x;
  int b = bg >> 5, g = bg & 31;
  float s = 0.f, sq = 0.f;
  #pragma unroll
  for (int i = 0; i < 8; i++){
    float2 v = part[b*NC + g*8 + i];
    s += v.x; sq += v.y;
  }
  const float n = 8.0f*HWSZ;
  float mu = s/n, var = sq/n - mu*mu;
  float rs = rsqrtf(var + 1e-5f);
  for (int i = 0; i < 8; i++){
    int ch = g*8 + i;
    float sc = rs * gw[ch];
    scale[b*NC + ch] = sc;
    shift[b*NC + ch] = gb[ch] - mu*sc;
  }
}

// ---------------- pack GN(x) into Bq planes ----------------
__global__ __launch_bounds__(256) void packx_k(const float* __restrict__ xbase, const float* __restrict__ scale,
                                               const float* __restrict__ shift, float* __restrict__ R0,
                                               size_t rstride){
  int bz = blockIdx.z;
  const float* xb = xbase + (size_t)bz*NC*HWSZ;
  const float* sc = scale + bz*NC;
  const float* sh = shift + bz*NC;
  unsigned int* BqH = (unsigned int*)(R0 + (size_t)bz*rstride + R_H);
  unsigned int* BqL = BqH + 2097152;
  int kb = blockIdx.y;
  int n = blockIdx.x*256 + threadIdx.x;
  float v[8];
  #pragma unroll
  for (int c = 0; c < 8; c++){
    int ch = kb*8 + c;
    v[c] = xb[(size_t)ch*HWSZ + n]*sc[ch] + sh[ch];
  }
  u32x4 h, l;
  #pragma unroll
  for (int q = 0; q < 4; q++){
    h[q] = pk_hi(v[2*q], v[2*q+1]);
    l[q] = pk_lo(v[2*q], v[2*q+1]);
  }
  *(u32x4*)&BqH[((size_t)kb*HWSZ + n)*4] = h;
  *(u32x4*)&BqL[((size_t)kb*HWSZ + n)*4] = l;
}

// ---------------- LDS-free packed split-bf16 MFMA GEMM, depth-1 register pipeline ----------------
__global__ __launch_bounds__(256) void gemm_pk(const unsigned int* __restrict__ Ah, const unsigned int* __restrict__ Al,
                                               const unsigned int* __restrict__ Bh0, const unsigned int* __restrict__ Bl0,
                                               const float* __restrict__ bias, float* __restrict__ C0,
                                               size_t bstride, size_t cstride){
  const unsigned int* Bh = Bh0 + (size_t)blockIdx.z*bstride;
  const unsigned int* Bl = Bl0 + (size_t)blockIdx.z*bstride;
  float* C = C0 + (size_t)blockIdx.z*cstride;
  int tid = threadIdx.x;
  int lane = tid & 63, wid = tid >> 6;
  int m0 = blockIdx.y*128, n0 = blockIdx.x*128;
  int wr = (wid>>1)*64, wc = (wid&1)*64;
  int lr = lane & 15, lk = lane >> 4;
  f32x4 acc[4][4] = {};
  size_t aoff[4], boff[4];
  #pragma unroll
  for (int i=0;i<4;i++) aoff[i] = (size_t)(m0 + wr + i*16 + lr)*128 + lk*4;
  #pragma unroll
  for (int j=0;j<4;j++) boff[j] = ((size_t)lk*HWSZ + n0 + wc + j*16 + lr)*4;
  short8 aH[2][4], aL[2][4], bH[2][4], bL[2][4];
  #pragma unroll
  for (int i=0;i<4;i++){ aH[0][i] = ld8g(Ah + aoff[i]); aL[0][i] = ld8g(Al + aoff[i]); }
  #pragma unroll
  for (int j=0;j<4;j++){ bH[0][j] = ld8g(Bh + boff[j]); bL[0][j] = ld8g(Bl + boff[j]); }
  #pragma unroll
  for (int kt = 0; kt < 8; kt++){
    int cur = kt & 1, nxt = cur ^ 1;
    if (kt < 7){
      size_t da = (size_t)(kt+1)*16;
      size_t db = (size_t)(kt+1)*4*HWSZ*4;
      #pragma unroll
      for (int i=0;i<4;i++){ aH[nxt][i] = ld8g(Ah + aoff[i] + da); aL[nxt][i] = ld8g(Al + aoff[i] + da); }
      #pragma unroll
      for (int j=0;j<4;j++){ bH[nxt][j] = ld8g(Bh + boff[j] + db); bL[nxt][j] = ld8g(Bl + boff[j] + db); }
    }
    #pragma unroll
    for (int i=0;i<4;i++)
      #pragma unroll
      for (int j=0;j<4;j++){
        acc[i][j] = __builtin_amdgcn_mfma_f32_16x16x32_bf16(aH[cur][i], bH[cur][j], acc[i][j], 0,0,0);
        acc[i][j] = __builtin_amdgcn_mfma_f32_16x16x32_bf16(aH[cur][i], bL[cur][j], acc[i][j], 0,0,0);
        acc[i][j] = __builtin_amdgcn_mfma_f32_16x16x32_bf16(aL[cur][i], bH[cur][j], acc[i][j], 0,0,0);
      }
  }
  #pragma unroll
  for (int i=0;i<4;i++){
    #pragma unroll
    for (int e=0;e<4;e++){
      int row = m0 + wr + i*16 + lk*4 + e;
      float bb = bias ? bias[row] : 0.0f;
      #pragma unroll
      for (int j=0;j<4;j++)
        C[(size_t)row*HWSZ + n0 + wc + j*16 + lr] = acc[i][j][e] + bb;
    }
  }
}

// ---------------- depthwise 3x3, tiled; epilogue packs Qf (flipped) and Kn planes ----------------
__global__ __launch_bounds__(256) void dwconv_tiled_k(float* __restrict__ R0, size_t rstride,
                                                      const float* __restrict__ wdw){
  float* Rb = R0 + (size_t)blockIdx.y*rstride;
  int blk = blockIdx.x;
  int ch = blk >> 2, sl = blk & 3;
  int h0 = sl*32;
  const float* in = Rb + R_SCR + (size_t)ch*HWSZ;
  float* part = Rb + R_DWP;
  float w[9];
  #pragma unroll
  for (int i=0;i<9;i++) w[i] = wdw[ch*9+i];
  __shared__ float tile[34][132];
  __shared__ float r0[256], r1[256], r2[256];
  int tid = threadIdx.x;
  #pragma unroll
  for (int i = 0; i < 5; i++){
    int id = tid + i*256;
    if (id < 1088){
      int r = id >> 5, c4 = id & 31;
      int gh = h0 - 1 + r;
      float4 v = (gh >= 0 && gh < 128) ? *(const float4*)&in[gh*128 + c4*4]
                                       : make_float4(0.f,0.f,0.f,0.f);
      *(float4*)&tile[r][c4*4] = v;
    }
  }
  __syncthreads();
  float s=0.f, sa=0.f, sq=0.f;
  #pragma unroll
  for (int it=0; it<4; it++){
    int idx = it*256 + tid;
    int lh = idx >> 5;
    int xq = idx & 31;
    int xb4 = xq*4;
    float o[4];
    #pragma unroll
    for (int e=0;e<4;e++){
      int xw = xb4 + e;
      float acc = 0.f;
      #pragma unroll
      for (int ky=0; ky<3; ky++){
        const float* tr = &tile[lh+ky][xw];
        if (xw > 0)   acc += tr[-1]*w[ky*3+0];
                      acc += tr[ 0]*w[ky*3+1];
        if (xw < 127) acc += tr[ 1]*w[ky*3+2];
      }
      o[e] = acc;
      s += acc; sq += acc*acc;
      sa += (e & 1) ? -acc : acc;
    }
    int sbase = (h0+lh)*128 + xb4;
    if (ch < 256){
      // Q channel: write packed bf16 hi/lo at FLIPPED positions (Qf planes)
      unsigned short* QHo = (unsigned short*)(Rb + R_QKV);
      unsigned short* QLo = (unsigned short*)(Rb + R_QKV + 2097152);
      size_t ro = (size_t)ch*HWSZ;
      #pragma unroll
      for (int e=0;e<4;e++){
        int sf = (16384 - (sbase+e)) & 16383;
        unsigned u = __float_as_uint(o[e]);
        QHo[ro + sf] = (unsigned short)(u >> 16);
        QLo[ro + sf] = b16rn(o[e] - __uint_as_float(u & 0xFFFF0000u));
      }
    } else if (ch < 512){
      // K channel: fp32 (for fft1) + packed Kn planes (for pri3)
      *(float4*)&(Rb + R_QKV + (size_t)ch*HWSZ)[sbase] = make_float4(o[0],o[1],o[2],o[3]);
      unsigned short* KHo = (unsigned short*)(Rb + R_H);
      unsigned short* KLo = (unsigned short*)(Rb + R_H + 2097152);
      size_t ro = (size_t)(ch-256)*HWSZ;
      #pragma unroll
      for (int e=0;e<4;e++){
        unsigned u = __float_as_uint(o[e]);
        KHo[ro + sbase+e] = (unsigned short)(u >> 16);
        KLo[ro + sbase+e] = b16rn(o[e] - __uint_as_float(u & 0xFFFF0000u));
      }
    } else {
      // V channel: fp32 only
      *(float4*)&(Rb + R_QKV + (size_t)ch*HWSZ)[sbase] = make_float4(o[0],o[1],o[2],o[3]);
    }
  }
  r0[tid]=s; r1[tid]=sa; r2[tid]=sq; __syncthreads();
  for (int off=128; off; off>>=1){
    if (tid<off){ r0[tid]+=r0[tid+off]; r1[tid]+=r1[tid+off]; r2[tid]+=r2[tid+off]; }
    __syncthreads();
  }
  if (tid==0){ part[blk]=r0[0]; part[3072+blk]=r1[0]; part[6144+blk]=r2[0]; }
}

// ---------------- FFT stage 1 (MFMA) ----------------
__global__ __launch_bounds__(256) void fft1_mfma_k(const float* __restrict__ ws, float* __restrict__ R0,
                                                   size_t rstride){
  float* Rb = R0 + (size_t)blockIdx.y*rstride;
  const float* Kb = Rb + R_QKV + (size_t)256*HWSZ;
  float2* Tc = (float2*)(Rb + R_SCR);
  const unsigned int* PK = (const unsigned int*)(ws + OFF_PACK);
  const float2* tw1 = (const float2*)(ws + OFF_TW1);
  __shared__ unsigned int Bth[128][20], Btl[128][20];
  int tid = threadIdx.x;
  int lane = tid & 63, wid = tid >> 6;
  int wr = (wid>>1)*64, wc = (wid&1)*64;
  int lr = lane & 15, lk = lane >> 4;
  int row = blockIdx.x;
  const float* src = Kb + (size_t)row*HWSZ;
  f32x4 aR[4][4] = {}, aI[4][4] = {};
  int bc = tid & 127, grp = tid >> 7;
  for (int kt = 0; kt < 4; kt++){
    #pragma unroll
    for (int p=0;p<8;p++){
      int kp = grp*8 + p;
      int a = kt*32 + 2*kp;
      float v0 = src[a*128 + bc], v1 = src[(a+1)*128 + bc];
      Bth[bc][kp] = pk_hi(v0, v1);
      Btl[bc][kp] = pk_lo(v0, v1);
    }
    __syncthreads();
    short8 bh[4], bl[4];
    #pragma unroll
    for (int j=0;j<4;j++){
      bh[j] = *(const short8*)&Bth[wc + j*16 + lr][lk*4];
      bl[j] = *(const short8*)&Btl[wc + j*16 + lr][lk*4];
    }
    #pragma unroll
    for (int i=0;i<4;i++){
      int off = (wr + i*16 + lr)*64 + kt*16 + lk*4;
      short8 ahR = ld8g(PK + TDA_RH + off), alR = ld8g(PK + TDA_RL + off);
      short8 ahI = ld8g(PK + TDA_IH + off), alI = ld8g(PK + TDA_IL + off);
      #pragma unroll
      for (int j=0;j<4;j++){
        aR[i][j] = __builtin_amdgcn_mfma_f32_16x16x32_bf16(ahR, bh[j], aR[i][j], 0,0,0);
        aR[i][j] = __builtin_amdgcn_mfma_f32_16x16x32_bf16(ahR, bl[j], aR[i][j], 0,0,0);
        aR[i][j] = __builtin_amdgcn_mfma_f32_16x16x32_bf16(alR, bh[j], aR[i][j], 0,0,0);
        aI[i][j] = __builtin_amdgcn_mfma_f32_16x16x32_bf16(ahI, bh[j], aI[i][j], 0,0,0);
        aI[i][j] = __builtin_amdgcn_mfma_f32_16x16x32_bf16(ahI, bl[j], aI[i][j], 0,0,0);
        aI[i][j] = __builtin_amdgcn_mfma_f32_16x16x32_bf16(alI, bh[j], aI[i][j], 0,0,0);
      }
    }
    __syncthreads();
  }
  #pragma unroll
  for (int i=0;i<4;i++)
    #pragma unroll
    for (int e=0;e<4;e++){
      int m = wr + i*16 + lk*4 + e;
      #pragma unroll
      for (int j=0;j<4;j++){
        int col = wc + j*16 + lr;
        float2 t = tw1[m*128 + col];
        float r = aR[i][j][e], im = aI[i][j][e];
        Tc[(size_t)m*32768 + row*128 + col] = make_float2(r*t.x - im*t.y, r*t.y + im*t.x);
      }
    }
}

// ---------------- FFT stage 2 (MFMA, in-place) ----------------
__global__ __launch_bounds__(256) void fft2_mfma_k(const float* __restrict__ ws, float* __restrict__ R0,
                                                   size_t rstride){
  float* Rb = R0 + (size_t)blockIdx.y*rstride;
  float2* TU = (float2*)(Rb + R_SCR);
  const unsigned int* PK = (const unsigned int*)(ws + OFF_PACK);
  const float2* tw2 = (const float2*)(ws + OFF_TW2);
  __shared__ unsigned int ARh[128][20], ARl[128][20], AIh[128][20], AIl[128][20];
  int tid = threadIdx.x;
  int lane = tid & 63, wid = tid >> 6;
  int wr = (wid>>1)*64, wc = (wid&1)*64;
  int lr = lane & 15, lk = lane >> 4;
  int m0 = blockIdx.x*128;
  f32x4 aR[4][4] = {}, aI[4][4] = {};
  const float* Tf = (const float*)TU;
  for (int kt = 0; kt < 4; kt++){
    #pragma unroll
    for (int s=0;s<8;s++){
      int id = tid + s*256;
      int r = id >> 4, kp = id & 15;
      int k = kt*32 + 2*kp;
      float4 v = *(const float4*)&Tf[((size_t)(m0+r)*128 + k)*2];
      ARh[r][kp] = pk_hi(v.x, v.z); ARl[r][kp] = pk_lo(v.x, v.z);
      AIh[r][kp] = pk_hi(v.y, v.w); AIl[r][kp] = pk_lo(v.y, v.w);
    }
    __syncthreads();
    short8 ahR[4], alR[4], ahI[4], alI[4];
    #pragma unroll
    for (int i=0;i<4;i++){
      int ar = wr + i*16 + lr;
      ahR[i] = *(const short8*)&ARh[ar][lk*4];
      alR[i] = *(const short8*)&ARl[ar][lk*4];
      ahI[i] = *(const short8*)&AIh[ar][lk*4];
      alI[i] = *(const short8*)&AIl[ar][lk*4];
    }
    #pragma unroll
    for (int j=0;j<4;j++){
      int boff = (wc + j*16 + lr)*64 + kt*16 + lk*4;
      short8 bhR = ld8g(PK + STB_RH + boff), blR = ld8g(PK + STB_RL + boff);
      short8 bhI = ld8g(PK + STB_IH + boff), blI = ld8g(PK + STB_IL + boff);
      short8 bhN = ld8g(PK + STB_NIH + boff), blN = ld8g(PK + STB_NIL + boff);
      #pragma unroll
      for (int i=0;i<4;i++){
        aR[i][j] = __builtin_amdgcn_mfma_f32_16x16x32_bf16(ahR[i], bhR, aR[i][j], 0,0,0);
        aR[i][j] = __builtin_amdgcn_mfma_f32_16x16x32_bf16(ahR[i], blR, aR[i][j], 0,0,0);
        aR[i][j] = __builtin_amdgcn_mfma_f32_16x16x32_bf16(alR[i], bhR, aR[i][j], 0,0,0);
        aR[i][j] = __builtin_amdgcn_mfma_f32_16x16x32_bf16(ahI[i], bhN, aR[i][j], 0,0,0);
        aR[i][j] = __builtin_amdgcn_mfma_f32_16x16x32_bf16(ahI[i], blN, aR[i][j], 0,0,0);
        aR[i][j] = __builtin_amdgcn_mfma_f32_16x16x32_bf16(alI[i], bhN, aR[i][j], 0,0,0);
        aI[i][j] = __builtin_amdgcn_mfma_f32_16x16x32_bf16(ahR[i], bhI, aI[i][j], 0,0,0);
        aI[i][j] = __builtin_amdgcn_mfma_f32_16x16x32_bf16(ahR[i], blI, aI[i][j], 0,0,0);
        aI[i][j] = __builtin_amdgcn_mfma_f32_16x16x32_bf16(alR[i], bhI, aI[i][j], 0,0,0);
        aI[i][j] = __builtin_amdgcn_mfma_f32_16x16x32_bf16(ahI[i], bhR, aI[i][j], 0,0,0);
        aI[i][j] = __builtin_amdgcn_mfma_f32_16x16x32_bf16(ahI[i], blR, aI[i][j], 0,0,0);
        aI[i][j] = __builtin_amdgcn_mfma_f32_16x16x32_bf16(alI[i], bhR, aI[i][j], 0,0,0);
      }
    }
    __syncthreads();
  }
  #pragma unroll
  for (int i=0;i<4;i++)
    #pragma unroll
    for (int e=0;e<4;e++){
      int m = m0 + wr + i*16 + lk*4 + e;
      int f0 = m >> 8;
      #pragma unroll
      for (int j=0;j<4;j++){
        int col = wc + j*16 + lr;
        float2 t = tw2[f0*128 + col];
        float r = aR[i][j][e], im = aI[i][j][e];
        TU[(size_t)m*128 + col] = make_float2(r*t.x - im*t.y, r*t.y + im*t.x);
      }
    }
}

// ---------------- FFT stage 3 (MFMA), writes Hn packed bf16 hi/lo (normal s order) ----------------
__global__ __launch_bounds__(256) void fft3_mfma_k(const float* __restrict__ ws, float* __restrict__ R0,
                                                   size_t rstride){
  float* Rb = R0 + (size_t)blockIdx.y*rstride;
  const float2* U = (const float2*)(Rb + R_SCR);
  unsigned short* HHo = (unsigned short*)(Rb + R_SCR + HNOFF);
  unsigned short* HLo = (unsigned short*)(Rb + R_SCR + HNOFF + 2097152);
  const unsigned int* PK = (const unsigned int*)(ws + OFF_PACK);
  __shared__ unsigned int BRh[128][20], BRl[128][20], BIh[128][20], BIl[128][20];
  int tid = threadIdx.x;
  int lane = tid & 63, wid = tid >> 6;
  int wr = (wid>>1)*64, wc = (wid&1)*64;
  int lr = lane & 15, lk = lane >> 4;
  int brow = blockIdx.x;                // d row 0..255
  f32x4 ac[4][4] = {};
  int bc = tid & 127, grp = tid >> 7;
  for (int kt = 0; kt < 4; kt++){
    #pragma unroll
    for (int p=0;p<8;p++){
      int kp = grp*8 + p;
      int k = kt*32 + 2*kp;
      float2 v0 = U[((size_t)k*256 + brow)*128 + bc];
      float2 v1 = U[((size_t)(k+1)*256 + brow)*128 + bc];
      BRh[bc][kp] = pk_hi(v0.x, v1.x); BRl[bc][kp] = pk_lo(v0.x, v1.x);
      BIh[bc][kp] = pk_hi(v0.y, v1.y); BIl[bc][kp] = pk_lo(v0.y, v1.y);
    }
    __syncthreads();
    short8 ahR[4], alR[4], ahI[4], alI[4];
    #pragma unroll
    for (int i=0;i<4;i++){
      int off = (wr + i*16 + lr)*64 + kt*16 + lk*4;
      ahR[i] = ld8g(PK + ETA_RH + off); alR[i] = ld8g(PK + ETA_RL + off);
      ahI[i] = ld8g(PK + ETA_IH + off); alI[i] = ld8g(PK + ETA_IL + off);
    }
    #pragma unroll
    for (int j=0;j<4;j++){
      int col = wc + j*16 + lr;
      short8 bhR = *(const short8*)&BRh[col][lk*4];
      short8 blR = *(const short8*)&BRl[col][lk*4];
      short8 bhI = *(const short8*)&BIh[col][lk*4];
      short8 blI = *(const short8*)&BIl[col][lk*4];
      #pragma unroll
      for (int i=0;i<4;i++){
        ac[i][j] = __builtin_amdgcn_mfma_f32_16x16x32_bf16(ahR[i], bhI, ac[i][j], 0,0,0);
        ac[i][j] = __builtin_amdgcn_mfma_f32_16x16x32_bf16(ahR[i], blI, ac[i][j], 0,0,0);
        ac[i][j] = __builtin_amdgcn_mfma_f32_16x16x32_bf16(alR[i], bhI, ac[i][j], 0,0,0);
        ac[i][j] = __builtin_amdgcn_mfma_f32_16x16x32_bf16(ahI[i], bhR, ac[i][j], 0,0,0);
        ac[i][j] = __builtin_amdgcn_mfma_f32_16x16x32_bf16(ahI[i], blR, ac[i][j], 0,0,0);
        ac[i][j] = __builtin_amdgcn_mfma_f32_16x16x32_bf16(alI[i], bhR, ac[i][j], 0,0,0);
      }
    }
    __syncthreads();
  }
  #pragma unroll
  for (int i=0;i<4;i++)
    #pragma unroll
    for (int e=0;e<4;e++){
      int m = wr + i*16 + lk*4 + e;     // u
      #pragma unroll
      for (int j=0;j<4;j++){
        int col = wc + j*16 + lr;       // r
        float v = ac[i][j][e];
        unsigned u = __float_as_uint(v);
        size_t o = (size_t)brow*HWSZ + m*128 + col;
        HHo[o] = (unsigned short)(u >> 16);
        HLo[o] = b16rn(v - __uint_as_float(u & 0xFFFF0000u));
      }
    }
}

// ---------------- P & Ri via LDS-free MFMA over packed planes: grid (64 sp, 4 head, zb) ----------------
__global__ __launch_bounds__(256) void pri3_k(float* __restrict__ R0, size_t rstride){
  float* Rb = R0 + (size_t)blockIdx.z*rstride;
  int sp = blockIdx.x, head = blockIdx.y;
  const unsigned short* QH = (const unsigned short*)(Rb + R_QKV);
  const unsigned short* QL = (const unsigned short*)(Rb + R_QKV + 2097152);
  const unsigned short* KH = (const unsigned short*)(Rb + R_H);
  const unsigned short* KL = (const unsigned short*)(Rb + R_H + 2097152);
  const unsigned short* HH = (const unsigned short*)(Rb + R_SCR + HNOFF);
  const unsigned short* HL = (const unsigned short*)(Rb + R_SCR + HNOFF + 2097152);
  float* Pp = Rb + R_PP;
  float* Rp = Rb + R_RP;
  int tid = threadIdx.x, lane = tid & 63, wid = tid >> 6;
  int wr = (wid>>1)*32, wc = (wid&1)*32;
  int lr = lane & 15, lk = lane >> 4;
  size_t qoff[2], koff[2];
  #pragma unroll
  for (int i=0;i<2;i++) qoff[i] = (size_t)(head*64 + wr + i*16 + lr)*HWSZ + sp*256 + lk*8;
  #pragma unroll
  for (int j=0;j<2;j++) koff[j] = (size_t)(head*64 + wc + j*16 + lr)*HWSZ + sp*256 + lk*8;
  f32x4 aP[2][2] = {}, aRi[2][2] = {};
  short8 qh[2][2], ql[2][2], k1h[2][2], k1l[2][2], k2h[2][2], k2l[2][2];
#define LDPRI(B,T) { int d = (T)*32; \
    _Pragma("unroll") \
    for (int i=0;i<2;i++){ \
      qh[B][i] = *(const short8*)(QH + qoff[i] + d); \
      ql[B][i] = *(const short8*)(QL + qoff[i] + d); } \
    _Pragma("unroll") \
    for (int j=0;j<2;j++){ \
      k1h[B][j] = *(const short8*)(KH + koff[j] + d); \
      k1l[B][j] = *(const short8*)(KL + koff[j] + d); \
      k2h[B][j] = *(const short8*)(HH + koff[j] + d); \
      k2l[B][j] = *(const short8*)(HL + koff[j] + d); } }
  LDPRI(0,0);
  #pragma unroll
  for (int kt = 0; kt < 8; kt++){
    int cur = kt & 1;
    if (kt < 7) LDPRI(cur^1, kt+1);
    #pragma unroll
    for (int i=0;i<2;i++)
      #pragma unroll
      for (int j=0;j<2;j++){
        aP[i][j]  = __builtin_amdgcn_mfma_f32_16x16x32_bf16(qh[cur][i], k1h[cur][j], aP[i][j], 0,0,0);
        aP[i][j]  = __builtin_amdgcn_mfma_f32_16x16x32_bf16(qh[cur][i], k1l[cur][j], aP[i][j], 0,0,0);
        aP[i][j]  = __builtin_amdgcn_mfma_f32_16x16x32_bf16(ql[cur][i], k1h[cur][j], aP[i][j], 0,0,0);
        aRi[i][j] = __builtin_amdgcn_mfma_f32_16x16x32_bf16(qh[cur][i], k2h[cur][j], aRi[i][j], 0,0,0);
        aRi[i][j] = __builtin_amdgcn_mfma_f32_16x16x32_bf16(qh[cur][i], k2l[cur][j], aRi[i][j], 0,0,0);
        aRi[i][j] = __builtin_amdgcn_mfma_f32_16x16x32_bf16(ql[cur][i], k2h[cur][j], aRi[i][j], 0,0,0);
      }
  }
#undef LDPRI
  size_t obase = ((size_t)(sp*4 + head)) << 12;
  #pragma unroll
  for (int i=0;i<2;i++)
    #pragma unroll
    for (int e=0;e<4;e++){
      int row = wr + i*16 + lk*4 + e;
      #pragma unroll
      for (int j=0;j<2;j++){
        int col = wc + j*16 + lr;
        size_t o = obase + (size_t)row*64 + col;
        Pp[o] = aP[i][j][e];
        Rp[o] = aRi[i][j][e];
      }
    }
}

// ---------------- split reduce + dw stat fold ----------------
__global__ __launch_bounds__(256) void red_k(float* __restrict__ R0, size_t rstride){
  float* Rb = R0 + (size_t)blockIdx.y*rstride;
  const float* Pp = Rb + R_PP;
  const float* Rp = Rb + R_RP;
  float* Ps = Rb + R_PS;
  float* Rs = Rb + R_RS;
  int tid = threadIdx.x;
  #pragma unroll
  for (int rep=0; rep<2; rep++){
    int g = blockIdx.x*512 + rep*256 + tid;
    int head = g >> 12, loc = g & 4095;
    float p = 0.f, ri = 0.f;
    for (int sp=0; sp<64; sp++){
      size_t o = ((size_t)(sp*4+head)<<12) + loc;
      p += Pp[o]; ri += Rp[o];
    }
    Ps[g] = p; Rs[g] = ri;
  }
  if (blockIdx.x == 0){
    const float* part = Rb + R_DWP;
    for (int ch = tid; ch < CH3; ch += 256){
      float s=0.f, sa=0.f, sq=0.f;
      #pragma unroll
      for (int sl=0; sl<4; sl++){
        s  += part[ch*4+sl];
        sa += part[3072+ch*4+sl];
        sq += part[6144+ch*4+sl];
      }
      Rb[R_SSUM+ch]=s; Rb[R_SALT+ch]=sa; Rb[R_SSQ+ch]=sq;
    }
  }
}

// ---------------- attn build ----------------
__global__ __launch_bounds__(256) void attn_build_k(const float* __restrict__ ws, float* __restrict__ R0,
                                                    size_t rstride, const float* __restrict__ temperature){
  float* Rb = R0 + (size_t)blockIdx.y*rstride;
  const float* Ps   = Rb + R_PS;
  const float* Rs   = Rb + R_RS;
  const float* ssum = Rb + R_SSUM;
  const float* salt = Rb + R_SALT;
  const float* ssq  = Rb + R_SSQ;
  float* attn = Rb + R_ATTN;
  const float* hmg  = ws + OFF_HM;
  __shared__ float Rn[64][65], Ril[64][65], hm[64];
  int head = blockIdx.x;
  int tid = threadIdx.x;
  if (tid < 64) hm[tid] = hmg[tid];
  for (int t=0;t<16;t++){
    int idx = tid + t*256; int c = idx>>6, d = idx&63;
    float P = Ps[head*4096 + idx], Ri = Rs[head*4096 + idx];
    int qch = head*64 + c;
    int kch = 256 + head*64 + d;
    float qs=ssum[qch], qa=salt[qch], qn=fmaxf(sqrtf(ssq[qch]), 1e-12f);
    float ks=ssum[kch], ka=salt[kch], kn=fmaxf(sqrtf(ssq[kch]), 1e-12f);
    float Rr = 0.5f*(16384.0f*P + qs*ks + qa*ka);
    float sc = 1.0f/(qn*kn);
    Rn[c][d]  = Rr*sc;
    Ril[c][d] = Ri*sc;
  }
  __syncthreads();
  float tmp2 = temperature[(head+2)&3];
  for (int t=0;t<16;t++){
    int idx = tid + t*256; int c = idx>>6, e = idx&63;
    float s = Rn[c][e];
    #pragma unroll 8
    for (int d=0; d<64; d++) s += Ril[c][d]*hm[(e-d)&63];
    attn[((size_t)head<<12) + (size_t)(c*64+e)] = s*tmp2;
  }
}

// ---------------- nested top-k masked softmax ----------------
__global__ __launch_bounds__(64) void topk_k(float* __restrict__ R0, size_t rstride,
                                             const float* __restrict__ attn_w){
  float* Rb = R0 + (size_t)blockIdx.y*rstride;
  const float* attn = Rb + R_ATTN;
  float* Acomb = Rb + R_ACOMB;
  int blk = blockIdx.x;
  int tid = threadIdx.x;
  __shared__ float row[64];
  float v = attn[(size_t)blk*64 + tid];
  row[tid] = v;
  __syncthreads();
  int rank = 0; float vmax = -1e30f;
  for (int l=0;l<64;l++){
    float w = row[l];
    if (w > v || (w == v && l < tid)) rank++;
    vmax = fmaxf(vmax, w);
  }
  float e = expf(v - vmax);
  const int kks[4] = {32,42,48,51};
  float denom[4];
  #pragma unroll
  for (int i=0;i<4;i++){
    float x = (rank < kks[i]) ? e : 0.0f;
    #pragma unroll
    for (int off=32; off; off>>=1) x += __shfl_xor(x, off);
    denom[i] = x;
  }
  float wgt = 0.f;
  #pragma unroll
  for (int i=0;i<4;i++) if (rank < kks[i]) wgt += attn_w[i] / denom[i];
  Acomb[(size_t)blk*64 + tid] = e * wgt;
}

// ---------------- out_head = A_comb @ v, packed output ----------------
__global__ __launch_bounds__(256) void av_k(float* __restrict__ R0, size_t rstride){
  float* Rb = R0 + (size_t)blockIdx.z*rstride;
  const float* Acomb = Rb + R_ACOMB;
  unsigned int* BqH = (unsigned int*)(Rb + R_H);
  unsigned int* BqL = BqH + 2097152;
  int head = blockIdx.y;
  int n0 = blockIdx.x*64;
  const float* Vb = Rb + R_QKV + (size_t)(512 + head*64)*HWSZ;
  __shared__ float As[64][65], Bs[16][65];
  int tid=threadIdx.x, tx=tid&15, ty=tid>>4;
  for (int t=0;t<16;t++){ int idx=tid+t*256; As[idx>>6][idx&63] = Acomb[((size_t)head<<12)+idx]; }
  __syncthreads();
  float acc[4][4]={};
  for (int k0=0;k0<64;k0+=16){
    #pragma unroll
    for (int i=0;i<4;i++){ int id=tid+i*256; int nn=id&63, k=id>>6;
      Bs[k][nn] = Vb[(size_t)(k0+k)*HWSZ + n0+nn]; }
    __syncthreads();
    #pragma unroll
    for (int k=0;k<16;k++){
      float a[4], bv[4];
      #pragma unroll
      for (int i=0;i<4;i++) a[i]=As[ty*4+i][k0+k];
      #pragma unroll
      for (int j=0;j<4;j++) bv[j]=Bs[k][tx*4+j];
      #pragma unroll
      for (int i=0;i<4;i++)
        #pragma unroll
        for (int j=0;j<4;j++) acc[i][j] += a[i]*bv[j];
    }
    __syncthreads();
  }
  int kpa = head*32 + ty*2;
  int kba = kpa >> 2, qa = kpa & 3;
  int kpb = kpa + 1;
  int kbb = kpb >> 2, qb = kpb & 3;
  #pragma unroll
  for (int j=0;j<4;j++){
    int n = n0 + tx*4 + j;
    BqH[((size_t)kba*HWSZ + n)*4 + qa] = pk_hi(acc[0][j], acc[1][j]);
    BqL[((size_t)kba*HWSZ + n)*4 + qa] = pk_lo(acc[0][j], acc[1][j]);
    BqH[((size_t)kbb*HWSZ + n)*4 + qb] = pk_hi(acc[2][j], acc[3][j]);
    BqL[((size_t)kbb*HWSZ + n)*4 + qb] = pk_lo(acc[2][j], acc[3][j]);
  }
}

extern "C" void kernel_launch(void* const* d_in, const int* in_sizes, int n_in,
                              void* d_out, int out_size, void* d_ws, size_t ws_size,
                              hipStream_t stream) {
  const float* x     = (const float*)d_in[0];
  const float* gn_w  = (const float*)d_in[1];
  const float* gn_b  = (const float*)d_in[2];
  const float* w_qkv = (const float*)d_in[3];
  const float* w_dw  = (const float*)d_in[4];
  const float* w_out = (const float*)d_in[5];
  const float* b_out = (const float*)d_in[6];
  const float* temperature = (const float*)d_in[7];
  const float* attn_w = (const float*)d_in[8];
  float* out = (float*)d_out;
  float* ws  = (float*)d_ws;
  unsigned int* AW = (unsigned int*)(ws + OFF_AW);
  float* R0 = ws + SHARED_END;
  const size_t CHW = (size_t)NC*HWSZ;

  size_t need2 = (SHARED_END + 2*RSTRIDE)*sizeof(float);
  size_t need4 = (SHARED_END + 4*RSTRIDE)*sizeof(float);
  int zb = (ws_size >= need4) ? 4 : (ws_size >= need2) ? 2 : 1;

  init_tables_k<<<64,256,0,stream>>>(ws);
  wpack_k<<<512,256,0,stream>>>(w_qkv, w_out, AW);
  gn_part_k<<<1024,256,0,stream>>>(x, (float2*)(ws+OFF_GNP));
  gn_fin_k<<<1,128,0,stream>>>((const float2*)(ws+OFF_GNP), gn_w, gn_b,
                               ws+OFF_SCALE, ws+OFF_SHIFT);

  for (int b0 = 0; b0 < 4; b0 += zb){
    packx_k<<<dim3(64,32,zb),256,0,stream>>>(x + (size_t)b0*CHW, ws+OFF_SCALE+b0*NC,
                                             ws+OFF_SHIFT+b0*NC, R0, RSTRIDE);
    gemm_pk<<<dim3(128,6,zb),256,0,stream>>>(AW+AWQ_H, AW+AWQ_L,
                                             (unsigned int*)(R0+R_H), (unsigned int*)(R0+R_H)+2097152,
                                             nullptr, R0+R_SCR, RSTRIDE, RSTRIDE);
    dwconv_tiled_k<<<dim3(3072,zb),256,0,stream>>>(R0, RSTRIDE, w_dw);
    fft1_mfma_k<<<dim3(256,zb),256,0,stream>>>(ws, R0, RSTRIDE);
    fft2_mfma_k<<<dim3(256,zb),256,0,stream>>>(ws, R0, RSTRIDE);
    fft3_mfma_k<<<dim3(256,zb),256,0,stream>>>(ws, R0, RSTRIDE);
    pri3_k<<<dim3(64,4,zb),256,0,stream>>>(R0, RSTRIDE);
    red_k<<<dim3(32,zb),256,0,stream>>>(R0, RSTRIDE);
    attn_build_k<<<dim3(4,zb),256,0,stream>>>(ws, R0, RSTRIDE, temperature);
    topk_k<<<dim3(256,zb),64,0,stream>>>(R0, RSTRIDE, attn_w);
    av_k<<<dim3(256,4,zb),256,0,stream>>>(R0, RSTRIDE);
    gemm_pk<<<dim3(128,2,zb),256,0,stream>>>(AW+AWO_H, AW+AWO_L,
                                             (unsigned int*)(R0+R_H), (unsigned int*)(R0+R_H)+2097152,
                                             b_out, out + (size_t)b0*CHW, RSTRIDE, CHW);
  }
}